// Round 4
// baseline (277.083 us; speedup 1.0000x reference)
//
#include <hip/hip_runtime.h>

// ---------------------------------------------------------------------------
// TransformerDecoderBlockV2: bf16 MFMA implementation for gfx950
// B=1, N=2048, M=2048, D=1024, H=16, dh=64, DFF=4096
// ---------------------------------------------------------------------------

using bf16x8 = __attribute__((ext_vector_type(8))) short;
using f32x4  = __attribute__((ext_vector_type(4))) float;
using f32x16 = __attribute__((ext_vector_type(16))) float;

__device__ __forceinline__ ushort f2bf(float f) {
    unsigned u = __float_as_uint(f);
    unsigned r = (u + 0x7fffu + ((u >> 16) & 1u)) >> 16;
    return (ushort)r;
}

__device__ __forceinline__ void gload16(const void* g, void* l) {
    __builtin_amdgcn_global_load_lds(
        (const __attribute__((address_space(1))) void*)g,
        (__attribute__((address_space(3))) void*)l, 16, 0, 0);
}

__device__ __forceinline__ float gelu_erf(float v) {
    return 0.5f * v * (1.0f + erff(v * 0.70710678118654752f));
}

__device__ __forceinline__ f32x16 mfma32(bf16x8 a, bf16x8 b, f32x16 c) {
    return __builtin_amdgcn_mfma_f32_32x32x16_bf16(a, b, c, 0, 0, 0);
}

__device__ __forceinline__ uint cvtpk(float a, float b) {
    uint r;
    asm("v_cvt_pk_bf16_f32 %0, %1, %2" : "=v"(r) : "v"(a), "v"(b));
    return r;
}

// ---------------------------------------------------------------------------
__global__ __launch_bounds__(256) void cvt4(const float* __restrict__ in,
                                            ushort* __restrict__ out, int n) {
    int i = (blockIdx.x * 256 + threadIdx.x) * 4;
    if (i + 3 < n) {
        float4 v = *(const float4*)(in + i);
        ushort4 o;
        o.x = f2bf(v.x); o.y = f2bf(v.y); o.z = f2bf(v.z); o.w = f2bf(v.w);
        *(ushort4*)(out + i) = o;
    }
}

// ---------------------------------------------------------------------------
__global__ __launch_bounds__(256) void tcvt(const float* __restrict__ in,
                                            ushort* __restrict__ out, int R, int C) {
    __shared__ float tile[32][33];
    const int tx = threadIdx.x, ty = threadIdx.y;
    const int c0 = blockIdx.x * 32, r0 = blockIdx.y * 32;
#pragma unroll
    for (int i = 0; i < 4; ++i)
        tile[ty + 8 * i][tx] = in[(size_t)(r0 + ty + 8 * i) * C + c0 + tx];
    __syncthreads();
#pragma unroll
    for (int i = 0; i < 4; ++i)
        out[(size_t)(c0 + ty + 8 * i) * R + r0 + tx] = f2bf(tile[tx][ty + 8 * i]);
}

// ---------------------------------------------------------------------------
__global__ __launch_bounds__(256) void vtrans(const ushort* __restrict__ KV,
                                              ushort* __restrict__ Vt) {
    __shared__ ushort tile[32][34];
    const int tx = threadIdx.x, ty = threadIdx.y;
    const int j0 = blockIdx.x * 32, d0 = blockIdx.y * 32;
#pragma unroll
    for (int i = 0; i < 4; ++i)
        tile[ty + 8 * i][tx] = KV[(size_t)(j0 + ty + 8 * i) * 2048 + 1024 + d0 + tx];
    __syncthreads();
#pragma unroll
    for (int i = 0; i < 4; ++i)
        Vt[(size_t)(d0 + ty + 8 * i) * 4096 + j0 + tx] = tile[tx][ty + 8 * i];
}

// ---------------------------------------------------------------------------
// GEMM: C[M][N] = epilogue( A[M][K] * Bt[N][K]^T + bias ), bf16 in.
// ---------------------------------------------------------------------------
template <int BM, int BN, int ACT, int OUTF32, int RES, int SCALED, int SPLITK>
__global__ __launch_bounds__(256) void gemm_bt(
    const ushort* __restrict__ A, int lda, const ushort* __restrict__ Bt, int ldb,
    const float* __restrict__ bias, const float* __restrict__ resid,
    void* __restrict__ Cout, int M, int N, int K, float scale) {
    constexpr int MR = BM / 32, NR = BN / 32;
    __shared__ __align__(16) ushort Asm[BM * 64];
    __shared__ __align__(16) ushort Bsm[BN * 64];
    const int tid = threadIdx.x;
    const int w = tid >> 6, lane = tid & 63, g = lane >> 4, i15 = lane & 15;
    const int wm = w >> 1, wn = w & 1;
    const int m0 = blockIdx.y * BM, n0 = blockIdx.x * BN;
    if (SPLITK) {
        A += (size_t)blockIdx.z * K;
        Bt += (size_t)blockIdx.z * K;
    }

    f32x4 acc[MR][NR] = {};

    for (int kt = 0; kt < K; kt += 64) {
#pragma unroll
        for (int q = 0; q < BM / 32; ++q) {
            int off = (w * (BM / 32) + q) * 1024 + lane * 16;
            int r = off >> 7, cb = off & 127;
            int scb = cb ^ ((r & 7) << 4);
            const void* src = (const char*)A + ((size_t)(m0 + r) * lda + kt) * 2 + scb;
            gload16(src, (char*)Asm + (w * (BM / 32) + q) * 1024);
        }
#pragma unroll
        for (int q = 0; q < BN / 32; ++q) {
            int off = (w * (BN / 32) + q) * 1024 + lane * 16;
            int r = off >> 7, cb = off & 127;
            int scb = cb ^ ((r & 7) << 4);
            const void* src = (const char*)Bt + ((size_t)(n0 + r) * ldb + kt) * 2 + scb;
            gload16(src, (char*)Bsm + (w * (BN / 32) + q) * 1024);
        }
        __syncthreads();

#pragma unroll
        for (int kc = 0; kc < 2; ++kc) {
            bf16x8 af[MR], bfr[NR];
#pragma unroll
            for (int mi = 0; mi < MR; ++mi) {
                int r = wm * (BM / 2) + mi * 16 + i15;
                af[mi] = *(const bf16x8*)((const char*)Asm + r * 128 +
                                          ((kc * 64 + g * 16) ^ ((r & 7) << 4)));
            }
#pragma unroll
            for (int ni = 0; ni < NR; ++ni) {
                int r = wn * (BN / 2) + ni * 16 + i15;
                bfr[ni] = *(const bf16x8*)((const char*)Bsm + r * 128 +
                                           ((kc * 64 + g * 16) ^ ((r & 7) << 4)));
            }
#pragma unroll
            for (int mi = 0; mi < MR; ++mi)
#pragma unroll
                for (int ni = 0; ni < NR; ++ni)
                    acc[mi][ni] = __builtin_amdgcn_mfma_f32_16x16x32_bf16(
                        af[mi], bfr[ni], acc[mi][ni], 0, 0, 0);
        }
        __syncthreads();
    }

    float* Cf = (float*)Cout;
    if (SPLITK) Cf += (size_t)blockIdx.z * M * N;

#pragma unroll
    for (int ni = 0; ni < NR; ++ni) {
        int col = n0 + wn * (BN / 2) + ni * 16 + i15;
        float bb = bias ? bias[col] : 0.f;
#pragma unroll
        for (int mi = 0; mi < MR; ++mi) {
#pragma unroll
            for (int r2 = 0; r2 < 4; ++r2) {
                int row = m0 + wm * (BM / 2) + mi * 16 + 4 * g + r2;
                float v = acc[mi][ni][r2] + bb;
                if (ACT) v = gelu_erf(v);
                if (SCALED) v *= scale;
                size_t off = (size_t)row * N + col;
                if (OUTF32) {
                    float rv = RES ? resid[off] : 0.f;
                    Cf[off] = v + rv;
                } else {
                    ((ushort*)Cout)[off] = f2bf(v);
                }
            }
        }
    }
}

// ---------------------------------------------------------------------------
// Flash attention v3: 32x32x16 MFMA, all-register, zero LDS, zero barriers.
// Wave = 32 q-rows. S^T = K*Q^T (lane owns row i = lane&31 of softmax);
// O^T = V^T*P^T with P^T built in-register via cvt_pk + permlane32_swap.
// K/V/Q fragments read directly from global (L2, XCD-pinned by h).
// NS-way KV split -> f32 partials + (m,l), merged by attn_combine.
// ---------------------------------------------------------------------------
template <int NS>
__global__ __launch_bounds__(256) void flash_attn2(
    const ushort* __restrict__ Q,    // [2048][1024] bf16 (pre-scaled 0.125*log2e)
    const ushort* __restrict__ KVb,  // [4096][2048] bf16 (K = cols 0..1023)
    const ushort* __restrict__ Vt,   // [1024][4096] bf16
    ushort* __restrict__ O,          // NS==1: [2048][1024] bf16
    float* __restrict__ Opart,       // NS>1: [NS][2048][1024] f32
    float* __restrict__ Ml) {        // NS>1: [NS][2048][16][2] f32
    const int tid = threadIdx.x;
    const int w = tid >> 6, lane = tid & 63;
    const int i31 = lane & 31, hig = lane >> 5;
    const int bid = blockIdx.x;
    const int h = bid & 15;                    // bid%8 == h%8 -> same-head same-XCD
    const int qB = 15 - ((bid >> 4) & 15);     // heavy q-blocks first
    const int s = bid >> 8;
    const int qb = qB * 128 + w * 32;
    const int qrow = qb + i31;
    const int diag = qb >> 6;
    const int nt = diag + 33;
    const int lo = (s * nt) / NS;
    const int ht = ((s + 1) * nt) / NS;

    bf16x8 qf[4], kf[8], vf[8];
    {
        const ushort* qp = Q + (size_t)qrow * 1024 + h * 64 + hig * 8;
#pragma unroll
        for (int ks = 0; ks < 4; ++ks) qf[ks] = *(const bf16x8*)(qp + ks * 16);
    }
    const ushort* kb_p = KVb + h * 64 + hig * 8;
    const ushort* vb_p = Vt + (size_t)(h * 64 + i31) * 4096 + hig * 8;

    auto load_k = [&](int jt) {
#pragma unroll
        for (int sub = 0; sub < 2; ++sub)
#pragma unroll
            for (int ks = 0; ks < 4; ++ks)
                kf[sub * 4 + ks] = *(const bf16x8*)(
                    kb_p + (size_t)(jt * 64 + sub * 32 + i31) * 2048 + ks * 16);
    };
    auto load_v = [&](int jt) {
#pragma unroll
        for (int ds = 0; ds < 2; ++ds)
#pragma unroll
            for (int t4 = 0; t4 < 4; ++t4)
                vf[ds * 4 + t4] = *(const bf16x8*)(
                    vb_p + (size_t)ds * 32 * 4096 + jt * 64 + t4 * 16);
    };

    f32x16 o0 = {}, o1 = {};
    float m_run = -INFINITY, l_run = 0.f;

    {
        int jt0 = (lo <= diag) ? lo : 32 + (lo - diag - 1);
        load_k(jt0);
        load_v(jt0);
    }

    for (int t = lo; t < ht; ++t) {
        const int tn = (t + 1 < ht) ? t + 1 : t;
        const int jtn = (tn <= diag) ? tn : 32 + (tn - diag - 1);

        // S^T subtiles (rows j, col i = lane&31)
        f32x16 s0 = {}, s1 = {};
#pragma unroll
        for (int ks = 0; ks < 4; ++ks) s0 = mfma32(kf[ks], qf[ks], s0);
#pragma unroll
        for (int ks = 0; ks < 4; ++ks) s1 = mfma32(kf[4 + ks], qf[ks], s1);
        load_k(jtn);                         // prefetch next K (regs free, WAR-safe)

        if (t == diag) {
            const int jb = diag * 64;
#pragma unroll
            for (int r = 0; r < 16; ++r) {
                int jl = (r & 3) + 8 * (r >> 2) + 4 * hig;
                if (jb + jl > qrow) s0[r] = -50000.f;
                if (jb + 32 + jl > qrow) s1[r] = -50000.f;
            }
        }

        // per-lane row max (row i is fully lane-local + partner)
        float mt = -INFINITY;
#pragma unroll
        for (int r = 0; r < 16; ++r) mt = fmaxf(mt, fmaxf(s0[r], s1[r]));
        mt = fmaxf(mt, __shfl_xor(mt, 32));

        const bool skip = __all(mt - m_run <= 8.f);   // defer-max
        float mnew, fscale;
        if (skip) { mnew = m_run; fscale = 1.f; }
        else      { mnew = fmaxf(m_run, mt); fscale = exp2f(m_run - mnew); }

        float psum = 0.f;
#pragma unroll
        for (int r = 0; r < 16; ++r) {
            s0[r] = exp2f(s0[r] - mnew);
            s1[r] = exp2f(s1[r] - mnew);
            psum += s0[r] + s1[r];
        }
        psum += __shfl_xor(psum, 32);
        l_run = l_run * fscale + psum;
        m_run = mnew;

        if (!skip) {
#pragma unroll
            for (int r = 0; r < 16; ++r) { o0[r] *= fscale; o1[r] *= fscale; }
        }

        // build P^T frags (cvt_pk + permlane32_swap) and accumulate O^T += V^T P^T
#pragma unroll
        for (int t4 = 0; t4 < 4; ++t4) {
            const int r0 = 8 * (t4 & 1);
            uint w0, w1, w2, w3;
            if (t4 < 2) {
                w0 = cvtpk(s0[r0 + 0], s0[r0 + 1]);
                w1 = cvtpk(s0[r0 + 2], s0[r0 + 3]);
                w2 = cvtpk(s0[r0 + 4], s0[r0 + 5]);
                w3 = cvtpk(s0[r0 + 6], s0[r0 + 7]);
            } else {
                w0 = cvtpk(s1[r0 + 0], s1[r0 + 1]);
                w1 = cvtpk(s1[r0 + 2], s1[r0 + 3]);
                w2 = cvtpk(s1[r0 + 4], s1[r0 + 5]);
                w3 = cvtpk(s1[r0 + 6], s1[r0 + 7]);
            }
            asm volatile("v_permlane32_swap_b32 %0, %1" : "+v"(w0), "+v"(w2));
            asm volatile("v_permlane32_swap_b32 %0, %1" : "+v"(w1), "+v"(w3));
            uint4 pw; pw.x = w0; pw.y = w1; pw.z = w2; pw.w = w3;
            bf16x8 pfr = *(bf16x8*)&pw;
            o0 = mfma32(vf[t4], pfr, o0);
            o1 = mfma32(vf[4 + t4], pfr, o1);
        }
        load_v(jtn);                         // prefetch next V
    }

    if (NS == 1) {
        float inv = 1.f / l_run;
#pragma unroll
        for (int ds = 0; ds < 2; ++ds)
#pragma unroll
            for (int q = 0; q < 4; ++q) {
                float v0 = (ds ? o1[4 * q + 0] : o0[4 * q + 0]) * inv;
                float v1 = (ds ? o1[4 * q + 1] : o0[4 * q + 1]) * inv;
                float v2 = (ds ? o1[4 * q + 2] : o0[4 * q + 2]) * inv;
                float v3 = (ds ? o1[4 * q + 3] : o0[4 * q + 3]) * inv;
                uint2 pk; pk.x = cvtpk(v0, v1); pk.y = cvtpk(v2, v3);
                int col = h * 64 + ds * 32 + 8 * q + 4 * hig;
                *(uint2*)(O + (size_t)qrow * 1024 + col) = pk;
            }
    } else {
        if (hig == 0) {
            float* mp = Ml + ((size_t)(s * 2048 + qrow) * 16 + h) * 2;
            mp[0] = m_run; mp[1] = l_run;
        }
#pragma unroll
        for (int ds = 0; ds < 2; ++ds)
#pragma unroll
            for (int q = 0; q < 4; ++q) {
                float4 v;
                v.x = ds ? o1[4 * q + 0] : o0[4 * q + 0];
                v.y = ds ? o1[4 * q + 1] : o0[4 * q + 1];
                v.z = ds ? o1[4 * q + 2] : o0[4 * q + 2];
                v.w = ds ? o1[4 * q + 3] : o0[4 * q + 3];
                int col = h * 64 + ds * 32 + 8 * q + 4 * hig;
                *(float4*)(Opart + (size_t)(s * 2048 + qrow) * 1024 + col) = v;
            }
    }
}

// ---------------------------------------------------------------------------
template <int NS>
__global__ __launch_bounds__(256) void attn_combine(
    const float* __restrict__ Opart, const float* __restrict__ Ml,
    ushort* __restrict__ O) {
    const int row = blockIdx.x, tid = threadIdx.x;
    const int c = tid * 4, h = c >> 6;
    float ms[NS], ls[NS];
#pragma unroll
    for (int s = 0; s < NS; ++s) {
        const float* mp = Ml + ((size_t)(s * 2048 + row) * 16 + h) * 2;
        ms[s] = mp[0]; ls[s] = mp[1];
    }
    float m = ms[0];
#pragma unroll
    for (int s = 1; s < NS; ++s) m = fmaxf(m, ms[s]);
    float denom = 0.f, wgt[NS];
#pragma unroll
    for (int s = 0; s < NS; ++s) { wgt[s] = exp2f(ms[s] - m); denom += ls[s] * wgt[s]; }
    const float inv = 1.f / denom;
    float ax = 0, ay = 0, az = 0, aw = 0;
#pragma unroll
    for (int s = 0; s < NS; ++s) {
        float4 a = *(const float4*)(Opart + (size_t)(s * 2048 + row) * 1024 + c);
        ax += a.x * wgt[s]; ay += a.y * wgt[s]; az += a.z * wgt[s]; aw += a.w * wgt[s];
    }
    ushort4 ob;
    ob.x = f2bf(ax * inv); ob.y = f2bf(ay * inv);
    ob.z = f2bf(az * inv); ob.w = f2bf(aw * inv);
    *(ushort4*)(O + (size_t)row * 1024 + c) = ob;
}

// ---------------------------------------------------------------------------
__global__ __launch_bounds__(256) void layernorm_k(
    const float* __restrict__ in, const float* __restrict__ gam,
    const float* __restrict__ bet, float* __restrict__ outf,
    ushort* __restrict__ outb) {
    const int row = blockIdx.x, tid = threadIdx.x;
    const float4 v = *(const float4*)(in + (size_t)row * 1024 + tid * 4);
    float s = v.x + v.y + v.z + v.w;
    float sq = v.x * v.x + v.y * v.y + v.z * v.z + v.w * v.w;
#pragma unroll
    for (int d = 1; d < 64; d <<= 1) {
        s += __shfl_xor(s, d);
        sq += __shfl_xor(sq, d);
    }
    __shared__ float red[8];
    const int w = tid >> 6;
    if ((tid & 63) == 0) { red[w] = s; red[4 + w] = sq; }
    __syncthreads();
    s = red[0] + red[1] + red[2] + red[3];
    sq = red[4] + red[5] + red[6] + red[7];
    const float mu = s * (1.f / 1024.f);
    const float rs = rsqrtf(sq * (1.f / 1024.f) - mu * mu + 1e-5f);
    const float4 gg = *(const float4*)(gam + tid * 4);
    const float4 bb = *(const float4*)(bet + tid * 4);
    float4 o;
    o.x = (v.x - mu) * rs * gg.x + bb.x;
    o.y = (v.y - mu) * rs * gg.y + bb.y;
    o.z = (v.z - mu) * rs * gg.z + bb.z;
    o.w = (v.w - mu) * rs * gg.w + bb.w;
    *(float4*)(outf + (size_t)row * 1024 + tid * 4) = o;
    if (outb) {
        ushort4 ob;
        ob.x = f2bf(o.x); ob.y = f2bf(o.y); ob.z = f2bf(o.z); ob.w = f2bf(o.w);
        *(ushort4*)(outb + (size_t)row * 1024 + tid * 4) = ob;
    }
}

// ---------------------------------------------------------------------------
__global__ __launch_bounds__(256) void layernorm_comb(
    const float* __restrict__ in0, const float* __restrict__ in1,
    const float* __restrict__ bias, const float* __restrict__ resid,
    const float* __restrict__ gam, const float* __restrict__ bet,
    float* __restrict__ outf) {
    const int row = blockIdx.x, tid = threadIdx.x;
    const float4 a = *(const float4*)(in0 + (size_t)row * 1024 + tid * 4);
    const float4 b = *(const float4*)(in1 + (size_t)row * 1024 + tid * 4);
    const float4 rr = *(const float4*)(resid + (size_t)row * 1024 + tid * 4);
    const float4 bs = *(const float4*)(bias + tid * 4);
    float4 v;
    v.x = a.x + b.x + rr.x + bs.x;
    v.y = a.y + b.y + rr.y + bs.y;
    v.z = a.z + b.z + rr.z + bs.z;
    v.w = a.w + b.w + rr.w + bs.w;
    float s = v.x + v.y + v.z + v.w;
    float sq = v.x * v.x + v.y * v.y + v.z * v.z + v.w * v.w;
#pragma unroll
    for (int d = 1; d < 64; d <<= 1) {
        s += __shfl_xor(s, d);
        sq += __shfl_xor(sq, d);
    }
    __shared__ float red[8];
    const int w = tid >> 6;
    if ((tid & 63) == 0) { red[w] = s; red[4 + w] = sq; }
    __syncthreads();
    s = red[0] + red[1] + red[2] + red[3];
    sq = red[4] + red[5] + red[6] + red[7];
    const float mu = s * (1.f / 1024.f);
    const float rs = rsqrtf(sq * (1.f / 1024.f) - mu * mu + 1e-5f);
    const float4 gg = *(const float4*)(gam + tid * 4);
    const float4 bb = *(const float4*)(bet + tid * 4);
    float4 o;
    o.x = (v.x - mu) * rs * gg.x + bb.x;
    o.y = (v.y - mu) * rs * gg.y + bb.y;
    o.z = (v.z - mu) * rs * gg.z + bb.z;
    o.w = (v.w - mu) * rs * gg.w + bb.w;
    *(float4*)(outf + (size_t)row * 1024 + tid * 4) = o;
}

// ---------------------------------------------------------------------------
extern "C" void kernel_launch(void* const* d_in, const int* in_sizes, int n_in,
                              void* d_out, int out_size, void* d_ws, size_t ws_size,
                              hipStream_t stream) {
    const float* x    = (const float*)d_in[0];
    const float* ctx  = (const float*)d_in[1];
    const float* Wq   = (const float*)d_in[2];
    const float* bq   = (const float*)d_in[3];
    const float* Wkv  = (const float*)d_in[4];
    const float* bkv  = (const float*)d_in[5];
    const float* Wo   = (const float*)d_in[6];
    const float* bo   = (const float*)d_in[7];
    const float* g1   = (const float*)d_in[8];
    const float* b1   = (const float*)d_in[9];
    const float* W1   = (const float*)d_in[10];
    const float* bf1  = (const float*)d_in[11];
    const float* W2   = (const float*)d_in[12];
    const float* bf2  = (const float*)d_in[13];
    const float* g2   = (const float*)d_in[14];
    const float* b2   = (const float*)d_in[15];

    char* ws = (char*)d_ws;
    const size_t MB = 1u << 20;
    ushort* XCb  = (ushort*)(ws + 0);        // 8MB; later FFN2 partials P0/P1
    ushort* WoT  = (ushort*)(ws + 8 * MB);   // 2MB
    ushort* W1T  = (ushort*)(ws + 10 * MB);  // 8MB
    ushort* W2T  = (ushort*)(ws + 18 * MB);  // 8MB
    ushort* WqT  = (ushort*)(ws + 26 * MB);  // 2MB; later x1b
    ushort* WkvT = (ushort*)(ws + 28 * MB);  // 4MB
    ushort* Qs   = (ushort*)(ws + 32 * MB);  // 4MB; later x1f
    ushort* attn = (ushort*)(ws + 36 * MB);  // 4MB
    ushort* KV   = (ushort*)(ws + 40 * MB);  // 16MB; later ff
    ushort* Vt   = (ushort*)(ws + 56 * MB);  // 8MB; later y1
    ushort* x1b  = (ushort*)(ws + 26 * MB);  // 4MB
    float*  x1f  = (float*)(ws + 32 * MB);   // 8MB
    ushort* ffb  = (ushort*)(ws + 40 * MB);  // 16MB
    float*  y1   = (float*)(ws + 56 * MB);   // 8MB
    float*  Pk   = (float*)(ws + 0);         // 16MB: FFN2 split-K partials
    float*  Opart = (float*)(ws + 64 * MB);  // NS*8MB: attn split partials

    cvt4<<<2048, 256, 0, stream>>>(x, XCb, 2048 * 1024);
    cvt4<<<2048, 256, 0, stream>>>(ctx, XCb + 2048 * 1024, 2048 * 1024);
    tcvt<<<dim3(32, 32), dim3(32, 8), 0, stream>>>(Wq, WqT, 1024, 1024);
    tcvt<<<dim3(64, 32), dim3(32, 8), 0, stream>>>(Wkv, WkvT, 1024, 2048);
    tcvt<<<dim3(32, 32), dim3(32, 8), 0, stream>>>(Wo, WoT, 1024, 1024);
    tcvt<<<dim3(128, 32), dim3(32, 8), 0, stream>>>(W1, W1T, 1024, 4096);
    tcvt<<<dim3(32, 128), dim3(32, 8), 0, stream>>>(W2, W2T, 4096, 1024);
    // Q = (x@Wq + bq) * 0.125 * log2(e)
    gemm_bt<64, 64, 0, 0, 0, 1, 0><<<dim3(16, 32), 256, 0, stream>>>(
        XCb, 1024, WqT, 1024, bq, nullptr, Qs, 2048, 1024, 1024, 0.18033688011112042f);
    gemm_bt<128, 128, 0, 0, 0, 0, 0><<<dim3(16, 32), 256, 0, stream>>>(
        XCb, 1024, WkvT, 1024, bkv, nullptr, KV, 4096, 2048, 1024, 1.f);
    vtrans<<<dim3(128, 32), dim3(32, 8), 0, stream>>>(KV, Vt);

    const size_t need4 = 64 * MB + 4 * 8 * MB + 4 * 2048 * 16 * 2 * 4;
    const size_t need2 = 64 * MB + 2 * 8 * MB + 2 * 2048 * 16 * 2 * 4;
    if (ws_size >= need4) {
        float* Ml = Opart + (size_t)4 * 2048 * 1024;
        flash_attn2<4><<<1024, 256, 0, stream>>>(Qs, KV, Vt, nullptr, Opart, Ml);
        attn_combine<4><<<2048, 256, 0, stream>>>(Opart, Ml, attn);
    } else if (ws_size >= need2) {
        float* Ml = Opart + (size_t)2 * 2048 * 1024;
        flash_attn2<2><<<512, 256, 0, stream>>>(Qs, KV, Vt, nullptr, Opart, Ml);
        attn_combine<2><<<2048, 256, 0, stream>>>(Opart, Ml, attn);
    } else {
        flash_attn2<1><<<256, 256, 0, stream>>>(Qs, KV, Vt, attn, nullptr, nullptr);
    }

    gemm_bt<64, 64, 0, 1, 1, 0, 0><<<dim3(16, 32), 256, 0, stream>>>(
        attn, 1024, WoT, 1024, bo, x, y1, 2048, 1024, 1024, 1.f);
    layernorm_k<<<2048, 256, 0, stream>>>(y1, g1, b1, x1f, x1b);
    gemm_bt<128, 128, 1, 0, 0, 0, 0><<<dim3(32, 16), 256, 0, stream>>>(
        x1b, 1024, W1T, 1024, bf1, nullptr, ffb, 2048, 4096, 1024, 1.f);
    gemm_bt<64, 64, 0, 1, 0, 0, 1><<<dim3(16, 32, 2), 256, 0, stream>>>(
        ffb, 4096, W2T, 4096, nullptr, nullptr, Pk, 2048, 1024, 2048, 1.f);
    layernorm_comb<<<2048, 256, 0, stream>>>(Pk, Pk + 2048 * 1024, bf2, x1f,
                                             g2, b2, (float*)d_out);
}

// Round 5
// 237.591 us; speedup vs baseline: 1.1662x; 1.1662x over previous
//
#include <hip/hip_runtime.h>

// ---------------------------------------------------------------------------
// TransformerDecoderBlockV2: bf16 MFMA implementation for gfx950
// B=1, N=2048, M=2048, D=1024, H=16, dh=64, DFF=4096
// ---------------------------------------------------------------------------

using bf16x8 = __attribute__((ext_vector_type(8))) short;
using f32x4  = __attribute__((ext_vector_type(4))) float;
using f32x16 = __attribute__((ext_vector_type(16))) float;

__device__ __forceinline__ ushort f2bf(float f) {
    unsigned u = __float_as_uint(f);
    unsigned r = (u + 0x7fffu + ((u >> 16) & 1u)) >> 16;
    return (ushort)r;
}

__device__ __forceinline__ void gload16(const void* g, void* l) {
    __builtin_amdgcn_global_load_lds(
        (const __attribute__((address_space(1))) void*)g,
        (__attribute__((address_space(3))) void*)l, 16, 0, 0);
}

__device__ __forceinline__ float gelu_erf(float v) {
    return 0.5f * v * (1.0f + erff(v * 0.70710678118654752f));
}

__device__ __forceinline__ f32x16 mfma32(bf16x8 a, bf16x8 b, f32x16 c) {
    return __builtin_amdgcn_mfma_f32_32x32x16_bf16(a, b, c, 0, 0, 0);
}

__device__ __forceinline__ uint cvtpk(float a, float b) {
    uint r;
    asm("v_cvt_pk_bf16_f32 %0, %1, %2" : "=v"(r) : "v"(a), "v"(b));
    return r;
}

// ---------------------------------------------------------------------------
__global__ __launch_bounds__(256) void cvt4(const float* __restrict__ in,
                                            ushort* __restrict__ out, int n) {
    int i = (blockIdx.x * 256 + threadIdx.x) * 4;
    if (i + 3 < n) {
        float4 v = *(const float4*)(in + i);
        ushort4 o;
        o.x = f2bf(v.x); o.y = f2bf(v.y); o.z = f2bf(v.z); o.w = f2bf(v.w);
        *(ushort4*)(out + i) = o;
    }
}

// ---------------------------------------------------------------------------
__global__ __launch_bounds__(256) void tcvt(const float* __restrict__ in,
                                            ushort* __restrict__ out, int R, int C) {
    __shared__ float tile[32][33];
    const int tx = threadIdx.x, ty = threadIdx.y;
    const int c0 = blockIdx.x * 32, r0 = blockIdx.y * 32;
#pragma unroll
    for (int i = 0; i < 4; ++i)
        tile[ty + 8 * i][tx] = in[(size_t)(r0 + ty + 8 * i) * C + c0 + tx];
    __syncthreads();
#pragma unroll
    for (int i = 0; i < 4; ++i)
        out[(size_t)(c0 + ty + 8 * i) * R + r0 + tx] = f2bf(tile[tx][ty + 8 * i]);
}

// ---------------------------------------------------------------------------
__global__ __launch_bounds__(256) void vtrans(const ushort* __restrict__ KV,
                                              ushort* __restrict__ Vt) {
    __shared__ ushort tile[32][34];
    const int tx = threadIdx.x, ty = threadIdx.y;
    const int j0 = blockIdx.x * 32, d0 = blockIdx.y * 32;
#pragma unroll
    for (int i = 0; i < 4; ++i)
        tile[ty + 8 * i][tx] = KV[(size_t)(j0 + ty + 8 * i) * 2048 + 1024 + d0 + tx];
    __syncthreads();
#pragma unroll
    for (int i = 0; i < 4; ++i)
        Vt[(size_t)(d0 + ty + 8 * i) * 4096 + j0 + tx] = tile[tx][ty + 8 * i];
}

// ---------------------------------------------------------------------------
// GEMM: C[M][N] = epilogue( A[M][K] * Bt[N][K]^T + bias ), bf16 in.
// ---------------------------------------------------------------------------
template <int BM, int BN, int ACT, int OUTF32, int RES, int SCALED, int SPLITK>
__global__ __launch_bounds__(256) void gemm_bt(
    const ushort* __restrict__ A, int lda, const ushort* __restrict__ Bt, int ldb,
    const float* __restrict__ bias, const float* __restrict__ resid,
    void* __restrict__ Cout, int M, int N, int K, float scale) {
    constexpr int MR = BM / 32, NR = BN / 32;
    __shared__ __align__(16) ushort Asm[BM * 64];
    __shared__ __align__(16) ushort Bsm[BN * 64];
    const int tid = threadIdx.x;
    const int w = tid >> 6, lane = tid & 63, g = lane >> 4, i15 = lane & 15;
    const int wm = w >> 1, wn = w & 1;
    const int m0 = blockIdx.y * BM, n0 = blockIdx.x * BN;
    if (SPLITK) {
        A += (size_t)blockIdx.z * K;
        Bt += (size_t)blockIdx.z * K;
    }

    f32x4 acc[MR][NR] = {};

    for (int kt = 0; kt < K; kt += 64) {
#pragma unroll
        for (int q = 0; q < BM / 32; ++q) {
            int off = (w * (BM / 32) + q) * 1024 + lane * 16;
            int r = off >> 7, cb = off & 127;
            int scb = cb ^ ((r & 7) << 4);
            const void* src = (const char*)A + ((size_t)(m0 + r) * lda + kt) * 2 + scb;
            gload16(src, (char*)Asm + (w * (BM / 32) + q) * 1024);
        }
#pragma unroll
        for (int q = 0; q < BN / 32; ++q) {
            int off = (w * (BN / 32) + q) * 1024 + lane * 16;
            int r = off >> 7, cb = off & 127;
            int scb = cb ^ ((r & 7) << 4);
            const void* src = (const char*)Bt + ((size_t)(n0 + r) * ldb + kt) * 2 + scb;
            gload16(src, (char*)Bsm + (w * (BN / 32) + q) * 1024);
        }
        __syncthreads();

#pragma unroll
        for (int kc = 0; kc < 2; ++kc) {
            bf16x8 af[MR], bfr[NR];
#pragma unroll
            for (int mi = 0; mi < MR; ++mi) {
                int r = wm * (BM / 2) + mi * 16 + i15;
                af[mi] = *(const bf16x8*)((const char*)Asm + r * 128 +
                                          ((kc * 64 + g * 16) ^ ((r & 7) << 4)));
            }
#pragma unroll
            for (int ni = 0; ni < NR; ++ni) {
                int r = wn * (BN / 2) + ni * 16 + i15;
                bfr[ni] = *(const bf16x8*)((const char*)Bsm + r * 128 +
                                           ((kc * 64 + g * 16) ^ ((r & 7) << 4)));
            }
#pragma unroll
            for (int mi = 0; mi < MR; ++mi)
#pragma unroll
                for (int ni = 0; ni < NR; ++ni)
                    acc[mi][ni] = __builtin_amdgcn_mfma_f32_16x16x32_bf16(
                        af[mi], bfr[ni], acc[mi][ni], 0, 0, 0);
        }
        __syncthreads();
    }

    float* Cf = (float*)Cout;
    if (SPLITK) Cf += (size_t)blockIdx.z * M * N;

#pragma unroll
    for (int ni = 0; ni < NR; ++ni) {
        int col = n0 + wn * (BN / 2) + ni * 16 + i15;
        float bb = bias ? bias[col] : 0.f;
#pragma unroll
        for (int mi = 0; mi < MR; ++mi) {
#pragma unroll
            for (int r2 = 0; r2 < 4; ++r2) {
                int row = m0 + wm * (BM / 2) + mi * 16 + 4 * g + r2;
                float v = acc[mi][ni][r2] + bb;
                if (ACT) v = gelu_erf(v);
                if (SCALED) v *= scale;
                size_t off = (size_t)row * N + col;
                if (OUTF32) {
                    float rv = RES ? resid[off] : 0.f;
                    Cf[off] = v + rv;
                } else {
                    ((ushort*)Cout)[off] = f2bf(v);
                }
            }
        }
    }
}

// ---------------------------------------------------------------------------
// Flash attention v4: 32x32x16 MFMA, lane-local softmax (S^T = K*Q^T),
// P^T built in-register (cvt_pk + permlane32_swap), O^T = V^T*P^T.
// K/V staged once per block into double-buffered LDS via global_load_lds
// (pre-swizzled source, linear dest), ONE barrier per tile.
// Block = 128 q-rows (4 waves x 32) x head h; NS-way KV split -> f32 partials.
// ---------------------------------------------------------------------------
template <int NS>
__global__ __launch_bounds__(256) void flash_attn3(
    const ushort* __restrict__ Q,    // [2048][1024] bf16 (pre-scaled 0.125*log2e)
    const ushort* __restrict__ KVb,  // [4096][2048] bf16 (K = cols 0..1023)
    const ushort* __restrict__ Vt,   // [1024][4096] bf16
    ushort* __restrict__ O,          // NS==1: [2048][1024] bf16
    float* __restrict__ Opart,       // NS>1: [NS][2048][1024] f32
    float* __restrict__ Ml) {        // NS>1: [NS][2048][16][2] f32
    __shared__ __align__(16) ushort Ksm[2][64 * 64];   // [j][d] swizzled rows
    __shared__ __align__(16) ushort Vsm[2][64 * 64];   // [d][j] swizzled rows

    const int tid = threadIdx.x;
    const int w = tid >> 6, lane = tid & 63;
    const int i31 = lane & 31, hig = lane >> 5;
    const int bid = blockIdx.x;
    const int h = bid & 15;                    // bid%8 == h%8 -> same-head same-XCD
    const int qB = 15 - ((bid >> 4) & 15);     // heavy q-blocks first
    const int s = bid >> 8;
    const int qb = qB * 128 + w * 32;
    const int qrow = qb + i31;
    const int diagW = qb >> 6;                 // wave's first masked self tile
    const int diagB = qB * 2 + 1;              // block's last self tile
    const int nt = diagB + 33;                 // block-uniform tile count
    const int lo = (s * nt) / NS;
    const int hi = ((s + 1) * nt) / NS;

    bf16x8 qf[4];
    {
        const ushort* qp = Q + (size_t)qrow * 1024 + h * 64 + hig * 8;
#pragma unroll
        for (int ks = 0; ks < 4; ++ks) qf[ks] = *(const bf16x8*)(qp + ks * 16);
    }

    // staging: 64x64 bf16 tile = 8KB = 256 thr x 2 chunks x 16B, swizzled src
    const int r0s = tid >> 3;                  // 0..31
    const int cb  = (tid & 7) * 16;
    const int swz = cb ^ ((r0s & 7) << 4);     // (r0s+32)&7 == r0s&7
    const char* ksrc0 = (const char*)KVb + h * 128 + (size_t)r0s * 4096 + swz;
    const char* vsrc0 = (const char*)Vt + (size_t)(h * 64 + r0s) * 8192 + swz;

    auto jt_of = [&](int t) { return (t <= diagB) ? t : (32 + (t - diagB - 1)); };
    auto stage = [&](int buf, int jt) {
        char* kd = (char*)Ksm[buf] + tid * 16;
        char* vd = (char*)Vsm[buf] + tid * 16;
        const char* ks_ = ksrc0 + (size_t)jt * 64 * 4096;
        const char* vs_ = vsrc0 + (size_t)jt * 128;
        gload16(ks_, kd);
        gload16(ks_ + (size_t)32 * 4096, kd + 4096);
        gload16(vs_, vd);
        gload16(vs_ + (size_t)32 * 8192, vd + 4096);
    };

    f32x16 o0 = {}, o1 = {};
    float m_run = -INFINITY, l_run = 0.f;

    stage(0, jt_of(lo));
    __syncthreads();
    int cur = 0;

    const int swk = (i31 & 7) << 4;            // frag-row swizzle (row = *32 + i31)

    for (int t = lo; t < hi; ++t) {
        const int jt = jt_of(t);
        if (t + 1 < hi) stage(cur ^ 1, jt_of(t + 1));

        // S^T = K * Q^T  (lane owns softmax row i = i31; rows j in regs)
        f32x16 s0 = {}, s1 = {};
#pragma unroll
        for (int ks = 0; ks < 4; ++ks) {
            bf16x8 ka = *(const bf16x8*)((const char*)Ksm[cur] + i31 * 128 +
                                         ((ks * 32 + hig * 16) ^ swk));
            s0 = mfma32(ka, qf[ks], s0);
        }
#pragma unroll
        for (int ks = 0; ks < 4; ++ks) {
            bf16x8 ka = *(const bf16x8*)((const char*)Ksm[cur] + (32 + i31) * 128 +
                                         ((ks * 32 + hig * 16) ^ swk));
            s1 = mfma32(ka, qf[ks], s1);
        }

        if (jt >= diagW && jt < 32) {
            const int jb = jt * 64;
#pragma unroll
            for (int r = 0; r < 16; ++r) {
                int jl = (r & 3) + 8 * (r >> 2) + 4 * hig;
                if (jb + jl > qrow) s0[r] = -50000.f;
                if (jb + 32 + jl > qrow) s1[r] = -50000.f;
            }
        }

        // per-lane row max
        float mt = -INFINITY;
#pragma unroll
        for (int r = 0; r < 16; ++r) mt = fmaxf(mt, fmaxf(s0[r], s1[r]));
        mt = fmaxf(mt, __shfl_xor(mt, 32));

        const bool skip = __all(mt - m_run <= 8.f);   // defer-max
        float mnew, fscale;
        if (skip) { mnew = m_run; fscale = 1.f; }
        else      { mnew = fmaxf(m_run, mt); fscale = exp2f(m_run - mnew); }

        float psum = 0.f;
#pragma unroll
        for (int r = 0; r < 16; ++r) {
            s0[r] = exp2f(s0[r] - mnew);
            s1[r] = exp2f(s1[r] - mnew);
            psum += s0[r] + s1[r];
        }
        psum += __shfl_xor(psum, 32);
        l_run = l_run * fscale + psum;
        m_run = mnew;

        if (!skip) {
#pragma unroll
            for (int r = 0; r < 16; ++r) { o0[r] *= fscale; o1[r] *= fscale; }
        }

        // build P^T frags and accumulate O^T += V^T P^T
#pragma unroll
        for (int t4 = 0; t4 < 4; ++t4) {
            const int r0 = 8 * (t4 & 1);
            uint w0, w1, w2, w3;
            if (t4 < 2) {
                w0 = cvtpk(s0[r0 + 0], s0[r0 + 1]);
                w1 = cvtpk(s0[r0 + 2], s0[r0 + 3]);
                w2 = cvtpk(s0[r0 + 4], s0[r0 + 5]);
                w3 = cvtpk(s0[r0 + 6], s0[r0 + 7]);
            } else {
                w0 = cvtpk(s1[r0 + 0], s1[r0 + 1]);
                w1 = cvtpk(s1[r0 + 2], s1[r0 + 3]);
                w2 = cvtpk(s1[r0 + 4], s1[r0 + 5]);
                w3 = cvtpk(s1[r0 + 6], s1[r0 + 7]);
            }
            asm volatile("v_permlane32_swap_b32 %0, %1" : "+v"(w0), "+v"(w2));
            asm volatile("v_permlane32_swap_b32 %0, %1" : "+v"(w1), "+v"(w3));
            uint4 pw; pw.x = w0; pw.y = w1; pw.z = w2; pw.w = w3;
            bf16x8 pfr = *(bf16x8*)&pw;
            bf16x8 va = *(const bf16x8*)((const char*)Vsm[cur] + i31 * 128 +
                                         ((t4 * 32 + hig * 16) ^ swk));
            bf16x8 vb = *(const bf16x8*)((const char*)Vsm[cur] + (32 + i31) * 128 +
                                         ((t4 * 32 + hig * 16) ^ swk));
            o0 = mfma32(va, pfr, o0);
            o1 = mfma32(vb, pfr, o1);
        }

        __syncthreads();                     // one barrier per tile
        cur ^= 1;
    }

    if (NS == 1) {
        float inv = 1.f / l_run;
#pragma unroll
        for (int ds = 0; ds < 2; ++ds)
#pragma unroll
            for (int q = 0; q < 4; ++q) {
                float v0 = (ds ? o1[4 * q + 0] : o0[4 * q + 0]) * inv;
                float v1 = (ds ? o1[4 * q + 1] : o0[4 * q + 1]) * inv;
                float v2 = (ds ? o1[4 * q + 2] : o0[4 * q + 2]) * inv;
                float v3 = (ds ? o1[4 * q + 3] : o0[4 * q + 3]) * inv;
                uint2 pk; pk.x = cvtpk(v0, v1); pk.y = cvtpk(v2, v3);
                int col = h * 64 + ds * 32 + 8 * q + 4 * hig;
                *(uint2*)(O + (size_t)qrow * 1024 + col) = pk;
            }
    } else {
        if (hig == 0) {
            float* mp = Ml + ((size_t)(s * 2048 + qrow) * 16 + h) * 2;
            mp[0] = m_run; mp[1] = l_run;
        }
#pragma unroll
        for (int ds = 0; ds < 2; ++ds)
#pragma unroll
            for (int q = 0; q < 4; ++q) {
                float4 v;
                v.x = ds ? o1[4 * q + 0] : o0[4 * q + 0];
                v.y = ds ? o1[4 * q + 1] : o0[4 * q + 1];
                v.z = ds ? o1[4 * q + 2] : o0[4 * q + 2];
                v.w = ds ? o1[4 * q + 3] : o0[4 * q + 3];
                int col = h * 64 + ds * 32 + 8 * q + 4 * hig;
                *(float4*)(Opart + (size_t)(s * 2048 + qrow) * 1024 + col) = v;
            }
    }
}

// ---------------------------------------------------------------------------
template <int NS>
__global__ __launch_bounds__(256) void attn_combine(
    const float* __restrict__ Opart, const float* __restrict__ Ml,
    ushort* __restrict__ O) {
    const int row = blockIdx.x, tid = threadIdx.x;
    const int c = tid * 4, h = c >> 6;
    float ms[NS], ls[NS];
#pragma unroll
    for (int s = 0; s < NS; ++s) {
        const float* mp = Ml + ((size_t)(s * 2048 + row) * 16 + h) * 2;
        ms[s] = mp[0]; ls[s] = mp[1];
    }
    float m = ms[0];
#pragma unroll
    for (int s = 1; s < NS; ++s) m = fmaxf(m, ms[s]);
    float denom = 0.f, wgt[NS];
#pragma unroll
    for (int s = 0; s < NS; ++s) { wgt[s] = exp2f(ms[s] - m); denom += ls[s] * wgt[s]; }
    const float inv = 1.f / denom;
    float ax = 0, ay = 0, az = 0, aw = 0;
#pragma unroll
    for (int s = 0; s < NS; ++s) {
        float4 a = *(const float4*)(Opart + (size_t)(s * 2048 + row) * 1024 + c);
        ax += a.x * wgt[s]; ay += a.y * wgt[s]; az += a.z * wgt[s]; aw += a.w * wgt[s];
    }
    ushort4 ob;
    ob.x = f2bf(ax * inv); ob.y = f2bf(ay * inv);
    ob.z = f2bf(az * inv); ob.w = f2bf(aw * inv);
    *(ushort4*)(O + (size_t)row * 1024 + c) = ob;
}

// ---------------------------------------------------------------------------
__global__ __launch_bounds__(256) void layernorm_k(
    const float* __restrict__ in, const float* __restrict__ gam,
    const float* __restrict__ bet, float* __restrict__ outf,
    ushort* __restrict__ outb) {
    const int row = blockIdx.x, tid = threadIdx.x;
    const float4 v = *(const float4*)(in + (size_t)row * 1024 + tid * 4);
    float s = v.x + v.y + v.z + v.w;
    float sq = v.x * v.x + v.y * v.y + v.z * v.z + v.w * v.w;
#pragma unroll
    for (int d = 1; d < 64; d <<= 1) {
        s += __shfl_xor(s, d);
        sq += __shfl_xor(sq, d);
    }
    __shared__ float red[8];
    const int w = tid >> 6;
    if ((tid & 63) == 0) { red[w] = s; red[4 + w] = sq; }
    __syncthreads();
    s = red[0] + red[1] + red[2] + red[3];
    sq = red[4] + red[5] + red[6] + red[7];
    const float mu = s * (1.f / 1024.f);
    const float rs = rsqrtf(sq * (1.f / 1024.f) - mu * mu + 1e-5f);
    const float4 gg = *(const float4*)(gam + tid * 4);
    const float4 bb = *(const float4*)(bet + tid * 4);
    float4 o;
    o.x = (v.x - mu) * rs * gg.x + bb.x;
    o.y = (v.y - mu) * rs * gg.y + bb.y;
    o.z = (v.z - mu) * rs * gg.z + bb.z;
    o.w = (v.w - mu) * rs * gg.w + bb.w;
    *(float4*)(outf + (size_t)row * 1024 + tid * 4) = o;
    if (outb) {
        ushort4 ob;
        ob.x = f2bf(o.x); ob.y = f2bf(o.y); ob.z = f2bf(o.z); ob.w = f2bf(o.w);
        *(ushort4*)(outb + (size_t)row * 1024 + tid * 4) = ob;
    }
}

// ---------------------------------------------------------------------------
__global__ __launch_bounds__(256) void layernorm_comb(
    const float* __restrict__ in0, const float* __restrict__ in1,
    const float* __restrict__ bias, const float* __restrict__ resid,
    const float* __restrict__ gam, const float* __restrict__ bet,
    float* __restrict__ outf) {
    const int row = blockIdx.x, tid = threadIdx.x;
    const float4 a = *(const float4*)(in0 + (size_t)row * 1024 + tid * 4);
    const float4 b = *(const float4*)(in1 + (size_t)row * 1024 + tid * 4);
    const float4 rr = *(const float4*)(resid + (size_t)row * 1024 + tid * 4);
    const float4 bs = *(const float4*)(bias + tid * 4);
    float4 v;
    v.x = a.x + b.x + rr.x + bs.x;
    v.y = a.y + b.y + rr.y + bs.y;
    v.z = a.z + b.z + rr.z + bs.z;
    v.w = a.w + b.w + rr.w + bs.w;
    float s = v.x + v.y + v.z + v.w;
    float sq = v.x * v.x + v.y * v.y + v.z * v.z + v.w * v.w;
#pragma unroll
    for (int d = 1; d < 64; d <<= 1) {
        s += __shfl_xor(s, d);
        sq += __shfl_xor(sq, d);
    }
    __shared__ float red[8];
    const int w = tid >> 6;
    if ((tid & 63) == 0) { red[w] = s; red[4 + w] = sq; }
    __syncthreads();
    s = red[0] + red[1] + red[2] + red[3];
    sq = red[4] + red[5] + red[6] + red[7];
    const float mu = s * (1.f / 1024.f);
    const float rs = rsqrtf(sq * (1.f / 1024.f) - mu * mu + 1e-5f);
    const float4 gg = *(const float4*)(gam + tid * 4);
    const float4 bb = *(const float4*)(bet + tid * 4);
    float4 o;
    o.x = (v.x - mu) * rs * gg.x + bb.x;
    o.y = (v.y - mu) * rs * gg.y + bb.y;
    o.z = (v.z - mu) * rs * gg.z + bb.z;
    o.w = (v.w - mu) * rs * gg.w + bb.w;
    *(float4*)(outf + (size_t)row * 1024 + tid * 4) = o;
}

// ---------------------------------------------------------------------------
extern "C" void kernel_launch(void* const* d_in, const int* in_sizes, int n_in,
                              void* d_out, int out_size, void* d_ws, size_t ws_size,
                              hipStream_t stream) {
    const float* x    = (const float*)d_in[0];
    const float* ctx  = (const float*)d_in[1];
    const float* Wq   = (const float*)d_in[2];
    const float* bq   = (const float*)d_in[3];
    const float* Wkv  = (const float*)d_in[4];
    const float* bkv  = (const float*)d_in[5];
    const float* Wo   = (const float*)d_in[6];
    const float* bo   = (const float*)d_in[7];
    const float* g1   = (const float*)d_in[8];
    const float* b1   = (const float*)d_in[9];
    const float* W1   = (const float*)d_in[10];
    const float* bf1  = (const float*)d_in[11];
    const float* W2   = (const float*)d_in[12];
    const float* bf2  = (const float*)d_in[13];
    const float* g2   = (const float*)d_in[14];
    const float* b2   = (const float*)d_in[15];

    char* ws = (char*)d_ws;
    const size_t MB = 1u << 20;
    ushort* XCb  = (ushort*)(ws + 0);        // 8MB; later FFN2 partials P0/P1
    ushort* WoT  = (ushort*)(ws + 8 * MB);   // 2MB
    ushort* W1T  = (ushort*)(ws + 10 * MB);  // 8MB
    ushort* W2T  = (ushort*)(ws + 18 * MB);  // 8MB
    ushort* WqT  = (ushort*)(ws + 26 * MB);  // 2MB; later x1b
    ushort* WkvT = (ushort*)(ws + 28 * MB);  // 4MB
    ushort* Qs   = (ushort*)(ws + 32 * MB);  // 4MB; later x1f
    ushort* attn = (ushort*)(ws + 36 * MB);  // 4MB
    ushort* KV   = (ushort*)(ws + 40 * MB);  // 16MB; later ff
    ushort* Vt   = (ushort*)(ws + 56 * MB);  // 8MB; later y1
    ushort* x1b  = (ushort*)(ws + 26 * MB);  // 4MB
    float*  x1f  = (float*)(ws + 32 * MB);   // 8MB
    ushort* ffb  = (ushort*)(ws + 40 * MB);  // 16MB
    float*  y1   = (float*)(ws + 56 * MB);   // 8MB
    float*  Pk   = (float*)(ws + 0);         // 16MB: FFN2 split-K partials
    float*  Opart = (float*)(ws + 64 * MB);  // NS*8MB: attn split partials

    cvt4<<<2048, 256, 0, stream>>>(x, XCb, 2048 * 1024);
    cvt4<<<2048, 256, 0, stream>>>(ctx, XCb + 2048 * 1024, 2048 * 1024);
    tcvt<<<dim3(32, 32), dim3(32, 8), 0, stream>>>(Wq, WqT, 1024, 1024);
    tcvt<<<dim3(64, 32), dim3(32, 8), 0, stream>>>(Wkv, WkvT, 1024, 2048);
    tcvt<<<dim3(32, 32), dim3(32, 8), 0, stream>>>(Wo, WoT, 1024, 1024);
    tcvt<<<dim3(128, 32), dim3(32, 8), 0, stream>>>(W1, W1T, 1024, 4096);
    tcvt<<<dim3(32, 128), dim3(32, 8), 0, stream>>>(W2, W2T, 4096, 1024);
    // Q = (x@Wq + bq) * 0.125 * log2(e)
    gemm_bt<64, 64, 0, 0, 0, 1, 0><<<dim3(16, 32), 256, 0, stream>>>(
        XCb, 1024, WqT, 1024, bq, nullptr, Qs, 2048, 1024, 1024, 0.18033688011112042f);
    gemm_bt<128, 128, 0, 0, 0, 0, 0><<<dim3(16, 32), 256, 0, stream>>>(
        XCb, 1024, WkvT, 1024, bkv, nullptr, KV, 4096, 2048, 1024, 1.f);
    vtrans<<<dim3(128, 32), dim3(32, 8), 0, stream>>>(KV, Vt);

    const size_t need4 = 64 * MB + 4 * 8 * MB + 4 * 2048 * 16 * 2 * 4;
    const size_t need2 = 64 * MB + 2 * 8 * MB + 2 * 2048 * 16 * 2 * 4;
    if (ws_size >= need4) {
        float* Ml = Opart + (size_t)4 * 2048 * 1024;
        flash_attn3<4><<<1024, 256, 0, stream>>>(Qs, KV, Vt, nullptr, Opart, Ml);
        attn_combine<4><<<2048, 256, 0, stream>>>(Opart, Ml, attn);
    } else if (ws_size >= need2) {
        float* Ml = Opart + (size_t)2 * 2048 * 1024;
        flash_attn3<2><<<512, 256, 0, stream>>>(Qs, KV, Vt, nullptr, Opart, Ml);
        attn_combine<2><<<2048, 256, 0, stream>>>(Opart, Ml, attn);
    } else {
        flash_attn3<1><<<256, 256, 0, stream>>>(Qs, KV, Vt, attn, nullptr, nullptr);
    }

    gemm_bt<64, 64, 0, 1, 1, 0, 0><<<dim3(16, 32), 256, 0, stream>>>(
        attn, 1024, WoT, 1024, bo, x, y1, 2048, 1024, 1024, 1.f);
    layernorm_k<<<2048, 256, 0, stream>>>(y1, g1, b1, x1f, x1b);
    gemm_bt<128, 128, 1, 0, 0, 0, 0><<<dim3(32, 16), 256, 0, stream>>>(
        x1b, 1024, W1T, 1024, bf1, nullptr, ffb, 2048, 4096, 1024, 1.f);
    gemm_bt<64, 64, 0, 1, 0, 0, 1><<<dim3(16, 32, 2), 256, 0, stream>>>(
        ffb, 4096, W2T, 4096, nullptr, nullptr, Pk, 2048, 1024, 2048, 1.f);
    layernorm_comb<<<2048, 256, 0, stream>>>(Pk, Pk + 2048 * 1024, bf2, x1f,
                                             g2, b2, (float*)d_out);
}

// Round 6
// 234.512 us; speedup vs baseline: 1.1815x; 1.0131x over previous
//
#include <hip/hip_runtime.h>

// ---------------------------------------------------------------------------
// TransformerDecoderBlockV2: bf16 MFMA implementation for gfx950
// B=1, N=2048, M=2048, D=1024, H=16, dh=64, DFF=4096
// ---------------------------------------------------------------------------

using bf16x8 = __attribute__((ext_vector_type(8))) short;
using f32x4  = __attribute__((ext_vector_type(4))) float;

__device__ __forceinline__ ushort f2bf(float f) {
    unsigned u = __float_as_uint(f);
    unsigned r = (u + 0x7fffu + ((u >> 16) & 1u)) >> 16;
    return (ushort)r;
}

__device__ __forceinline__ void gload16(const void* g, void* l) {
    __builtin_amdgcn_global_load_lds(
        (const __attribute__((address_space(1))) void*)g,
        (__attribute__((address_space(3))) void*)l, 16, 0, 0);
}

__device__ __forceinline__ float gelu_erf(float v) {
    return 0.5f * v * (1.0f + erff(v * 0.70710678118654752f));
}

__device__ __forceinline__ uint cvtpk(float a, float b) {
    uint r;
    asm("v_cvt_pk_bf16_f32 %0, %1, %2" : "=v"(r) : "v"(a), "v"(b));
    return r;
}

// ---------------------------------------------------------------------------
__global__ __launch_bounds__(256) void cvt4(const float* __restrict__ in,
                                            ushort* __restrict__ out, int n) {
    int i = (blockIdx.x * 256 + threadIdx.x) * 4;
    if (i + 3 < n) {
        float4 v = *(const float4*)(in + i);
        ushort4 o;
        o.x = f2bf(v.x); o.y = f2bf(v.y); o.z = f2bf(v.z); o.w = f2bf(v.w);
        *(ushort4*)(out + i) = o;
    }
}

// ---------------------------------------------------------------------------
__global__ __launch_bounds__(256) void tcvt(const float* __restrict__ in,
                                            ushort* __restrict__ out, int R, int C) {
    __shared__ float tile[32][33];
    const int tx = threadIdx.x, ty = threadIdx.y;
    const int c0 = blockIdx.x * 32, r0 = blockIdx.y * 32;
#pragma unroll
    for (int i = 0; i < 4; ++i)
        tile[ty + 8 * i][tx] = in[(size_t)(r0 + ty + 8 * i) * C + c0 + tx];
    __syncthreads();
#pragma unroll
    for (int i = 0; i < 4; ++i)
        out[(size_t)(c0 + ty + 8 * i) * R + r0 + tx] = f2bf(tile[tx][ty + 8 * i]);
}

// ---------------------------------------------------------------------------
__global__ __launch_bounds__(256) void vtrans(const ushort* __restrict__ KV,
                                              ushort* __restrict__ Vt) {
    __shared__ ushort tile[32][34];
    const int tx = threadIdx.x, ty = threadIdx.y;
    const int j0 = blockIdx.x * 32, d0 = blockIdx.y * 32;
#pragma unroll
    for (int i = 0; i < 4; ++i)
        tile[ty + 8 * i][tx] = KV[(size_t)(j0 + ty + 8 * i) * 2048 + 1024 + d0 + tx];
    __syncthreads();
#pragma unroll
    for (int i = 0; i < 4; ++i)
        Vt[(size_t)(d0 + ty + 8 * i) * 4096 + j0 + tx] = tile[tx][ty + 8 * i];
}

// ---------------------------------------------------------------------------
// GEMM: C[M][N] = epilogue( A[M][K] * Bt[N][K]^T + bias ), bf16 in.
// 128x128 = m97-class structure (874 TF); SPLITK via blockIdx.z, f32 partials.
// ---------------------------------------------------------------------------
template <int BM, int BN, int ACT, int OUTF32, int RES, int SCALED, int SPLITK>
__global__ __launch_bounds__(256) void gemm_bt(
    const ushort* __restrict__ A, int lda, const ushort* __restrict__ Bt, int ldb,
    const float* __restrict__ bias, const float* __restrict__ resid,
    void* __restrict__ Cout, int M, int N, int K, float scale) {
    constexpr int MR = BM / 32, NR = BN / 32;
    __shared__ __align__(16) ushort Asm[BM * 64];
    __shared__ __align__(16) ushort Bsm[BN * 64];
    const int tid = threadIdx.x;
    const int w = tid >> 6, lane = tid & 63, g = lane >> 4, i15 = lane & 15;
    const int wm = w >> 1, wn = w & 1;
    const int m0 = blockIdx.y * BM, n0 = blockIdx.x * BN;
    if (SPLITK) {
        A += (size_t)blockIdx.z * K;
        Bt += (size_t)blockIdx.z * K;
    }

    f32x4 acc[MR][NR] = {};

    for (int kt = 0; kt < K; kt += 64) {
#pragma unroll
        for (int q = 0; q < BM / 32; ++q) {
            int off = (w * (BM / 32) + q) * 1024 + lane * 16;
            int r = off >> 7, cb = off & 127;
            int scb = cb ^ ((r & 7) << 4);
            const void* src = (const char*)A + ((size_t)(m0 + r) * lda + kt) * 2 + scb;
            gload16(src, (char*)Asm + (w * (BM / 32) + q) * 1024);
        }
#pragma unroll
        for (int q = 0; q < BN / 32; ++q) {
            int off = (w * (BN / 32) + q) * 1024 + lane * 16;
            int r = off >> 7, cb = off & 127;
            int scb = cb ^ ((r & 7) << 4);
            const void* src = (const char*)Bt + ((size_t)(n0 + r) * ldb + kt) * 2 + scb;
            gload16(src, (char*)Bsm + (w * (BN / 32) + q) * 1024);
        }
        __syncthreads();

#pragma unroll
        for (int kc = 0; kc < 2; ++kc) {
            bf16x8 af[MR], bfr[NR];
#pragma unroll
            for (int mi = 0; mi < MR; ++mi) {
                int r = wm * (BM / 2) + mi * 16 + i15;
                af[mi] = *(const bf16x8*)((const char*)Asm + r * 128 +
                                          ((kc * 64 + g * 16) ^ ((r & 7) << 4)));
            }
#pragma unroll
            for (int ni = 0; ni < NR; ++ni) {
                int r = wn * (BN / 2) + ni * 16 + i15;
                bfr[ni] = *(const bf16x8*)((const char*)Bsm + r * 128 +
                                           ((kc * 64 + g * 16) ^ ((r & 7) << 4)));
            }
#pragma unroll
            for (int mi = 0; mi < MR; ++mi)
#pragma unroll
                for (int ni = 0; ni < NR; ++ni)
                    acc[mi][ni] = __builtin_amdgcn_mfma_f32_16x16x32_bf16(
                        af[mi], bfr[ni], acc[mi][ni], 0, 0, 0);
        }
        __syncthreads();
    }

    float* Cf = (float*)Cout;
    if (SPLITK) Cf += (size_t)blockIdx.z * M * N;

#pragma unroll
    for (int ni = 0; ni < NR; ++ni) {
        int col = n0 + wn * (BN / 2) + ni * 16 + i15;
        float bb = bias ? bias[col] : 0.f;
#pragma unroll
        for (int mi = 0; mi < MR; ++mi) {
#pragma unroll
            for (int r2 = 0; r2 < 4; ++r2) {
                int row = m0 + wm * (BM / 2) + mi * 16 + 4 * g + r2;
                float v = acc[mi][ni][r2] + bb;
                if (ACT) v = gelu_erf(v);
                if (SCALED) v *= scale;
                size_t off = (size_t)row * N + col;
                if (OUTF32) {
                    float rv = RES ? resid[off] : 0.f;
                    Cf[off] = v + rv;
                } else {
                    ((ushort*)Cout)[off] = f2bf(v);
                }
            }
        }
    }
}

// ---------------------------------------------------------------------------
// Flash attention v2 (r3's measured-best) + tree reductions.
// 4 waves x 16 q-rows, KVBLK=64, exp2 space, double-buffered K/V LDS,
// register prefetch, ONE barrier/tile, defer-max.
// SPLIT=1: 2-way KV split; f32 partials + (m,l) merged by attn_combine.
// ---------------------------------------------------------------------------
template <int SPLIT>
__global__ __launch_bounds__(256) void flash_attn(
    const ushort* __restrict__ Q,    // [2048][1024] bf16 (pre-scaled 0.125*log2e)
    const ushort* __restrict__ KVb,  // [4096][2048] bf16 (K = cols 0..1023)
    const ushort* __restrict__ Vt,   // [1024][4096] bf16
    ushort* __restrict__ O,          // SPLIT=0: [2048][1024] bf16
    float* __restrict__ Opart,       // SPLIT=1: [2][2048][1024] f32
    float* __restrict__ Ml) {        // SPLIT=1: [2][2048][16][2] f32
    constexpr int D = 1024;
    __shared__ __align__(16) ushort Ksm[2][64 * 64];
    __shared__ __align__(16) ushort Vsm[2][64 * 64];
    __shared__ __align__(16) ushort Psm[4][16 * 64];   // per-wave, XOR-swizzled

    const int tid = threadIdx.x;
    const int w = tid >> 6, lane = tid & 63, g = lane >> 4, i15 = lane & 15;
    const int bid = blockIdx.x;
    const int h = bid & 15;                 // bid%8 == h%8 -> same-head same-XCD
    int qi, s;
    if (SPLIT) { qi = 31 - ((bid >> 4) >> 1); s = (bid >> 4) & 1; }
    else       { qi = 31 - (bid >> 4); s = 0; }
    const int qb = qi * 64;
    const int qrow = qb + w * 16 + i15;

    bf16x8 qf[2];
    qf[0] = *(const bf16x8*)(Q + (size_t)qrow * D + h * 64 + g * 8);
    qf[1] = *(const bf16x8*)(Q + (size_t)qrow * D + h * 64 + 32 + g * 8);

    f32x4 o[4] = {};
    float m_run = -INFINITY, l_run = 0.f;

    const int diag = qi;
    const int nt = diag + 33;
    const int lo = (SPLIT && s) ? (nt >> 1) : 0;
    const int hi = SPLIT ? (s ? nt : (nt >> 1)) : nt;

    const int sr  = tid >> 3;               // rows 0..31 (and +32)
    const int scb = (tid & 7) * 16;
    const int ssw = scb ^ ((sr & 7) << 4);
    const char* kb0 = (const char*)KVb + ((size_t)sr * 2048 + h * 64) * 2 + scb;
    const char* vb0 = (const char*)Vt + ((size_t)(h * 64 + sr) * 4096) * 2 + scb;

    uint4 kreg0, kreg1, vreg0, vreg1;
    auto jt_of = [&](int t) { return (t <= diag) ? t : (32 + (t - diag - 1)); };
    auto stage = [&](int jt) {
        const char* kb = kb0 + (size_t)jt * 64 * 2048 * 2;
        kreg0 = *(const uint4*)kb;
        kreg1 = *(const uint4*)(kb + 32 * 2048 * 2);
        const char* vb = vb0 + (size_t)jt * 64 * 2;
        vreg0 = *(const uint4*)vb;
        vreg1 = *(const uint4*)(vb + 32 * 4096 * 2);
    };
    auto wlds = [&](int buf) {
        *(uint4*)((char*)Ksm[buf] + sr * 128 + ssw) = kreg0;
        *(uint4*)((char*)Ksm[buf] + (sr + 32) * 128 + ssw) = kreg1;
        *(uint4*)((char*)Vsm[buf] + sr * 128 + ssw) = vreg0;
        *(uint4*)((char*)Vsm[buf] + (sr + 32) * 128 + ssw) = vreg1;
    };

    stage(jt_of(lo));
    wlds(0);
    __syncthreads();
    int cur = 0;

    const int pbase = i15 * 128;            // within Psm[w]
    const int psw = (i15 & 7) << 4;

    for (int t = lo; t < hi; ++t) {
        const int jt = jt_of(t);
        const bool more = (t + 1 < hi);
        if (more) stage(jt_of(t + 1));

        // S^T = K * Q^T
        f32x4 st[4];
#pragma unroll
        for (int jg = 0; jg < 4; ++jg) {
            int jr = jg * 16 + i15;
            bf16x8 ka0 = *(const bf16x8*)((const char*)Ksm[cur] + jr * 128 +
                                          ((g * 16) ^ ((jr & 7) << 4)));
            bf16x8 ka1 = *(const bf16x8*)((const char*)Ksm[cur] + jr * 128 +
                                          ((64 + g * 16) ^ ((jr & 7) << 4)));
            f32x4 z = {};
            z = __builtin_amdgcn_mfma_f32_16x16x32_bf16(ka0, qf[0], z, 0, 0, 0);
            z = __builtin_amdgcn_mfma_f32_16x16x32_bf16(ka1, qf[1], z, 0, 0, 0);
            st[jg] = z;
        }
        if (jt == diag) {
#pragma unroll
            for (int jg = 0; jg < 4; ++jg)
#pragma unroll
                for (int r = 0; r < 4; ++r) {
                    int j = jt * 64 + jg * 16 + 4 * g + r;
                    if (j > qrow) st[jg][r] = -50000.f;
                }
        }

        // row max: 4-deep tree (ILP) instead of 16-deep serial chain
        float v8[8];
#pragma unroll
        for (int jg = 0; jg < 4; ++jg) {
            v8[2 * jg]     = fmaxf(st[jg][0], st[jg][1]);
            v8[2 * jg + 1] = fmaxf(st[jg][2], st[jg][3]);
        }
        v8[0] = fmaxf(v8[0], v8[4]); v8[1] = fmaxf(v8[1], v8[5]);
        v8[2] = fmaxf(v8[2], v8[6]); v8[3] = fmaxf(v8[3], v8[7]);
        float mt = fmaxf(fmaxf(v8[0], v8[1]), fmaxf(v8[2], v8[3]));
        mt = fmaxf(mt, __shfl_xor(mt, 16));
        mt = fmaxf(mt, __shfl_xor(mt, 32));

        const bool skip = __all(mt - m_run <= 8.f);
        float mnew, fscale;
        if (skip) { mnew = m_run; fscale = 1.f; }
        else      { mnew = fmaxf(m_run, mt); fscale = exp2f(m_run - mnew); }

        float pf[4][4], sj[4];
#pragma unroll
        for (int jg = 0; jg < 4; ++jg) {
#pragma unroll
            for (int r = 0; r < 4; ++r) pf[jg][r] = exp2f(st[jg][r] - mnew);
            sj[jg] = (pf[jg][0] + pf[jg][1]) + (pf[jg][2] + pf[jg][3]);
        }
        float psum = (sj[0] + sj[1]) + (sj[2] + sj[3]);
        psum += __shfl_xor(psum, 16);
        psum += __shfl_xor(psum, 32);
        l_run = l_run * fscale + psum;
        m_run = mnew;

        if (!skip) {
#pragma unroll
            for (int r = 0; r < 4; ++r) {
                float fr = __shfl(fscale, 20 * g + r);
#pragma unroll
                for (int dg = 0; dg < 4; ++dg) o[dg][r] *= fr;
            }
        }

        // pack P (cvt_pk) -> per-wave swizzled LDS [16 i][64 j]
#pragma unroll
        for (int jg = 0; jg < 4; ++jg) {
            uint2 pk;
            pk.x = cvtpk(pf[jg][0], pf[jg][1]);
            pk.y = cvtpk(pf[jg][2], pf[jg][3]);
            *(uint2*)((char*)Psm[w] + pbase + ((jg * 32 + g * 8) ^ psw)) = pk;
        }

        // O += P * V
#pragma unroll
        for (int jc = 0; jc < 2; ++jc) {
            bf16x8 pa = *(const bf16x8*)((const char*)Psm[w] + pbase +
                                         ((jc * 64 + g * 16) ^ psw));
#pragma unroll
            for (int dg = 0; dg < 4; ++dg) {
                int dr = dg * 16 + i15;
                bf16x8 vb = *(const bf16x8*)((const char*)Vsm[cur] + dr * 128 +
                                             ((jc * 64 + g * 16) ^ ((dr & 7) << 4)));
                o[dg] = __builtin_amdgcn_mfma_f32_16x16x32_bf16(pa, vb, o[dg], 0, 0, 0);
            }
        }

        if (more) wlds(cur ^ 1);
        __syncthreads();
        cur ^= 1;
    }

    if (SPLIT) {
        if (g == 0) {
            float* mp = Ml + ((size_t)(s * 2048 + qb + w * 16 + i15) * 16 + h) * 2;
            mp[0] = m_run; mp[1] = l_run;
        }
#pragma unroll
        for (int r = 0; r < 4; ++r)
#pragma unroll
            for (int dg = 0; dg < 4; ++dg) {
                int row = qb + w * 16 + 4 * g + r;
                int col = h * 64 + dg * 16 + i15;
                Opart[(size_t)(s * 2048 + row) * 1024 + col] = o[dg][r];
            }
    } else {
#pragma unroll
        for (int r = 0; r < 4; ++r) {
            float lr = __shfl(l_run, 20 * g + r);
            float inv = 1.f / lr;
#pragma unroll
            for (int dg = 0; dg < 4; ++dg) {
                int row = qb + w * 16 + 4 * g + r;
                int col = h * 64 + dg * 16 + i15;
                O[(size_t)row * D + col] = f2bf(o[dg][r] * inv);
            }
        }
    }
}

// ---------------------------------------------------------------------------
__global__ __launch_bounds__(256) void attn_combine(
    const float* __restrict__ Opart, const float* __restrict__ Ml,
    ushort* __restrict__ O) {
    const int row = blockIdx.x, tid = threadIdx.x;
    const int c = tid * 4, h = c >> 6;
    const float* mp0 = Ml + ((size_t)row * 16 + h) * 2;
    const float* mp1 = Ml + ((size_t)(2048 + row) * 16 + h) * 2;
    float m0 = mp0[0], l0 = mp0[1], m1 = mp1[0], l1 = mp1[1];
    float m = fmaxf(m0, m1);
    float w0 = exp2f(m0 - m), w1 = exp2f(m1 - m);
    float inv = 1.f / (l0 * w0 + l1 * w1);
    float4 a = *(const float4*)(Opart + (size_t)row * 1024 + c);
    float4 b = *(const float4*)(Opart + (size_t)(2048 + row) * 1024 + c);
    ushort4 ob;
    ob.x = f2bf((a.x * w0 + b.x * w1) * inv);
    ob.y = f2bf((a.y * w0 + b.y * w1) * inv);
    ob.z = f2bf((a.z * w0 + b.z * w1) * inv);
    ob.w = f2bf((a.w * w0 + b.w * w1) * inv);
    *(ushort4*)(O + (size_t)row * 1024 + c) = ob;
}

// ---------------------------------------------------------------------------
__global__ __launch_bounds__(256) void layernorm_k(
    const float* __restrict__ in, const float* __restrict__ gam,
    const float* __restrict__ bet, float* __restrict__ outf,
    ushort* __restrict__ outb) {
    const int row = blockIdx.x, tid = threadIdx.x;
    const float4 v = *(const float4*)(in + (size_t)row * 1024 + tid * 4);
    float s = v.x + v.y + v.z + v.w;
    float sq = v.x * v.x + v.y * v.y + v.z * v.z + v.w * v.w;
#pragma unroll
    for (int d = 1; d < 64; d <<= 1) {
        s += __shfl_xor(s, d);
        sq += __shfl_xor(sq, d);
    }
    __shared__ float red[8];
    const int w = tid >> 6;
    if ((tid & 63) == 0) { red[w] = s; red[4 + w] = sq; }
    __syncthreads();
    s = red[0] + red[1] + red[2] + red[3];
    sq = red[4] + red[5] + red[6] + red[7];
    const float mu = s * (1.f / 1024.f);
    const float rs = rsqrtf(sq * (1.f / 1024.f) - mu * mu + 1e-5f);
    const float4 gg = *(const float4*)(gam + tid * 4);
    const float4 bb = *(const float4*)(bet + tid * 4);
    float4 o;
    o.x = (v.x - mu) * rs * gg.x + bb.x;
    o.y = (v.y - mu) * rs * gg.y + bb.y;
    o.z = (v.z - mu) * rs * gg.z + bb.z;
    o.w = (v.w - mu) * rs * gg.w + bb.w;
    *(float4*)(outf + (size_t)row * 1024 + tid * 4) = o;
    if (outb) {
        ushort4 ob;
        ob.x = f2bf(o.x); ob.y = f2bf(o.y); ob.z = f2bf(o.z); ob.w = f2bf(o.w);
        *(ushort4*)(outb + (size_t)row * 1024 + tid * 4) = ob;
    }
}

// ---------------------------------------------------------------------------
// Final LN over (sum of NP split-K partials + bias + resid)
// ---------------------------------------------------------------------------
template <int NP>
__global__ __launch_bounds__(256) void layernorm_comb(
    const float* __restrict__ P,
    const float* __restrict__ bias, const float* __restrict__ resid,
    const float* __restrict__ gam, const float* __restrict__ bet,
    float* __restrict__ outf) {
    const int row = blockIdx.x, tid = threadIdx.x;
    const float4 rr = *(const float4*)(resid + (size_t)row * 1024 + tid * 4);
    const float4 bs = *(const float4*)(bias + tid * 4);
    float4 v;
    v.x = rr.x + bs.x; v.y = rr.y + bs.y; v.z = rr.z + bs.z; v.w = rr.w + bs.w;
#pragma unroll
    for (int p = 0; p < NP; ++p) {
        const float4 a = *(const float4*)(P + (size_t)(p * 2048 + row) * 1024 + tid * 4);
        v.x += a.x; v.y += a.y; v.z += a.z; v.w += a.w;
    }
    float s = v.x + v.y + v.z + v.w;
    float sq = v.x * v.x + v.y * v.y + v.z * v.z + v.w * v.w;
#pragma unroll
    for (int d = 1; d < 64; d <<= 1) {
        s += __shfl_xor(s, d);
        sq += __shfl_xor(sq, d);
    }
    __shared__ float red[8];
    const int w = tid >> 6;
    if ((tid & 63) == 0) { red[w] = s; red[4 + w] = sq; }
    __syncthreads();
    s = red[0] + red[1] + red[2] + red[3];
    sq = red[4] + red[5] + red[6] + red[7];
    const float mu = s * (1.f / 1024.f);
    const float rs = rsqrtf(sq * (1.f / 1024.f) - mu * mu + 1e-5f);
    const float4 gg = *(const float4*)(gam + tid * 4);
    const float4 bb = *(const float4*)(bet + tid * 4);
    float4 o;
    o.x = (v.x - mu) * rs * gg.x + bb.x;
    o.y = (v.y - mu) * rs * gg.y + bb.y;
    o.z = (v.z - mu) * rs * gg.z + bb.z;
    o.w = (v.w - mu) * rs * gg.w + bb.w;
    *(float4*)(outf + (size_t)row * 1024 + tid * 4) = o;
}

// ---------------------------------------------------------------------------
extern "C" void kernel_launch(void* const* d_in, const int* in_sizes, int n_in,
                              void* d_out, int out_size, void* d_ws, size_t ws_size,
                              hipStream_t stream) {
    const float* x    = (const float*)d_in[0];
    const float* ctx  = (const float*)d_in[1];
    const float* Wq   = (const float*)d_in[2];
    const float* bq   = (const float*)d_in[3];
    const float* Wkv  = (const float*)d_in[4];
    const float* bkv  = (const float*)d_in[5];
    const float* Wo   = (const float*)d_in[6];
    const float* bo   = (const float*)d_in[7];
    const float* g1   = (const float*)d_in[8];
    const float* b1   = (const float*)d_in[9];
    const float* W1   = (const float*)d_in[10];
    const float* bf1  = (const float*)d_in[11];
    const float* W2   = (const float*)d_in[12];
    const float* bf2  = (const float*)d_in[13];
    const float* g2   = (const float*)d_in[14];
    const float* b2   = (const float*)d_in[15];

    char* ws = (char*)d_ws;
    const size_t MB = 1u << 20;
    ushort* XCb  = (ushort*)(ws + 0);        // 8MB; dead after KV gemm
    ushort* WoT  = (ushort*)(ws + 8 * MB);   // 2MB; dead after Wo gemm
    ushort* W1T  = (ushort*)(ws + 10 * MB);  // 8MB; dead after FFN1
    ushort* W2T  = (ushort*)(ws + 18 * MB);  // 8MB
    ushort* WqT  = (ushort*)(ws + 26 * MB);  // 2MB; later x1b
    ushort* WkvT = (ushort*)(ws + 28 * MB);  // 4MB
    ushort* Qs   = (ushort*)(ws + 32 * MB);  // 4MB; later x1f
    ushort* attn = (ushort*)(ws + 36 * MB);  // 4MB
    ushort* KV   = (ushort*)(ws + 40 * MB);  // 16MB; later ff
    ushort* Vt   = (ushort*)(ws + 56 * MB);  // 8MB; later y1
    ushort* x1b  = (ushort*)(ws + 26 * MB);  // 4MB
    float*  x1f  = (float*)(ws + 32 * MB);   // 8MB
    ushort* ffb  = (ushort*)(ws + 40 * MB);  // 16MB
    float*  y1   = (float*)(ws + 56 * MB);   // 8MB
    float*  Opart = (float*)(ws + 64 * MB);  // 16MB attn partials; later Pk
    float*  Ml    = (float*)(ws + 80 * MB);  // 512KB
    float*  Pk4   = (float*)(ws + 64 * MB);  // 32MB FFN2 split-4 partials
    float*  Pk2   = (float*)(ws + 0);        // 16MB FFN2 split-2 fallback

    cvt4<<<2048, 256, 0, stream>>>(x, XCb, 2048 * 1024);
    cvt4<<<2048, 256, 0, stream>>>(ctx, XCb + 2048 * 1024, 2048 * 1024);
    tcvt<<<dim3(32, 32), dim3(32, 8), 0, stream>>>(Wq, WqT, 1024, 1024);
    tcvt<<<dim3(64, 32), dim3(32, 8), 0, stream>>>(Wkv, WkvT, 1024, 2048);
    tcvt<<<dim3(32, 32), dim3(32, 8), 0, stream>>>(Wo, WoT, 1024, 1024);
    tcvt<<<dim3(128, 32), dim3(32, 8), 0, stream>>>(W1, W1T, 1024, 4096);
    tcvt<<<dim3(32, 128), dim3(32, 8), 0, stream>>>(W2, W2T, 4096, 1024);
    // Q = (x@Wq + bq) * 0.125 * log2(e)
    gemm_bt<64, 128, 0, 0, 0, 1, 0><<<dim3(8, 32), 256, 0, stream>>>(
        XCb, 1024, WqT, 1024, bq, nullptr, Qs, 2048, 1024, 1024, 0.18033688011112042f);
    gemm_bt<128, 128, 0, 0, 0, 0, 0><<<dim3(16, 32), 256, 0, stream>>>(
        XCb, 1024, WkvT, 1024, bkv, nullptr, KV, 4096, 2048, 1024, 1.f);
    vtrans<<<dim3(128, 32), dim3(32, 8), 0, stream>>>(KV, Vt);

    const bool split = ws_size >= 81 * MB;
    if (split) {
        flash_attn<1><<<1024, 256, 0, stream>>>(Qs, KV, Vt, nullptr, Opart, Ml);
        attn_combine<<<2048, 256, 0, stream>>>(Opart, Ml, attn);
    } else {
        flash_attn<0><<<512, 256, 0, stream>>>(Qs, KV, Vt, attn, nullptr, nullptr);
    }

    gemm_bt<64, 128, 0, 1, 1, 0, 0><<<dim3(8, 32), 256, 0, stream>>>(
        attn, 1024, WoT, 1024, bo, x, y1, 2048, 1024, 1024, 1.f);
    layernorm_k<<<2048, 256, 0, stream>>>(y1, g1, b1, x1f, x1b);
    gemm_bt<128, 128, 1, 0, 0, 0, 0><<<dim3(32, 16), 256, 0, stream>>>(
        x1b, 1024, W1T, 1024, bf1, nullptr, ffb, 2048, 4096, 1024, 1.f);
    // FFN2: 128x128 split-K, f32 partials merged in final LN
    if (ws_size >= 96 * MB) {
        gemm_bt<128, 128, 0, 1, 0, 0, 1><<<dim3(8, 16, 4), 256, 0, stream>>>(
            ffb, 4096, W2T, 4096, nullptr, nullptr, Pk4, 2048, 1024, 1024, 1.f);
        layernorm_comb<4><<<2048, 256, 0, stream>>>(Pk4, bf2, x1f, g2, b2,
                                                    (float*)d_out);
    } else {
        gemm_bt<128, 128, 0, 1, 0, 0, 1><<<dim3(8, 16, 2), 256, 0, stream>>>(
            ffb, 4096, W2T, 4096, nullptr, nullptr, Pk2, 2048, 1024, 2048, 1.f);
        layernorm_comb<2><<<2048, 256, 0, stream>>>(Pk2, bf2, x1f, g2, b2,
                                                    (float*)d_out);
    }
}

// Round 7
// 234.076 us; speedup vs baseline: 1.1837x; 1.0019x over previous
//
#include <hip/hip_runtime.h>

// ---------------------------------------------------------------------------
// TransformerDecoderBlockV2: bf16 MFMA implementation for gfx950
// B=1, N=2048, M=2048, D=1024, H=16, dh=64, DFF=4096
// ---------------------------------------------------------------------------

using bf16x8 = __attribute__((ext_vector_type(8))) short;
using f32x4  = __attribute__((ext_vector_type(4))) float;

__device__ __forceinline__ ushort f2bf(float f) {
    unsigned u = __float_as_uint(f);
    unsigned r = (u + 0x7fffu + ((u >> 16) & 1u)) >> 16;
    return (ushort)r;
}

__device__ __forceinline__ void gload16(const void* g, void* l) {
    __builtin_amdgcn_global_load_lds(
        (const __attribute__((address_space(1))) void*)g,
        (__attribute__((address_space(3))) void*)l, 16, 0, 0);
}

__device__ __forceinline__ float gelu_erf(float v) {
    return 0.5f * v * (1.0f + erff(v * 0.70710678118654752f));
}

__device__ __forceinline__ uint cvtpk(float a, float b) {
    uint r;
    asm("v_cvt_pk_bf16_f32 %0, %1, %2" : "=v"(r) : "v"(a), "v"(b));
    return r;
}

// ---------------------------------------------------------------------------
__global__ __launch_bounds__(256) void cvt4(const float* __restrict__ in,
                                            ushort* __restrict__ out, int n) {
    int i = (blockIdx.x * 256 + threadIdx.x) * 4;
    if (i + 3 < n) {
        float4 v = *(const float4*)(in + i);
        ushort4 o;
        o.x = f2bf(v.x); o.y = f2bf(v.y); o.z = f2bf(v.z); o.w = f2bf(v.w);
        *(ushort4*)(out + i) = o;
    }
}

// ---------------------------------------------------------------------------
__global__ __launch_bounds__(256) void tcvt(const float* __restrict__ in,
                                            ushort* __restrict__ out, int R, int C) {
    __shared__ float tile[32][33];
    const int tx = threadIdx.x, ty = threadIdx.y;
    const int c0 = blockIdx.x * 32, r0 = blockIdx.y * 32;
#pragma unroll
    for (int i = 0; i < 4; ++i)
        tile[ty + 8 * i][tx] = in[(size_t)(r0 + ty + 8 * i) * C + c0 + tx];
    __syncthreads();
#pragma unroll
    for (int i = 0; i < 4; ++i)
        out[(size_t)(c0 + ty + 8 * i) * R + r0 + tx] = f2bf(tile[tx][ty + 8 * i]);
}

// ---------------------------------------------------------------------------
__global__ __launch_bounds__(256) void vtrans(const ushort* __restrict__ KV,
                                              ushort* __restrict__ Vt) {
    __shared__ ushort tile[32][34];
    const int tx = threadIdx.x, ty = threadIdx.y;
    const int j0 = blockIdx.x * 32, d0 = blockIdx.y * 32;
#pragma unroll
    for (int i = 0; i < 4; ++i)
        tile[ty + 8 * i][tx] = KV[(size_t)(j0 + ty + 8 * i) * 2048 + 1024 + d0 + tx];
    __syncthreads();
#pragma unroll
    for (int i = 0; i < 4; ++i)
        Vt[(size_t)(d0 + ty + 8 * i) * 4096 + j0 + tx] = tile[tx][ty + 8 * i];
}

// ---------------------------------------------------------------------------
// GEMM: C[M][N] = epilogue( A[M][K] * Bt[N][K]^T + bias ), bf16 in.
// 128x128 = m97-class structure; SPLITK via blockIdx.z, f32 partials.
// ---------------------------------------------------------------------------
template <int BM, int BN, int ACT, int OUTF32, int RES, int SCALED, int SPLITK>
__global__ __launch_bounds__(256) void gemm_bt(
    const ushort* __restrict__ A, int lda, const ushort* __restrict__ Bt, int ldb,
    const float* __restrict__ bias, const float* __restrict__ resid,
    void* __restrict__ Cout, int M, int N, int K, float scale) {
    constexpr int MR = BM / 32, NR = BN / 32;
    __shared__ __align__(16) ushort Asm[BM * 64];
    __shared__ __align__(16) ushort Bsm[BN * 64];
    const int tid = threadIdx.x;
    const int w = tid >> 6, lane = tid & 63, g = lane >> 4, i15 = lane & 15;
    const int wm = w >> 1, wn = w & 1;
    const int m0 = blockIdx.y * BM, n0 = blockIdx.x * BN;
    if (SPLITK) {
        A += (size_t)blockIdx.z * K;
        Bt += (size_t)blockIdx.z * K;
    }

    f32x4 acc[MR][NR] = {};

    for (int kt = 0; kt < K; kt += 64) {
#pragma unroll
        for (int q = 0; q < BM / 32; ++q) {
            int off = (w * (BM / 32) + q) * 1024 + lane * 16;
            int r = off >> 7, cb = off & 127;
            int scb = cb ^ ((r & 7) << 4);
            const void* src = (const char*)A + ((size_t)(m0 + r) * lda + kt) * 2 + scb;
            gload16(src, (char*)Asm + (w * (BM / 32) + q) * 1024);
        }
#pragma unroll
        for (int q = 0; q < BN / 32; ++q) {
            int off = (w * (BN / 32) + q) * 1024 + lane * 16;
            int r = off >> 7, cb = off & 127;
            int scb = cb ^ ((r & 7) << 4);
            const void* src = (const char*)Bt + ((size_t)(n0 + r) * ldb + kt) * 2 + scb;
            gload16(src, (char*)Bsm + (w * (BN / 32) + q) * 1024);
        }
        __syncthreads();

#pragma unroll
        for (int kc = 0; kc < 2; ++kc) {
            bf16x8 af[MR], bfr[NR];
#pragma unroll
            for (int mi = 0; mi < MR; ++mi) {
                int r = wm * (BM / 2) + mi * 16 + i15;
                af[mi] = *(const bf16x8*)((const char*)Asm + r * 128 +
                                          ((kc * 64 + g * 16) ^ ((r & 7) << 4)));
            }
#pragma unroll
            for (int ni = 0; ni < NR; ++ni) {
                int r = wn * (BN / 2) + ni * 16 + i15;
                bfr[ni] = *(const bf16x8*)((const char*)Bsm + r * 128 +
                                           ((kc * 64 + g * 16) ^ ((r & 7) << 4)));
            }
#pragma unroll
            for (int mi = 0; mi < MR; ++mi)
#pragma unroll
                for (int ni = 0; ni < NR; ++ni)
                    acc[mi][ni] = __builtin_amdgcn_mfma_f32_16x16x32_bf16(
                        af[mi], bfr[ni], acc[mi][ni], 0, 0, 0);
        }
        __syncthreads();
    }

    float* Cf = (float*)Cout;
    if (SPLITK) Cf += (size_t)blockIdx.z * M * N;

#pragma unroll
    for (int ni = 0; ni < NR; ++ni) {
        int col = n0 + wn * (BN / 2) + ni * 16 + i15;
        float bb = bias ? bias[col] : 0.f;
#pragma unroll
        for (int mi = 0; mi < MR; ++mi) {
#pragma unroll
            for (int r2 = 0; r2 < 4; ++r2) {
                int row = m0 + wm * (BM / 2) + mi * 16 + 4 * g + r2;
                float v = acc[mi][ni][r2] + bb;
                if (ACT) v = gelu_erf(v);
                if (SCALED) v *= scale;
                size_t off = (size_t)row * N + col;
                if (OUTF32) {
                    float rv = RES ? resid[off] : 0.f;
                    Cf[off] = v + rv;
                } else {
                    ((ushort*)Cout)[off] = f2bf(v);
                }
            }
        }
    }
}

// ---------------------------------------------------------------------------
// Flash attention v5: 8 waves (512 thr) x 16 q-rows = 128 q-rows/block.
// Same per-wave math as v2 (16x16 swapped QK^T, exp2, defer-max), but:
// shared K/V LDS staging across 8 waves, 2x-unrolled loop with compile-time
// buffer index (loop-invariant LDS addresses), 48KB LDS -> 3 blocks/CU.
// NS-way KV split -> f32 partials + (m,l); fully-masked tiles self-correct
// through the online-softmax rescale (verified r4/r5).
// ---------------------------------------------------------------------------
template <int NS>
__global__ __launch_bounds__(512) void flash_attn(
    const ushort* __restrict__ Q,    // [2048][1024] bf16 (pre-scaled 0.125*log2e)
    const ushort* __restrict__ KVb,  // [4096][2048] bf16 (K = cols 0..1023)
    const ushort* __restrict__ Vt,   // [1024][4096] bf16
    ushort* __restrict__ O,          // NS==1: [2048][1024] bf16
    float* __restrict__ Opart,       // NS>1: [NS][2048][1024] f32
    float* __restrict__ Ml) {        // NS>1: [NS][2048][16][2] f32
    constexpr int D = 1024;
    __shared__ __align__(16) ushort Ksm[2][64 * 64];
    __shared__ __align__(16) ushort Vsm[2][64 * 64];
    __shared__ __align__(16) ushort Psm[8][16 * 64];

    const int tid = threadIdx.x;
    const int w = tid >> 6, lane = tid & 63, g = lane >> 4, i15 = lane & 15;
    const int bid = blockIdx.x;
    const int h = bid & 15;                 // bid%8 == h%8 -> same-head same-XCD
    const int qB = 15 - ((bid >> 4) & 15);  // heavy q-blocks first
    const int s = (NS > 1) ? (bid >> 8) : 0;
    const int qb = qB * 128 + w * 16;
    const int qrow = qb + i15;
    const int diagW = qb >> 6;              // wave's partial-mask tile
    const int diagB = 2 * qB + 1;           // block's last self tile
    const int nt = diagB + 33;
    const int lo = (s * nt) / NS;
    const int hi = ((s + 1) * nt) / NS;

    bf16x8 qf[2];
    qf[0] = *(const bf16x8*)(Q + (size_t)qrow * D + h * 64 + g * 8);
    qf[1] = *(const bf16x8*)(Q + (size_t)qrow * D + h * 64 + 32 + g * 8);

    f32x4 o[4] = {};
    float m_run = -INFINITY, l_run = 0.f;

    // staging: 512 threads, 64x64 bf16 K tile + V tile, 1 uint4 each
    const int sr  = tid >> 3;               // 0..63
    const int scb = (tid & 7) * 16;
    const int ssw = scb ^ ((sr & 7) << 4);
    const char* kb0 = (const char*)KVb + ((size_t)sr * 2048 + h * 64) * 2 + scb;
    const char* vb0 = (const char*)Vt + ((size_t)(h * 64 + sr) * 4096) * 2 + scb;

    uint4 kreg, vreg;
    auto jt_of = [&](int t) { return (t <= diagB) ? t : (32 + (t - diagB - 1)); };
    auto stage = [&](int t) {
        const int jt = jt_of(t);
        kreg = *(const uint4*)(kb0 + (size_t)jt * 64 * 4096);
        vreg = *(const uint4*)(vb0 + (size_t)jt * 128);
    };
    auto wlds = [&](int buf) {
        *(uint4*)((char*)Ksm[buf] + sr * 128 + ssw) = kreg;
        *(uint4*)((char*)Vsm[buf] + sr * 128 + ssw) = vreg;
    };

    const int pbase = i15 * 128;            // within Psm[w]
    const int psw = (i15 & 7) << 4;

    auto body = [&](int buf, int t) {
        const int jt = jt_of(t);
        // S^T = K * Q^T
        f32x4 st[4];
#pragma unroll
        for (int jg = 0; jg < 4; ++jg) {
            int jr = jg * 16 + i15;
            bf16x8 ka0 = *(const bf16x8*)((const char*)Ksm[buf] + jr * 128 +
                                          ((g * 16) ^ ((jr & 7) << 4)));
            bf16x8 ka1 = *(const bf16x8*)((const char*)Ksm[buf] + jr * 128 +
                                          ((64 + g * 16) ^ ((jr & 7) << 4)));
            f32x4 z = {};
            z = __builtin_amdgcn_mfma_f32_16x16x32_bf16(ka0, qf[0], z, 0, 0, 0);
            z = __builtin_amdgcn_mfma_f32_16x16x32_bf16(ka1, qf[1], z, 0, 0, 0);
            st[jg] = z;
        }
        if (jt >= diagW && jt <= diagB) {   // partial or fully masked self tile
#pragma unroll
            for (int jg = 0; jg < 4; ++jg)
#pragma unroll
                for (int r = 0; r < 4; ++r) {
                    int j = jt * 64 + jg * 16 + 4 * g + r;
                    if (j > qrow) st[jg][r] = -50000.f;
                }
        }

        // row max (tree)
        float v8[8];
#pragma unroll
        for (int jg = 0; jg < 4; ++jg) {
            v8[2 * jg]     = fmaxf(st[jg][0], st[jg][1]);
            v8[2 * jg + 1] = fmaxf(st[jg][2], st[jg][3]);
        }
        v8[0] = fmaxf(v8[0], v8[4]); v8[1] = fmaxf(v8[1], v8[5]);
        v8[2] = fmaxf(v8[2], v8[6]); v8[3] = fmaxf(v8[3], v8[7]);
        float mt = fmaxf(fmaxf(v8[0], v8[1]), fmaxf(v8[2], v8[3]));
        mt = fmaxf(mt, __shfl_xor(mt, 16));
        mt = fmaxf(mt, __shfl_xor(mt, 32));

        const bool skip = __all(mt - m_run <= 8.f);
        float mnew, fscale;
        if (skip) { mnew = m_run; fscale = 1.f; }
        else      { mnew = fmaxf(m_run, mt); fscale = exp2f(m_run - mnew); }

        float pf[4][4], sj[4];
#pragma unroll
        for (int jg = 0; jg < 4; ++jg) {
#pragma unroll
            for (int r = 0; r < 4; ++r) pf[jg][r] = exp2f(st[jg][r] - mnew);
            sj[jg] = (pf[jg][0] + pf[jg][1]) + (pf[jg][2] + pf[jg][3]);
        }
        float psum = (sj[0] + sj[1]) + (sj[2] + sj[3]);
        psum += __shfl_xor(psum, 16);
        psum += __shfl_xor(psum, 32);
        l_run = l_run * fscale + psum;
        m_run = mnew;

        if (!skip) {
#pragma unroll
            for (int r = 0; r < 4; ++r) {
                float fr = __shfl(fscale, 20 * g + r);
#pragma unroll
                for (int dg = 0; dg < 4; ++dg) o[dg][r] *= fr;
            }
        }

        // pack P -> per-wave swizzled LDS [16 i][64 j]
#pragma unroll
        for (int jg = 0; jg < 4; ++jg) {
            uint2 pk;
            pk.x = cvtpk(pf[jg][0], pf[jg][1]);
            pk.y = cvtpk(pf[jg][2], pf[jg][3]);
            *(uint2*)((char*)Psm[w] + pbase + ((jg * 32 + g * 8) ^ psw)) = pk;
        }

        // O += P * V
#pragma unroll
        for (int jc = 0; jc < 2; ++jc) {
            bf16x8 pa = *(const bf16x8*)((const char*)Psm[w] + pbase +
                                         ((jc * 64 + g * 16) ^ psw));
#pragma unroll
            for (int dg = 0; dg < 4; ++dg) {
                int dr = dg * 16 + i15;
                bf16x8 vb = *(const bf16x8*)((const char*)Vsm[buf] + dr * 128 +
                                             ((jc * 64 + g * 16) ^ ((dr & 7) << 4)));
                o[dg] = __builtin_amdgcn_mfma_f32_16x16x32_bf16(pa, vb, o[dg], 0, 0, 0);
            }
        }
    };

    stage(lo);
    wlds(0);
    __syncthreads();

    int t = lo;
    for (; t + 1 < hi; t += 2) {
        stage(t + 1);
        body(0, t);
        wlds(1);
        __syncthreads();
        if (t + 2 < hi) stage(t + 2);
        body(1, t + 1);
        if (t + 2 < hi) { wlds(0); __syncthreads(); }
    }
    if (t < hi) body(0, t);

    if (NS > 1) {
        if (g == 0) {
            float* mp = Ml + ((size_t)(s * 2048 + qrow) * 16 + h) * 2;
            mp[0] = m_run; mp[1] = l_run;
        }
#pragma unroll
        for (int r = 0; r < 4; ++r)
#pragma unroll
            for (int dg = 0; dg < 4; ++dg) {
                int row = qb + 4 * g + r;
                int col = h * 64 + dg * 16 + i15;
                Opart[(size_t)(s * 2048 + row) * 1024 + col] = o[dg][r];
            }
    } else {
#pragma unroll
        for (int r = 0; r < 4; ++r) {
            float lr = __shfl(l_run, 20 * g + r);
            float inv = 1.f / lr;
#pragma unroll
            for (int dg = 0; dg < 4; ++dg) {
                int row = qb + 4 * g + r;
                int col = h * 64 + dg * 16 + i15;
                O[(size_t)row * D + col] = f2bf(o[dg][r] * inv);
            }
        }
    }
}

// ---------------------------------------------------------------------------
template <int NS>
__global__ __launch_bounds__(256) void attn_combine(
    const float* __restrict__ Opart, const float* __restrict__ Ml,
    ushort* __restrict__ O) {
    const int row = blockIdx.x, tid = threadIdx.x;
    const int c = tid * 4, h = c >> 6;
    float ms[NS], ls[NS];
#pragma unroll
    for (int s = 0; s < NS; ++s) {
        const float* mp = Ml + ((size_t)(s * 2048 + row) * 16 + h) * 2;
        ms[s] = mp[0]; ls[s] = mp[1];
    }
    float m = ms[0];
#pragma unroll
    for (int s = 1; s < NS; ++s) m = fmaxf(m, ms[s]);
    float denom = 0.f, wgt[NS];
#pragma unroll
    for (int s = 0; s < NS; ++s) { wgt[s] = exp2f(ms[s] - m); denom += ls[s] * wgt[s]; }
    const float inv = 1.f / denom;
    float ax = 0, ay = 0, az = 0, aw = 0;
#pragma unroll
    for (int s = 0; s < NS; ++s) {
        float4 a = *(const float4*)(Opart + (size_t)(s * 2048 + row) * 1024 + c);
        ax += a.x * wgt[s]; ay += a.y * wgt[s]; az += a.z * wgt[s]; aw += a.w * wgt[s];
    }
    ushort4 ob;
    ob.x = f2bf(ax * inv); ob.y = f2bf(ay * inv);
    ob.z = f2bf(az * inv); ob.w = f2bf(aw * inv);
    *(ushort4*)(O + (size_t)row * 1024 + c) = ob;
}

// ---------------------------------------------------------------------------
__global__ __launch_bounds__(256) void layernorm_k(
    const float* __restrict__ in, const float* __restrict__ gam,
    const float* __restrict__ bet, float* __restrict__ outf,
    ushort* __restrict__ outb) {
    const int row = blockIdx.x, tid = threadIdx.x;
    const float4 v = *(const float4*)(in + (size_t)row * 1024 + tid * 4);
    float s = v.x + v.y + v.z + v.w;
    float sq = v.x * v.x + v.y * v.y + v.z * v.z + v.w * v.w;
#pragma unroll
    for (int d = 1; d < 64; d <<= 1) {
        s += __shfl_xor(s, d);
        sq += __shfl_xor(sq, d);
    }
    __shared__ float red[8];
    const int w = tid >> 6;
    if ((tid & 63) == 0) { red[w] = s; red[4 + w] = sq; }
    __syncthreads();
    s = red[0] + red[1] + red[2] + red[3];
    sq = red[4] + red[5] + red[6] + red[7];
    const float mu = s * (1.f / 1024.f);
    const float rs = rsqrtf(sq * (1.f / 1024.f) - mu * mu + 1e-5f);
    const float4 gg = *(const float4*)(gam + tid * 4);
    const float4 bb = *(const float4*)(bet + tid * 4);
    float4 o;
    o.x = (v.x - mu) * rs * gg.x + bb.x;
    o.y = (v.y - mu) * rs * gg.y + bb.y;
    o.z = (v.z - mu) * rs * gg.z + bb.z;
    o.w = (v.w - mu) * rs * gg.w + bb.w;
    *(float4*)(outf + (size_t)row * 1024 + tid * 4) = o;
    if (outb) {
        ushort4 ob;
        ob.x = f2bf(o.x); ob.y = f2bf(o.y); ob.z = f2bf(o.z); ob.w = f2bf(o.w);
        *(ushort4*)(outb + (size_t)row * 1024 + tid * 4) = ob;
    }
}

// ---------------------------------------------------------------------------
// Final LN over (sum of NP split-K partials + bias + resid)
// ---------------------------------------------------------------------------
template <int NP>
__global__ __launch_bounds__(256) void layernorm_comb(
    const float* __restrict__ P,
    const float* __restrict__ bias, const float* __restrict__ resid,
    const float* __restrict__ gam, const float* __restrict__ bet,
    float* __restrict__ outf) {
    const int row = blockIdx.x, tid = threadIdx.x;
    const float4 rr = *(const float4*)(resid + (size_t)row * 1024 + tid * 4);
    const float4 bs = *(const float4*)(bias + tid * 4);
    float4 v;
    v.x = rr.x + bs.x; v.y = rr.y + bs.y; v.z = rr.z + bs.z; v.w = rr.w + bs.w;
#pragma unroll
    for (int p = 0; p < NP; ++p) {
        const float4 a = *(const float4*)(P + (size_t)(p * 2048 + row) * 1024 + tid * 4);
        v.x += a.x; v.y += a.y; v.z += a.z; v.w += a.w;
    }
    float s = v.x + v.y + v.z + v.w;
    float sq = v.x * v.x + v.y * v.y + v.z * v.z + v.w * v.w;
#pragma unroll
    for (int d = 1; d < 64; d <<= 1) {
        s += __shfl_xor(s, d);
        sq += __shfl_xor(sq, d);
    }
    __shared__ float red[8];
    const int w = tid >> 6;
    if ((tid & 63) == 0) { red[w] = s; red[4 + w] = sq; }
    __syncthreads();
    s = red[0] + red[1] + red[2] + red[3];
    sq = red[4] + red[5] + red[6] + red[7];
    const float mu = s * (1.f / 1024.f);
    const float rs = rsqrtf(sq * (1.f / 1024.f) - mu * mu + 1e-5f);
    const float4 gg = *(const float4*)(gam + tid * 4);
    const float4 bb = *(const float4*)(bet + tid * 4);
    float4 o;
    o.x = (v.x - mu) * rs * gg.x + bb.x;
    o.y = (v.y - mu) * rs * gg.y + bb.y;
    o.z = (v.z - mu) * rs * gg.z + bb.z;
    o.w = (v.w - mu) * rs * gg.w + bb.w;
    *(float4*)(outf + (size_t)row * 1024 + tid * 4) = o;
}

// ---------------------------------------------------------------------------
extern "C" void kernel_launch(void* const* d_in, const int* in_sizes, int n_in,
                              void* d_out, int out_size, void* d_ws, size_t ws_size,
                              hipStream_t stream) {
    const float* x    = (const float*)d_in[0];
    const float* ctx  = (const float*)d_in[1];
    const float* Wq   = (const float*)d_in[2];
    const float* bq   = (const float*)d_in[3];
    const float* Wkv  = (const float*)d_in[4];
    const float* bkv  = (const float*)d_in[5];
    const float* Wo   = (const float*)d_in[6];
    const float* bo   = (const float*)d_in[7];
    const float* g1   = (const float*)d_in[8];
    const float* b1   = (const float*)d_in[9];
    const float* W1   = (const float*)d_in[10];
    const float* bf1  = (const float*)d_in[11];
    const float* W2   = (const float*)d_in[12];
    const float* bf2  = (const float*)d_in[13];
    const float* g2   = (const float*)d_in[14];
    const float* b2   = (const float*)d_in[15];

    char* ws = (char*)d_ws;
    const size_t MB = 1u << 20;
    ushort* XCb  = (ushort*)(ws + 0);        // 8MB; dead after KV gemm
    ushort* WoT  = (ushort*)(ws + 8 * MB);   // 2MB
    ushort* W1T  = (ushort*)(ws + 10 * MB);  // 8MB
    ushort* W2T  = (ushort*)(ws + 18 * MB);  // 8MB
    ushort* WqT  = (ushort*)(ws + 26 * MB);  // 2MB; later x1b
    ushort* WkvT = (ushort*)(ws + 28 * MB);  // 4MB
    ushort* Qs   = (ushort*)(ws + 32 * MB);  // 4MB; later x1f
    ushort* attn = (ushort*)(ws + 36 * MB);  // 4MB
    ushort* KV   = (ushort*)(ws + 40 * MB);  // 16MB; later ff
    ushort* Vt   = (ushort*)(ws + 56 * MB);  // 8MB; later y1
    ushort* x1b  = (ushort*)(ws + 26 * MB);  // 4MB
    float*  x1f  = (float*)(ws + 32 * MB);   // 8MB
    ushort* ffb  = (ushort*)(ws + 40 * MB);  // 16MB
    float*  y1   = (float*)(ws + 56 * MB);   // 8MB
    float*  Opart = (float*)(ws + 64 * MB);  // NS*8MB attn partials; later Pk4
    float*  Pk4   = (float*)(ws + 64 * MB);  // 32MB FFN2 split-4 partials
    float*  Pk2   = (float*)(ws + 0);        // 16MB FFN2 split-2 fallback

    cvt4<<<2048, 256, 0, stream>>>(x, XCb, 2048 * 1024);
    cvt4<<<2048, 256, 0, stream>>>(ctx, XCb + 2048 * 1024, 2048 * 1024);
    tcvt<<<dim3(32, 32), dim3(32, 8), 0, stream>>>(Wq, WqT, 1024, 1024);
    tcvt<<<dim3(64, 32), dim3(32, 8), 0, stream>>>(Wkv, WkvT, 1024, 2048);
    tcvt<<<dim3(32, 32), dim3(32, 8), 0, stream>>>(Wo, WoT, 1024, 1024);
    tcvt<<<dim3(128, 32), dim3(32, 8), 0, stream>>>(W1, W1T, 1024, 4096);
    tcvt<<<dim3(32, 128), dim3(32, 8), 0, stream>>>(W2, W2T, 4096, 1024);
    // Q = (x@Wq + bq) * 0.125 * log2(e)
    gemm_bt<64, 128, 0, 0, 0, 1, 0><<<dim3(8, 32), 256, 0, stream>>>(
        XCb, 1024, WqT, 1024, bq, nullptr, Qs, 2048, 1024, 1024, 0.18033688011112042f);
    gemm_bt<128, 128, 0, 0, 0, 0, 0><<<dim3(16, 32), 256, 0, stream>>>(
        XCb, 1024, WkvT, 1024, bkv, nullptr, KV, 4096, 2048, 1024, 1.f);
    vtrans<<<dim3(128, 32), dim3(32, 8), 0, stream>>>(KV, Vt);

    // attention: split-4 (97MB ws) > split-2 (81MB) > single
    if (ws_size >= 97 * MB) {
        float* Ml = (float*)(ws + 96 * MB);
        flash_attn<4><<<1024, 512, 0, stream>>>(Qs, KV, Vt, nullptr, Opart, Ml);
        attn_combine<4><<<2048, 256, 0, stream>>>(Opart, Ml, attn);
    } else if (ws_size >= 81 * MB) {
        float* Ml = (float*)(ws + 80 * MB);
        flash_attn<2><<<512, 512, 0, stream>>>(Qs, KV, Vt, nullptr, Opart, Ml);
        attn_combine<2><<<2048, 256, 0, stream>>>(Opart, Ml, attn);
    } else {
        flash_attn<1><<<256, 512, 0, stream>>>(Qs, KV, Vt, attn, nullptr, nullptr);
    }

    gemm_bt<64, 128, 0, 1, 1, 0, 0><<<dim3(8, 32), 256, 0, stream>>>(
        attn, 1024, WoT, 1024, bo, x, y1, 2048, 1024, 1024, 1.f);
    layernorm_k<<<2048, 256, 0, stream>>>(y1, g1, b1, x1f, x1b);
    gemm_bt<128, 128, 1, 0, 0, 0, 0><<<dim3(32, 16), 256, 0, stream>>>(
        x1b, 1024, W1T, 1024, bf1, nullptr, ffb, 2048, 4096, 1024, 1.f);
    // FFN2: 128x128 split-K, f32 partials merged in final LN
    if (ws_size >= 96 * MB) {
        gemm_bt<128, 128, 0, 1, 0, 0, 1><<<dim3(8, 16, 4), 256, 0, stream>>>(
            ffb, 4096, W2T, 4096, nullptr, nullptr, Pk4, 2048, 1024, 1024, 1.f);
        layernorm_comb<4><<<2048, 256, 0, stream>>>(Pk4, bf2, x1f, g2, b2,
                                                    (float*)d_out);
    } else {
        gemm_bt<128, 128, 0, 1, 0, 0, 1><<<dim3(8, 16, 2), 256, 0, stream>>>(
            ffb, 4096, W2T, 4096, nullptr, nullptr, Pk2, 2048, 1024, 2048, 1.f);
        layernorm_comb<2><<<2048, 256, 0, stream>>>(Pk2, bf2, x1f, g2, b2,
                                                    (float*)d_out);
    }
}

// Round 9
// 222.707 us; speedup vs baseline: 1.2442x; 1.0511x over previous
//
#include <hip/hip_runtime.h>

// ---------------------------------------------------------------------------
// TransformerDecoderBlockV2: bf16 MFMA implementation for gfx950
// B=1, N=2048, M=2048, D=1024, H=16, dh=64, DFF=4096
// ---------------------------------------------------------------------------

using bf16x8 = __attribute__((ext_vector_type(8))) short;
using f32x4  = __attribute__((ext_vector_type(4))) float;

__device__ __forceinline__ ushort f2bf(float f) {
    unsigned u = __float_as_uint(f);
    unsigned r = (u + 0x7fffu + ((u >> 16) & 1u)) >> 16;
    return (ushort)r;
}

__device__ __forceinline__ float bf2f(ushort u) {
    return __uint_as_float((uint)u << 16);
}

__device__ __forceinline__ void gload16(const void* g, void* l) {
    __builtin_amdgcn_global_load_lds(
        (const __attribute__((address_space(1))) void*)g,
        (__attribute__((address_space(3))) void*)l, 16, 0, 0);
}

__device__ __forceinline__ float gelu_erf(float v) {
    return 0.5f * v * (1.0f + erff(v * 0.70710678118654752f));
}

__device__ __forceinline__ uint cvtpk(float a, float b) {
    uint r;
    asm("v_cvt_pk_bf16_f32 %0, %1, %2" : "=v"(r) : "v"(a), "v"(b));
    return r;
}

// ---------------------------------------------------------------------------
// f32 -> bf16 convert, grid-stride; n = ELEMENT count (multiple of 4)
// ---------------------------------------------------------------------------
__global__ __launch_bounds__(256) void cvt_all(const float* __restrict__ in,
                                               ushort* __restrict__ out, int n) {
    for (int i = (blockIdx.x * 256 + threadIdx.x) * 4; i + 3 < n;
         i += gridDim.x * 1024) {
        float4 v = *(const float4*)(in + i);
        ushort4 o;
        o.x = f2bf(v.x); o.y = f2bf(v.y); o.z = f2bf(v.z); o.w = f2bf(v.w);
        *(ushort4*)(out + i) = o;
    }
}

// ---------------------------------------------------------------------------
// Batched transpose+convert for all 5 weights: out[C][R] = in[R][C]
// ---------------------------------------------------------------------------
__global__ __launch_bounds__(256) void tcvt_all(
    const float* __restrict__ Wq, const float* __restrict__ Wkv,
    const float* __restrict__ Wo, const float* __restrict__ W1,
    const float* __restrict__ W2,
    ushort* __restrict__ WqT, ushort* __restrict__ WkvT,
    ushort* __restrict__ WoT, ushort* __restrict__ W1T,
    ushort* __restrict__ W2T) {
    __shared__ float tile[32][33];
    int b = blockIdx.x;
    const float* in; ushort* out; int R, C, loc;
    if (b < 1024)      { in = Wq;  out = WqT;  R = 1024; C = 1024; loc = b; }
    else if (b < 3072) { in = Wkv; out = WkvT; R = 1024; C = 2048; loc = b - 1024; }
    else if (b < 4096) { in = Wo;  out = WoT;  R = 1024; C = 1024; loc = b - 3072; }
    else if (b < 8192) { in = W1;  out = W1T;  R = 1024; C = 4096; loc = b - 4096; }
    else               { in = W2;  out = W2T;  R = 4096; C = 1024; loc = b - 8192; }
    const int nbx = C >> 5;
    const int c0 = (loc % nbx) * 32, r0 = (loc / nbx) * 32;
    const int tx = threadIdx.x & 31, ty = threadIdx.x >> 5;
#pragma unroll
    for (int i = 0; i < 4; ++i)
        tile[ty + 8 * i][tx] = in[(size_t)(r0 + ty + 8 * i) * C + c0 + tx];
    __syncthreads();
#pragma unroll
    for (int i = 0; i < 4; ++i)
        out[(size_t)(c0 + ty + 8 * i) * R + r0 + tx] = f2bf(tile[tx][ty + 8 * i]);
}

// ---------------------------------------------------------------------------
// GEMM: C[M][N] = epilogue( A[M][K] * Bt[N][K]^T + bias ), bf16 in.
// 128x128 = m97-class structure; SPLITK via blockIdx.z, f32 partials.
// VT: cols >= 1024 are written TRANSPOSED as bf16 to Vout[col-1024][row]
//     (V^T for attention); cols < 1024 (K) go to Cout [M][1024].
// ---------------------------------------------------------------------------
template <int BM, int BN, int ACT, int OUTF32, int RES, int SCALED, int SPLITK, int VT>
__global__ __launch_bounds__(256) void gemm_bt(
    const ushort* __restrict__ A, int lda, const ushort* __restrict__ Bt, int ldb,
    const float* __restrict__ bias, const float* __restrict__ resid,
    void* __restrict__ Cout, ushort* __restrict__ Vout,
    int M, int N, int K, float scale) {
    constexpr int MR = BM / 32, NR = BN / 32;
    __shared__ __align__(16) ushort Asm[BM * 64];
    __shared__ __align__(16) ushort Bsm[BN * 64];
    const int tid = threadIdx.x;
    const int w = tid >> 6, lane = tid & 63, g = lane >> 4, i15 = lane & 15;
    const int wm = w >> 1, wn = w & 1;
    const int m0 = blockIdx.y * BM, n0 = blockIdx.x * BN;
    if (SPLITK) {
        A += (size_t)blockIdx.z * K;
        Bt += (size_t)blockIdx.z * K;
    }

    f32x4 acc[MR][NR] = {};

    for (int kt = 0; kt < K; kt += 64) {
#pragma unroll
        for (int q = 0; q < BM / 32; ++q) {
            int off = (w * (BM / 32) + q) * 1024 + lane * 16;
            int r = off >> 7, cb = off & 127;
            int scb = cb ^ ((r & 7) << 4);
            const void* src = (const char*)A + ((size_t)(m0 + r) * lda + kt) * 2 + scb;
            gload16(src, (char*)Asm + (w * (BM / 32) + q) * 1024);
        }
#pragma unroll
        for (int q = 0; q < BN / 32; ++q) {
            int off = (w * (BN / 32) + q) * 1024 + lane * 16;
            int r = off >> 7, cb = off & 127;
            int scb = cb ^ ((r & 7) << 4);
            const void* src = (const char*)Bt + ((size_t)(n0 + r) * ldb + kt) * 2 + scb;
            gload16(src, (char*)Bsm + (w * (BN / 32) + q) * 1024);
        }
        __syncthreads();

#pragma unroll
        for (int kc = 0; kc < 2; ++kc) {
            bf16x8 af[MR], bfr[NR];
#pragma unroll
            for (int mi = 0; mi < MR; ++mi) {
                int r = wm * (BM / 2) + mi * 16 + i15;
                af[mi] = *(const bf16x8*)((const char*)Asm + r * 128 +
                                          ((kc * 64 + g * 16) ^ ((r & 7) << 4)));
            }
#pragma unroll
            for (int ni = 0; ni < NR; ++ni) {
                int r = wn * (BN / 2) + ni * 16 + i15;
                bfr[ni] = *(const bf16x8*)((const char*)Bsm + r * 128 +
                                           ((kc * 64 + g * 16) ^ ((r & 7) << 4)));
            }
#pragma unroll
            for (int mi = 0; mi < MR; ++mi)
#pragma unroll
                for (int ni = 0; ni < NR; ++ni)
                    acc[mi][ni] = __builtin_amdgcn_mfma_f32_16x16x32_bf16(
                        af[mi], bfr[ni], acc[mi][ni], 0, 0, 0);
        }
        __syncthreads();
    }

    float* Cf = (float*)Cout;
    if (SPLITK) Cf += (size_t)blockIdx.z * M * N;

#pragma unroll
    for (int ni = 0; ni < NR; ++ni) {
        int col = n0 + wn * (BN / 2) + ni * 16 + i15;
        float bb = bias ? bias[col] : 0.f;
#pragma unroll
        for (int mi = 0; mi < MR; ++mi) {
            if (VT && col >= 1024) {
                // V^T: rows 4g..4g+3 consecutive -> vector 8B store
                int row = m0 + wm * (BM / 2) + mi * 16 + 4 * g;
                ushort4 ov;
                ov.x = f2bf(acc[mi][ni][0] + bb);
                ov.y = f2bf(acc[mi][ni][1] + bb);
                ov.z = f2bf(acc[mi][ni][2] + bb);
                ov.w = f2bf(acc[mi][ni][3] + bb);
                *(ushort4*)(Vout + (size_t)(col - 1024) * 4096 + row) = ov;
            } else {
#pragma unroll
                for (int r2 = 0; r2 < 4; ++r2) {
                    int row = m0 + wm * (BM / 2) + mi * 16 + 4 * g + r2;
                    float v = acc[mi][ni][r2] + bb;
                    if (ACT) v = gelu_erf(v);
                    if (SCALED) v *= scale;
                    size_t off = VT ? ((size_t)row * 1024 + col)
                                    : ((size_t)row * N + col);
                    if (OUTF32) {
                        float rv = RES ? resid[off] : 0.f;
                        Cf[off] = v + rv;
                    } else {
                        ((ushort*)Cout)[off] = f2bf(v);
                    }
                }
            }
        }
    }
}

// ---------------------------------------------------------------------------
// Flash attention v5b: 8 waves (512 thr) x 16 q-rows = 128 q-rows/block.
// 16x16 swapped QK^T, exp2, defer-max, shared K/V LDS, 2x-unrolled dbuf,
// setprio around MFMA clusters, bf16 split partials.
// K from Kb [4096][1024]; V^T from Vt [1024][4096].
// ---------------------------------------------------------------------------
template <int NS>
__global__ __launch_bounds__(512) void flash_attn(
    const ushort* __restrict__ Q,    // [2048][1024] bf16 (pre-scaled 0.125*log2e)
    const ushort* __restrict__ Kb,   // [4096][1024] bf16
    const ushort* __restrict__ Vt,   // [1024][4096] bf16
    ushort* __restrict__ O,          // NS==1: [2048][1024] bf16
    ushort* __restrict__ Opart,      // NS>1: [NS][2048][1024] bf16 (unnormalized)
    float* __restrict__ Ml) {        // NS>1: [NS][2048][16][2] f32
    constexpr int D = 1024;
    __shared__ __align__(16) ushort Ksm[2][64 * 64];
    __shared__ __align__(16) ushort Vsm[2][64 * 64];
    __shared__ __align__(16) ushort Psm[8][16 * 64];

    const int tid = threadIdx.x;
    const int w = tid >> 6, lane = tid & 63, g = lane >> 4, i15 = lane & 15;
    const int bid = blockIdx.x;
    const int h = bid & 15;                 // bid%8 == h%8 -> same-head same-XCD
    const int qB = 15 - ((bid >> 4) & 15);  // heavy q-blocks first
    const int s = (NS > 1) ? (bid >> 8) : 0;
    const int qb = qB * 128 + w * 16;
    const int qrow = qb + i15;
    const int diagW = qb >> 6;              // wave's partial-mask tile
    const int diagB = 2 * qB + 1;           // block's last self tile
    const int nt = diagB + 33;
    const int lo = (s * nt) / NS;
    const int hi = ((s + 1) * nt) / NS;

    bf16x8 qf[2];
    qf[0] = *(const bf16x8*)(Q + (size_t)qrow * D + h * 64 + g * 8);
    qf[1] = *(const bf16x8*)(Q + (size_t)qrow * D + h * 64 + 32 + g * 8);

    f32x4 o[4] = {};
    float m_run = -INFINITY, l_run = 0.f;

    // staging: 512 threads, 64x64 bf16 K tile + V tile, 1 uint4 each
    const int sr  = tid >> 3;               // 0..63
    const int scb = (tid & 7) * 16;
    const int ssw = scb ^ ((sr & 7) << 4);
    const char* kb0 = (const char*)Kb + ((size_t)sr * 1024 + h * 64) * 2 + scb;
    const char* vb0 = (const char*)Vt + ((size_t)(h * 64 + sr) * 4096) * 2 + scb;

    uint4 kreg, vreg;
    auto jt_of = [&](int t) { return (t <= diagB) ? t : (32 + (t - diagB - 1)); };
    auto stage = [&](int t) {
        const int jt = jt_of(t);
        kreg = *(const uint4*)(kb0 + (size_t)jt * 64 * 2048);
        vreg = *(const uint4*)(vb0 + (size_t)jt * 128);
    };
    auto wlds = [&](int buf) {
        *(uint4*)((char*)Ksm[buf] + sr * 128 + ssw) = kreg;
        *(uint4*)((char*)Vsm[buf] + sr * 128 + ssw) = vreg;
    };

    const int pbase = i15 * 128;            // within Psm[w]
    const int psw = (i15 & 7) << 4;

    auto body = [&](int buf, int t) {
        const int jt = jt_of(t);
        // S^T = K * Q^T
        f32x4 st[4];
        __builtin_amdgcn_s_setprio(1);
#pragma unroll
        for (int jg = 0; jg < 4; ++jg) {
            int jr = jg * 16 + i15;
            bf16x8 ka0 = *(const bf16x8*)((const char*)Ksm[buf] + jr * 128 +
                                          ((g * 16) ^ ((jr & 7) << 4)));
            bf16x8 ka1 = *(const bf16x8*)((const char*)Ksm[buf] + jr * 128 +
                                          ((64 + g * 16) ^ ((jr & 7) << 4)));
            f32x4 z = {};
            z = __builtin_amdgcn_mfma_f32_16x16x32_bf16(ka0, qf[0], z, 0, 0, 0);
            z = __builtin_amdgcn_mfma_f32_16x16x32_bf16(ka1, qf[1], z, 0, 0, 0);
            st[jg] = z;
        }
        __builtin_amdgcn_s_setprio(0);
        if (jt >= diagW && jt <= diagB) {   // partial or fully masked self tile
#pragma unroll
            for (int jg = 0; jg < 4; ++jg)
#pragma unroll
                for (int r = 0; r < 4; ++r) {
                    int j = jt * 64 + jg * 16 + 4 * g + r;
                    if (j > qrow) st[jg][r] = -50000.f;
                }
        }

        // row max (tree)
        float v8[8];
#pragma unroll
        for (int jg = 0; jg < 4; ++jg) {
            v8[2 * jg]     = fmaxf(st[jg][0], st[jg][1]);
            v8[2 * jg + 1] = fmaxf(st[jg][2], st[jg][3]);
        }
        v8[0] = fmaxf(v8[0], v8[4]); v8[1] = fmaxf(v8[1], v8[5]);
        v8[2] = fmaxf(v8[2], v8[6]); v8[3] = fmaxf(v8[3], v8[7]);
        float mt = fmaxf(fmaxf(v8[0], v8[1]), fmaxf(v8[2], v8[3]));
        mt = fmaxf(mt, __shfl_xor(mt, 16));
        mt = fmaxf(mt, __shfl_xor(mt, 32));

        const bool skip = __all(mt - m_run <= 8.f);
        float mnew, fscale;
        if (skip) { mnew = m_run; fscale = 1.f; }
        else      { mnew = fmaxf(m_run, mt); fscale = exp2f(m_run - mnew); }

        float pf[4][4], sj[4];
#pragma unroll
        for (int jg = 0; jg < 4; ++jg) {
#pragma unroll
            for (int r = 0; r < 4; ++r) pf[jg][r] = exp2f(st[jg][r] - mnew);
            sj[jg] = (pf[jg][0] + pf[jg][1]) + (pf[jg][2] + pf[jg][3]);
        }
        float psum = (sj[0] + sj[1]) + (sj[2] + sj[3]);
        psum += __shfl_xor(psum, 16);
        psum += __shfl_xor(psum, 32);
        l_run = l_run * fscale + psum;
        m_run = mnew;

        if (!skip) {
#pragma unroll
            for (int r = 0; r < 4; ++r) {
                float fr = __shfl(fscale, 20 * g + r);
#pragma unroll
                for (int dg = 0; dg < 4; ++dg) o[dg][r] *= fr;
            }
        }

        // pack P -> per-wave swizzled LDS [16 i][64 j]
#pragma unroll
        for (int jg = 0; jg < 4; ++jg) {
            uint2 pk;
            pk.x = cvtpk(pf[jg][0], pf[jg][1]);
            pk.y = cvtpk(pf[jg][2], pf[jg][3]);
            *(uint2*)((char*)Psm[w] + pbase + ((jg * 32 + g * 8) ^ psw)) = pk;
        }

        // O += P * V
        __builtin_amdgcn_s_setprio(1);
#pragma unroll
        for (int jc = 0; jc < 2; ++jc) {
            bf16x8 pa = *(const bf16x8*)((const char*)Psm[w] + pbase +
                                         ((jc * 64 + g * 16) ^ psw));
#pragma unroll
            for (int dg = 0; dg < 4; ++dg) {
                int dr = dg * 16 + i15;
                bf16x8 vb = *(const bf16x8*)((const char*)Vsm[buf] + dr * 128 +
                                             ((jc * 64 + g * 16) ^ ((dr & 7) << 4)));
                o[dg] = __builtin_amdgcn_mfma_f32_16x16x32_bf16(pa, vb, o[dg], 0, 0, 0);
            }
        }
        __builtin_amdgcn_s_setprio(0);
    };

    stage(lo);
    wlds(0);
    __syncthreads();

    int t = lo;
    for (; t + 1 < hi; t += 2) {
        stage(t + 1);
        body(0, t);
        wlds(1);
        __syncthreads();
        if (t + 2 < hi) stage(t + 2);
        body(1, t + 1);
        if (t + 2 < hi) { wlds(0); __syncthreads(); }
    }
    if (t < hi) body(0, t);

    if (NS > 1) {
        if (g == 0) {
            float* mp = Ml + ((size_t)(s * 2048 + qrow) * 16 + h) * 2;
            mp[0] = m_run; mp[1] = l_run;
        }
#pragma unroll
        for (int r = 0; r < 4; ++r)
#pragma unroll
            for (int dg = 0; dg < 4; ++dg) {
                int row = qb + 4 * g + r;
                int col = h * 64 + dg * 16 + i15;
                Opart[(size_t)(s * 2048 + row) * 1024 + col] = f2bf(o[dg][r]);
            }
    } else {
#pragma unroll
        for (int r = 0; r < 4; ++r) {
            float lr = __shfl(l_run, 20 * g + r);
            float inv = 1.f / lr;
#pragma unroll
            for (int dg = 0; dg < 4; ++dg) {
                int row = qb + 4 * g + r;
                int col = h * 64 + dg * 16 + i15;
                O[(size_t)row * D + col] = f2bf(o[dg][r] * inv);
            }
        }
    }
}

// ---------------------------------------------------------------------------
template <int NS>
__global__ __launch_bounds__(256) void attn_combine(
    const ushort* __restrict__ Opart, const float* __restrict__ Ml,
    ushort* __restrict__ O) {
    const int row = blockIdx.x, tid = threadIdx.x;
    const int c = tid * 4, h = c >> 6;
    float ms[NS], ls[NS];
#pragma unroll
    for (int s = 0; s < NS; ++s) {
        const float* mp = Ml + ((size_t)(s * 2048 + row) * 16 + h) * 2;
        ms[s] = mp[0]; ls[s] = mp[1];
    }
    float m = ms[0];
#pragma unroll
    for (int s = 1; s < NS; ++s) m = fmaxf(m, ms[s]);
    float denom = 0.f, wgt[NS];
#pragma unroll
    for (int s = 0; s < NS; ++s) { wgt[s] = exp2f(ms[s] - m); denom += ls[s] * wgt[s]; }
    const float inv = 1.f / denom;
    float ax = 0, ay = 0, az = 0, aw = 0;
#pragma unroll
    for (int s = 0; s < NS; ++s) {
        ushort4 a = *(const ushort4*)(Opart + (size_t)(s * 2048 + row) * 1024 + c);
        ax += bf2f(a.x) * wgt[s]; ay += bf2f(a.y) * wgt[s];
        az += bf2f(a.z) * wgt[s]; aw += bf2f(a.w) * wgt[s];
    }
    ushort4 ob;
    ob.x = f2bf(ax * inv); ob.y = f2bf(ay * inv);
    ob.z = f2bf(az * inv); ob.w = f2bf(aw * inv);
    *(ushort4*)(O + (size_t)row * 1024 + c) = ob;
}

// ---------------------------------------------------------------------------
__global__ __launch_bounds__(256) void layernorm_k(
    const float* __restrict__ in, const float* __restrict__ gam,
    const float* __restrict__ bet, float* __restrict__ outf,
    ushort* __restrict__ outb) {
    const int row = blockIdx.x, tid = threadIdx.x;
    const float4 v = *(const float4*)(in + (size_t)row * 1024 + tid * 4);
    float s = v.x + v.y + v.z + v.w;
    float sq = v.x * v.x + v.y * v.y + v.z * v.z + v.w * v.w;
#pragma unroll
    for (int d = 1; d < 64; d <<= 1) {
        s += __shfl_xor(s, d);
        sq += __shfl_xor(sq, d);
    }
    __shared__ float red[8];
    const int w = tid >> 6;
    if ((tid & 63) == 0) { red[w] = s; red[4 + w] = sq; }
    __syncthreads();
    s = red[0] + red[1] + red[2] + red[3];
    sq = red[4] + red[5] + red[6] + red[7];
    const float mu = s * (1.f / 1024.f);
    const float rs = rsqrtf(sq * (1.f / 1024.f) - mu * mu + 1e-5f);
    const float4 gg = *(const float4*)(gam + tid * 4);
    const float4 bb = *(const float4*)(bet + tid * 4);
    float4 o;
    o.x = (v.x - mu) * rs * gg.x + bb.x;
    o.y = (v.y - mu) * rs * gg.y + bb.y;
    o.z = (v.z - mu) * rs * gg.z + bb.z;
    o.w = (v.w - mu) * rs * gg.w + bb.w;
    *(float4*)(outf + (size_t)row * 1024 + tid * 4) = o;
    if (outb) {
        ushort4 ob;
        ob.x = f2bf(o.x); ob.y = f2bf(o.y); ob.z = f2bf(o.z); ob.w = f2bf(o.w);
        *(ushort4*)(outb + (size_t)row * 1024 + tid * 4) = ob;
    }
}

// ---------------------------------------------------------------------------
// Final LN over (sum of NP split-K partials + bias + resid)
// ---------------------------------------------------------------------------
template <int NP>
__global__ __launch_bounds__(256) void layernorm_comb(
    const float* __restrict__ P,
    const float* __restrict__ bias, const float* __restrict__ resid,
    const float* __restrict__ gam, const float* __restrict__ bet,
    float* __restrict__ outf) {
    const int row = blockIdx.x, tid = threadIdx.x;
    const float4 rr = *(const float4*)(resid + (size_t)row * 1024 + tid * 4);
    const float4 bs = *(const float4*)(bias + tid * 4);
    float4 v;
    v.x = rr.x + bs.x; v.y = rr.y + bs.y; v.z = rr.z + bs.z; v.w = rr.w + bs.w;
#pragma unroll
    for (int p = 0; p < NP; ++p) {
        const float4 a = *(const float4*)(P + (size_t)(p * 2048 + row) * 1024 + tid * 4);
        v.x += a.x; v.y += a.y; v.z += a.z; v.w += a.w;
    }
    float s = v.x + v.y + v.z + v.w;
    float sq = v.x * v.x + v.y * v.y + v.z * v.z + v.w * v.w;
#pragma unroll
    for (int d = 1; d < 64; d <<= 1) {
        s += __shfl_xor(s, d);
        sq += __shfl_xor(sq, d);
    }
    __shared__ float red[8];
    const int w = tid >> 6;
    if ((tid & 63) == 0) { red[w] = s; red[4 + w] = sq; }
    __syncthreads();
    s = red[0] + red[1] + red[2] + red[3];
    sq = red[4] + red[5] + red[6] + red[7];
    const float mu = s * (1.f / 1024.f);
    const float rs = rsqrtf(sq * (1.f / 1024.f) - mu * mu + 1e-5f);
    const float4 gg = *(const float4*)(gam + tid * 4);
    const float4 bb = *(const float4*)(bet + tid * 4);
    float4 o;
    o.x = (v.x - mu) * rs * gg.x + bb.x;
    o.y = (v.y - mu) * rs * gg.y + bb.y;
    o.z = (v.z - mu) * rs * gg.z + bb.z;
    o.w = (v.w - mu) * rs * gg.w + bb.w;
    *(float4*)(outf + (size_t)row * 1024 + tid * 4) = o;
}

// ---------------------------------------------------------------------------
extern "C" void kernel_launch(void* const* d_in, const int* in_sizes, int n_in,
                              void* d_out, int out_size, void* d_ws, size_t ws_size,
                              hipStream_t stream) {
    const float* x    = (const float*)d_in[0];
    const float* ctx  = (const float*)d_in[1];
    const float* Wq   = (const float*)d_in[2];
    const float* bq   = (const float*)d_in[3];
    const float* Wkv  = (const float*)d_in[4];
    const float* bkv  = (const float*)d_in[5];
    const float* Wo   = (const float*)d_in[6];
    const float* bo   = (const float*)d_in[7];
    const float* g1   = (const float*)d_in[8];
    const float* b1   = (const float*)d_in[9];
    const float* W1   = (const float*)d_in[10];
    const float* bf1  = (const float*)d_in[11];
    const float* W2   = (const float*)d_in[12];
    const float* bf2  = (const float*)d_in[13];
    const float* g2   = (const float*)d_in[14];
    const float* b2   = (const float*)d_in[15];

    char* ws = (char*)d_ws;
    const size_t MB = 1u << 20;
    ushort* XCb  = (ushort*)(ws + 0);        // 8MB; dead after KV gemm
    ushort* WoT  = (ushort*)(ws + 8 * MB);   // 2MB
    ushort* W1T  = (ushort*)(ws + 10 * MB);  // 8MB
    ushort* W2T  = (ushort*)(ws + 18 * MB);  // 8MB
    ushort* WqT  = (ushort*)(ws + 26 * MB);  // 2MB; later x1b
    ushort* WkvT = (ushort*)(ws + 28 * MB);  // 4MB
    ushort* Qs   = (ushort*)(ws + 32 * MB);  // 4MB; later x1f
    ushort* attn = (ushort*)(ws + 36 * MB);  // 4MB
    ushort* Kb   = (ushort*)(ws + 40 * MB);  // 8MB; later ff (part)
    ushort* Vt   = (ushort*)(ws + 48 * MB);  // 8MB; later ff (part)
    ushort* x1b  = (ushort*)(ws + 26 * MB);  // 4MB
    float*  x1f  = (float*)(ws + 32 * MB);   // 8MB (over Qs+attn after use)
    ushort* ffb  = (ushort*)(ws + 40 * MB);  // 16MB (over Kb+Vt)
    float*  y1   = (float*)(ws + 56 * MB);   // 8MB
    ushort* Opart = (ushort*)(ws + 64 * MB); // NS*4MB bf16 attn partials
    float*  Pk4   = (float*)(ws + 64 * MB);  // 32MB FFN2 split-4 partials
    float*  Pk2   = (float*)(ws + 0);        // 16MB FFN2 split-2 fallback

    cvt_all<<<2048, 256, 0, stream>>>(x, XCb, 2048 * 1024);
    cvt_all<<<2048, 256, 0, stream>>>(ctx, XCb + 2048 * 1024, 2048 * 1024);
    tcvt_all<<<12288, 256, 0, stream>>>(Wq, Wkv, Wo, W1, W2,
                                        WqT, WkvT, WoT, W1T, W2T);
    // Q = (x@Wq + bq) * 0.125 * log2(e)
    gemm_bt<64, 128, 0, 0, 0, 1, 0, 0><<<dim3(8, 32), 256, 0, stream>>>(
        XCb, 1024, WqT, 1024, bq, nullptr, Qs, nullptr,
        2048, 1024, 1024, 0.18033688011112042f);
    // KV projection: K -> Kb [4096][1024]; V -> Vt [1024][4096] (transposed)
    gemm_bt<128, 128, 0, 0, 0, 0, 0, 1><<<dim3(16, 32), 256, 0, stream>>>(
        XCb, 1024, WkvT, 1024, bkv, nullptr, Kb, Vt,
        4096, 2048, 1024, 1.f);

    // attention: split-4 (>=82MB ws) > split-2 > single
    if (ws_size >= 82 * MB) {
        float* Ml = (float*)(ws + 80 * MB);
        flash_attn<4><<<1024, 512, 0, stream>>>(Qs, Kb, Vt, nullptr, Opart, Ml);
        attn_combine<4><<<2048, 256, 0, stream>>>(Opart, Ml, attn);
    } else if (ws_size >= 73 * MB) {
        float* Ml = (float*)(ws + 72 * MB);
        flash_attn<2><<<512, 512, 0, stream>>>(Qs, Kb, Vt, nullptr, Opart, Ml);
        attn_combine<2><<<2048, 256, 0, stream>>>(Opart, Ml, attn);
    } else {
        flash_attn<1><<<256, 512, 0, stream>>>(Qs, Kb, Vt, attn, nullptr, nullptr);
    }

    gemm_bt<64, 128, 0, 1, 1, 0, 0, 0><<<dim3(8, 32), 256, 0, stream>>>(
        attn, 1024, WoT, 1024, bo, x, y1, nullptr, 2048, 1024, 1024, 1.f);
    layernorm_k<<<2048, 256, 0, stream>>>(y1, g1, b1, x1f, x1b);
    gemm_bt<128, 128, 1, 0, 0, 0, 0, 0><<<dim3(32, 16), 256, 0, stream>>>(
        x1b, 1024, W1T, 1024, bf1, nullptr, ffb, nullptr, 2048, 4096, 1024, 1.f);
    // FFN2: 128x128 split-K, f32 partials merged in final LN
    if (ws_size >= 96 * MB) {
        gemm_bt<128, 128, 0, 1, 0, 0, 1, 0><<<dim3(8, 16, 4), 256, 0, stream>>>(
            ffb, 4096, W2T, 4096, nullptr, nullptr, Pk4, nullptr,
            2048, 1024, 1024, 1.f);
        layernorm_comb<4><<<2048, 256, 0, stream>>>(Pk4, bf2, x1f, g2, b2,
                                                    (float*)d_out);
    } else {
        gemm_bt<128, 128, 0, 1, 0, 0, 1, 0><<<dim3(8, 16, 2), 256, 0, stream>>>(
            ffb, 4096, W2T, 4096, nullptr, nullptr, Pk2, nullptr,
            2048, 1024, 2048, 1.f);
        layernorm_comb<2><<<2048, 256, 0, stream>>>(Pk2, bf2, x1f, g2, b2,
                                                    (float*)d_out);
    }
}

// Round 10
// 221.457 us; speedup vs baseline: 1.2512x; 1.0056x over previous
//
#include <hip/hip_runtime.h>

// ---------------------------------------------------------------------------
// TransformerDecoderBlockV2: bf16 MFMA implementation for gfx950
// B=1, N=2048, M=2048, D=1024, H=16, dh=64, DFF=4096
// ---------------------------------------------------------------------------

using bf16x8 = __attribute__((ext_vector_type(8))) short;
using f32x4  = __attribute__((ext_vector_type(4))) float;

__device__ __forceinline__ ushort f2bf(float f) {
    unsigned u = __float_as_uint(f);
    unsigned r = (u + 0x7fffu + ((u >> 16) & 1u)) >> 16;
    return (ushort)r;
}

__device__ __forceinline__ float bf2f(ushort u) {
    return __uint_as_float((uint)u << 16);
}

__device__ __forceinline__ void gload16(const void* g, void* l) {
    __builtin_amdgcn_global_load_lds(
        (const __attribute__((address_space(1))) void*)g,
        (__attribute__((address_space(3))) void*)l, 16, 0, 0);
}

__device__ __forceinline__ float gelu_erf(float v) {
    return 0.5f * v * (1.0f + erff(v * 0.70710678118654752f));
}

__device__ __forceinline__ uint cvtpk(float a, float b) {
    uint r;
    asm("v_cvt_pk_bf16_f32 %0, %1, %2" : "=v"(r) : "v"(a), "v"(b));
    return r;
}

// ---------------------------------------------------------------------------
// f32 -> bf16 convert for x and ctx in ONE launch (4096 blocks, routed)
// ---------------------------------------------------------------------------
__global__ __launch_bounds__(256) void cvt2(const float* __restrict__ a,
                                            const float* __restrict__ b,
                                            ushort* __restrict__ oa,
                                            ushort* __restrict__ ob) {
    const int bb = blockIdx.x;
    const float* in = (bb < 2048) ? a : b;
    ushort* out = (bb < 2048) ? oa : ob;
    const int i = ((bb & 2047) * 256 + threadIdx.x) * 4;
    float4 v = *(const float4*)(in + i);
    ushort4 o;
    o.x = f2bf(v.x); o.y = f2bf(v.y); o.z = f2bf(v.z); o.w = f2bf(v.w);
    *(ushort4*)(out + i) = o;
}

// ---------------------------------------------------------------------------
// Batched transpose+convert for all 5 weights: out[C][R] = in[R][C]
// ---------------------------------------------------------------------------
__global__ __launch_bounds__(256) void tcvt_all(
    const float* __restrict__ Wq, const float* __restrict__ Wkv,
    const float* __restrict__ Wo, const float* __restrict__ W1,
    const float* __restrict__ W2,
    ushort* __restrict__ WqT, ushort* __restrict__ WkvT,
    ushort* __restrict__ WoT, ushort* __restrict__ W1T,
    ushort* __restrict__ W2T) {
    __shared__ float tile[32][33];
    int b = blockIdx.x;
    const float* in; ushort* out; int R, C, loc;
    if (b < 1024)      { in = Wq;  out = WqT;  R = 1024; C = 1024; loc = b; }
    else if (b < 3072) { in = Wkv; out = WkvT; R = 1024; C = 2048; loc = b - 1024; }
    else if (b < 4096) { in = Wo;  out = WoT;  R = 1024; C = 1024; loc = b - 3072; }
    else if (b < 8192) { in = W1;  out = W1T;  R = 1024; C = 4096; loc = b - 4096; }
    else               { in = W2;  out = W2T;  R = 4096; C = 1024; loc = b - 8192; }
    const int nbx = C >> 5;
    const int c0 = (loc % nbx) * 32, r0 = (loc / nbx) * 32;
    const int tx = threadIdx.x & 31, ty = threadIdx.x >> 5;
#pragma unroll
    for (int i = 0; i < 4; ++i)
        tile[ty + 8 * i][tx] = in[(size_t)(r0 + ty + 8 * i) * C + c0 + tx];
    __syncthreads();
#pragma unroll
    for (int i = 0; i < 4; ++i)
        out[(size_t)(c0 + ty + 8 * i) * R + r0 + tx] = f2bf(tile[tx][ty + 8 * i]);
}

// ---------------------------------------------------------------------------
// GEMM: C[M][N] = epilogue( A[M][K] * Bt[N][K]^T + bias ), bf16 in.
// 128x128 = m97-class structure; SPLITK via blockIdx.z, f32 partials.
// VT: cols >= 1024 are written TRANSPOSED as bf16 to Vout[col-1024][row]
//     (V^T for attention); cols < 1024 (K) go to Cout [M][1024].
// ---------------------------------------------------------------------------
template <int BM, int BN, int ACT, int OUTF32, int RES, int SCALED, int SPLITK, int VT>
__global__ __launch_bounds__(256) void gemm_bt(
    const ushort* __restrict__ A, int lda, const ushort* __restrict__ Bt, int ldb,
    const float* __restrict__ bias, const float* __restrict__ resid,
    void* __restrict__ Cout, ushort* __restrict__ Vout,
    int M, int N, int K, float scale) {
    constexpr int MR = BM / 32, NR = BN / 32;
    __shared__ __align__(16) ushort Asm[BM * 64];
    __shared__ __align__(16) ushort Bsm[BN * 64];
    const int tid = threadIdx.x;
    const int w = tid >> 6, lane = tid & 63, g = lane >> 4, i15 = lane & 15;
    const int wm = w >> 1, wn = w & 1;
    const int m0 = blockIdx.y * BM, n0 = blockIdx.x * BN;
    if (SPLITK) {
        A += (size_t)blockIdx.z * K;
        Bt += (size_t)blockIdx.z * K;
    }

    f32x4 acc[MR][NR] = {};

    for (int kt = 0; kt < K; kt += 64) {
#pragma unroll
        for (int q = 0; q < BM / 32; ++q) {
            int off = (w * (BM / 32) + q) * 1024 + lane * 16;
            int r = off >> 7, cb = off & 127;
            int scb = cb ^ ((r & 7) << 4);
            const void* src = (const char*)A + ((size_t)(m0 + r) * lda + kt) * 2 + scb;
            gload16(src, (char*)Asm + (w * (BM / 32) + q) * 1024);
        }
#pragma unroll
        for (int q = 0; q < BN / 32; ++q) {
            int off = (w * (BN / 32) + q) * 1024 + lane * 16;
            int r = off >> 7, cb = off & 127;
            int scb = cb ^ ((r & 7) << 4);
            const void* src = (const char*)Bt + ((size_t)(n0 + r) * ldb + kt) * 2 + scb;
            gload16(src, (char*)Bsm + (w * (BN / 32) + q) * 1024);
        }
        __syncthreads();

#pragma unroll
        for (int kc = 0; kc < 2; ++kc) {
            bf16x8 af[MR], bfr[NR];
#pragma unroll
            for (int mi = 0; mi < MR; ++mi) {
                int r = wm * (BM / 2) + mi * 16 + i15;
                af[mi] = *(const bf16x8*)((const char*)Asm + r * 128 +
                                          ((kc * 64 + g * 16) ^ ((r & 7) << 4)));
            }
#pragma unroll
            for (int ni = 0; ni < NR; ++ni) {
                int r = wn * (BN / 2) + ni * 16 + i15;
                bfr[ni] = *(const bf16x8*)((const char*)Bsm + r * 128 +
                                           ((kc * 64 + g * 16) ^ ((r & 7) << 4)));
            }
#pragma unroll
            for (int mi = 0; mi < MR; ++mi)
#pragma unroll
                for (int ni = 0; ni < NR; ++ni)
                    acc[mi][ni] = __builtin_amdgcn_mfma_f32_16x16x32_bf16(
                        af[mi], bfr[ni], acc[mi][ni], 0, 0, 0);
        }
        __syncthreads();
    }

    float* Cf = (float*)Cout;
    if (SPLITK) Cf += (size_t)blockIdx.z * M * N;

#pragma unroll
    for (int ni = 0; ni < NR; ++ni) {
        int col = n0 + wn * (BN / 2) + ni * 16 + i15;
        float bb = bias ? bias[col] : 0.f;
#pragma unroll
        for (int mi = 0; mi < MR; ++mi) {
            if (VT && col >= 1024) {
                // V^T: rows 4g..4g+3 consecutive -> vector 8B store
                int row = m0 + wm * (BM / 2) + mi * 16 + 4 * g;
                ushort4 ov;
                ov.x = f2bf(acc[mi][ni][0] + bb);
                ov.y = f2bf(acc[mi][ni][1] + bb);
                ov.z = f2bf(acc[mi][ni][2] + bb);
                ov.w = f2bf(acc[mi][ni][3] + bb);
                *(ushort4*)(Vout + (size_t)(col - 1024) * 4096 + row) = ov;
            } else {
#pragma unroll
                for (int r2 = 0; r2 < 4; ++r2) {
                    int row = m0 + wm * (BM / 2) + mi * 16 + 4 * g + r2;
                    float v = acc[mi][ni][r2] + bb;
                    if (ACT) v = gelu_erf(v);
                    if (SCALED) v *= scale;
                    size_t off = VT ? ((size_t)row * 1024 + col)
                                    : ((size_t)row * N + col);
                    if (OUTF32) {
                        float rv = RES ? resid[off] : 0.f;
                        Cf[off] = v + rv;
                    } else {
                        ((ushort*)Cout)[off] = f2bf(v);
                    }
                }
            }
        }
    }
}

// ---------------------------------------------------------------------------
// Flash attention v6: 8 waves (512 thr) x 16 q-rows = 128 q-rows/block.
// 16x16 swapped QK^T, exp2, defer-max, setprio, bf16 split partials.
// K/V staged DIRECTLY via global_load_lds: linear LDS dest (tid*16),
// inverse-swizzled global source (rule #21), swizzled frag reads.
// Double-buffered, ONE barrier/tile, 2x-unrolled compile-time buf.
// ---------------------------------------------------------------------------
template <int NS>
__global__ __launch_bounds__(512) void flash_attn(
    const ushort* __restrict__ Q,    // [2048][1024] bf16 (pre-scaled 0.125*log2e)
    const ushort* __restrict__ Kb,   // [4096][1024] bf16
    const ushort* __restrict__ Vt,   // [1024][4096] bf16
    ushort* __restrict__ O,          // NS==1: [2048][1024] bf16
    ushort* __restrict__ Opart,      // NS>1: [NS][2048][1024] bf16 (unnormalized)
    float* __restrict__ Ml) {        // NS>1: [NS][2048][16][2] f32
    constexpr int D = 1024;
    __shared__ __align__(16) ushort Ksm[2][64 * 64];
    __shared__ __align__(16) ushort Vsm[2][64 * 64];
    __shared__ __align__(16) ushort Psm[8][16 * 64];

    const int tid = threadIdx.x;
    const int w = tid >> 6, lane = tid & 63, g = lane >> 4, i15 = lane & 15;
    const int bid = blockIdx.x;
    const int h = bid & 15;                 // bid%8 == h%8 -> same-head same-XCD
    const int qB = 15 - ((bid >> 4) & 15);  // heavy q-blocks first
    const int s = (NS > 1) ? (bid >> 8) : 0;
    const int qb = qB * 128 + w * 16;
    const int qrow = qb + i15;
    const int diagW = qb >> 6;              // wave's partial-mask tile
    const int diagB = 2 * qB + 1;           // block's last self tile
    const int nt = diagB + 33;
    const int lo = (s * nt) / NS;
    const int hi = ((s + 1) * nt) / NS;

    bf16x8 qf[2];
    qf[0] = *(const bf16x8*)(Q + (size_t)qrow * D + h * 64 + g * 8);
    qf[1] = *(const bf16x8*)(Q + (size_t)qrow * D + h * 64 + 32 + g * 8);

    f32x4 o[4] = {};
    float m_run = -INFINITY, l_run = 0.f;

    // gload_lds staging: LDS slot (r = tid>>3, cb = (tid&7)*16) <- global
    // (row r of tile, byte col cb ^ ((r&7)<<4))  [swizzle is an involution]
    const int sr  = tid >> 3;               // 0..63
    const int ssw = ((tid & 7) * 16) ^ ((sr & 7) << 4);
    const char* kb0 = (const char*)Kb + (size_t)sr * 2048 + h * 128 + ssw;
    const char* vb0 = (const char*)Vt + (size_t)(h * 64 + sr) * 8192 + ssw;

    auto jt_of = [&](int t) { return (t <= diagB) ? t : (32 + (t - diagB - 1)); };
    auto stage_g = [&](int buf, int t) {
        const int jt = jt_of(t);
        gload16(kb0 + (size_t)jt * 131072, (char*)Ksm[buf] + tid * 16);
        gload16(vb0 + (size_t)jt * 128, (char*)Vsm[buf] + tid * 16);
    };

    const int pbase = i15 * 128;            // within Psm[w]
    const int psw = (i15 & 7) << 4;

    auto body = [&](int buf, int t) {
        const int jt = jt_of(t);
        // S^T = K * Q^T
        f32x4 st[4];
        __builtin_amdgcn_s_setprio(1);
#pragma unroll
        for (int jg = 0; jg < 4; ++jg) {
            int jr = jg * 16 + i15;
            bf16x8 ka0 = *(const bf16x8*)((const char*)Ksm[buf] + jr * 128 +
                                          ((g * 16) ^ ((jr & 7) << 4)));
            bf16x8 ka1 = *(const bf16x8*)((const char*)Ksm[buf] + jr * 128 +
                                          ((64 + g * 16) ^ ((jr & 7) << 4)));
            f32x4 z = {};
            z = __builtin_amdgcn_mfma_f32_16x16x32_bf16(ka0, qf[0], z, 0, 0, 0);
            z = __builtin_amdgcn_mfma_f32_16x16x32_bf16(ka1, qf[1], z, 0, 0, 0);
            st[jg] = z;
        }
        __builtin_amdgcn_s_setprio(0);
        if (jt >= diagW && jt <= diagB) {   // partial or fully masked self tile
#pragma unroll
            for (int jg = 0; jg < 4; ++jg)
#pragma unroll
                for (int r = 0; r < 4; ++r) {
                    int j = jt * 64 + jg * 16 + 4 * g + r;
                    if (j > qrow) st[jg][r] = -50000.f;
                }
        }

        // row max (tree)
        float v8[8];
#pragma unroll
        for (int jg = 0; jg < 4; ++jg) {
            v8[2 * jg]     = fmaxf(st[jg][0], st[jg][1]);
            v8[2 * jg + 1] = fmaxf(st[jg][2], st[jg][3]);
        }
        v8[0] = fmaxf(v8[0], v8[4]); v8[1] = fmaxf(v8[1], v8[5]);
        v8[2] = fmaxf(v8[2], v8[6]); v8[3] = fmaxf(v8[3], v8[7]);
        float mt = fmaxf(fmaxf(v8[0], v8[1]), fmaxf(v8[2], v8[3]));
        mt = fmaxf(mt, __shfl_xor(mt, 16));
        mt = fmaxf(mt, __shfl_xor(mt, 32));

        const bool skip = __all(mt - m_run <= 8.f);
        float mnew, fscale;
        if (skip) { mnew = m_run; fscale = 1.f; }
        else      { mnew = fmaxf(m_run, mt); fscale = exp2f(m_run - mnew); }

        float pf[4][4], sj[4];
#pragma unroll
        for (int jg = 0; jg < 4; ++jg) {
#pragma unroll
            for (int r = 0; r < 4; ++r) pf[jg][r] = exp2f(st[jg][r] - mnew);
            sj[jg] = (pf[jg][0] + pf[jg][1]) + (pf[jg][2] + pf[jg][3]);
        }
        float psum = (sj[0] + sj[1]) + (sj[2] + sj[3]);
        psum += __shfl_xor(psum, 16);
        psum += __shfl_xor(psum, 32);
        l_run = l_run * fscale + psum;
        m_run = mnew;

        if (!skip) {
#pragma unroll
            for (int r = 0; r < 4; ++r) {
                float fr = __shfl(fscale, 20 * g + r);
#pragma unroll
                for (int dg = 0; dg < 4; ++dg) o[dg][r] *= fr;
            }
        }

        // pack P -> per-wave swizzled LDS [16 i][64 j]
#pragma unroll
        for (int jg = 0; jg < 4; ++jg) {
            uint2 pk;
            pk.x = cvtpk(pf[jg][0], pf[jg][1]);
            pk.y = cvtpk(pf[jg][2], pf[jg][3]);
            *(uint2*)((char*)Psm[w] + pbase + ((jg * 32 + g * 8) ^ psw)) = pk;
        }

        // O += P * V
        __builtin_amdgcn_s_setprio(1);
#pragma unroll
        for (int jc = 0; jc < 2; ++jc) {
            bf16x8 pa = *(const bf16x8*)((const char*)Psm[w] + pbase +
                                         ((jc * 64 + g * 16) ^ psw));
#pragma unroll
            for (int dg = 0; dg < 4; ++dg) {
                int dr = dg * 16 + i15;
                bf16x8 vb = *(const bf16x8*)((const char*)Vsm[buf] + dr * 128 +
                                             ((jc * 64 + g * 16) ^ ((dr & 7) << 4)));
                o[dg] = __builtin_amdgcn_mfma_f32_16x16x32_bf16(pa, vb, o[dg], 0, 0, 0);
            }
        }
        __builtin_amdgcn_s_setprio(0);
    };

    stage_g(0, lo);
    __syncthreads();

    int t = lo;
    for (; t + 1 < hi; t += 2) {
        stage_g(1, t + 1);          // next tile in flight over body
        body(0, t);
        __syncthreads();            // drains gloads + all waves done with buf 0
        if (t + 2 < hi) stage_g(0, t + 2);
        body(1, t + 1);
        __syncthreads();
    }
    if (t < hi) body(0, t);

    if (NS > 1) {
        if (g == 0) {
            float* mp = Ml + ((size_t)(s * 2048 + qrow) * 16 + h) * 2;
            mp[0] = m_run; mp[1] = l_run;
        }
#pragma unroll
        for (int r = 0; r < 4; ++r)
#pragma unroll
            for (int dg = 0; dg < 4; ++dg) {
                int row = qb + 4 * g + r;
                int col = h * 64 + dg * 16 + i15;
                Opart[(size_t)(s * 2048 + row) * 1024 + col] = f2bf(o[dg][r]);
            }
    } else {
#pragma unroll
        for (int r = 0; r < 4; ++r) {
            float lr = __shfl(l_run, 20 * g + r);
            float inv = 1.f / lr;
#pragma unroll
            for (int dg = 0; dg < 4; ++dg) {
                int row = qb + 4 * g + r;
                int col = h * 64 + dg * 16 + i15;
                O[(size_t)row * D + col] = f2bf(o[dg][r] * inv);
            }
        }
    }
}

// ---------------------------------------------------------------------------
template <int NS>
__global__ __launch_bounds__(256) void attn_combine(
    const ushort* __restrict__ Opart, const float* __restrict__ Ml,
    ushort* __restrict__ O) {
    const int row = blockIdx.x, tid = threadIdx.x;
    const int c = tid * 4, h = c >> 6;
    float ms[NS], ls[NS];
#pragma unroll
    for (int s = 0; s < NS; ++s) {
        const float* mp = Ml + ((size_t)(s * 2048 + row) * 16 + h) * 2;
        ms[s] = mp[0]; ls[s] = mp[1];
    }
    float m = ms[0];
#pragma unroll
    for (int s = 1; s < NS; ++s) m = fmaxf(m, ms[s]);
    float denom = 0.f, wgt[NS];
#pragma unroll
    for (int s = 0; s < NS; ++s) { wgt[s] = exp2f(ms[s] - m); denom += ls[s] * wgt[s]; }
    const float inv = 1.f / denom;
    float ax = 0, ay = 0, az = 0, aw = 0;
#pragma unroll
    for (int s = 0; s < NS; ++s) {
        ushort4 a = *(const ushort4*)(Opart + (size_t)(s * 2048 + row) * 1024 + c);
        ax += bf2f(a.x) * wgt[s]; ay += bf2f(a.y) * wgt[s];
        az += bf2f(a.z) * wgt[s]; aw += bf2f(a.w) * wgt[s];
    }
    ushort4 ob;
    ob.x = f2bf(ax * inv); ob.y = f2bf(ay * inv);
    ob.z = f2bf(az * inv); ob.w = f2bf(aw * inv);
    *(ushort4*)(O + (size_t)row * 1024 + c) = ob;
}

// ---------------------------------------------------------------------------
__global__ __launch_bounds__(256) void layernorm_k(
    const float* __restrict__ in, const float* __restrict__ gam,
    const float* __restrict__ bet, float* __restrict__ outf,
    ushort* __restrict__ outb) {
    const int row = blockIdx.x, tid = threadIdx.x;
    const float4 v = *(const float4*)(in + (size_t)row * 1024 + tid * 4);
    float s = v.x + v.y + v.z + v.w;
    float sq = v.x * v.x + v.y * v.y + v.z * v.z + v.w * v.w;
#pragma unroll
    for (int d = 1; d < 64; d <<= 1) {
        s += __shfl_xor(s, d);
        sq += __shfl_xor(sq, d);
    }
    __shared__ float red[8];
    const int w = tid >> 6;
    if ((tid & 63) == 0) { red[w] = s; red[4 + w] = sq; }
    __syncthreads();
    s = red[0] + red[1] + red[2] + red[3];
    sq = red[4] + red[5] + red[6] + red[7];
    const float mu = s * (1.f / 1024.f);
    const float rs = rsqrtf(sq * (1.f / 1024.f) - mu * mu + 1e-5f);
    const float4 gg = *(const float4*)(gam + tid * 4);
    const float4 bb = *(const float4*)(bet + tid * 4);
    float4 o;
    o.x = (v.x - mu) * rs * gg.x + bb.x;
    o.y = (v.y - mu) * rs * gg.y + bb.y;
    o.z = (v.z - mu) * rs * gg.z + bb.z;
    o.w = (v.w - mu) * rs * gg.w + bb.w;
    *(float4*)(outf + (size_t)row * 1024 + tid * 4) = o;
    if (outb) {
        ushort4 ob;
        ob.x = f2bf(o.x); ob.y = f2bf(o.y); ob.z = f2bf(o.z); ob.w = f2bf(o.w);
        *(ushort4*)(outb + (size_t)row * 1024 + tid * 4) = ob;
    }
}

// ---------------------------------------------------------------------------
// Final LN over (sum of NP split-K partials + bias + resid)
// ---------------------------------------------------------------------------
template <int NP>
__global__ __launch_bounds__(256) void layernorm_comb(
    const float* __restrict__ P,
    const float* __restrict__ bias, const float* __restrict__ resid,
    const float* __restrict__ gam, const float* __restrict__ bet,
    float* __restrict__ outf) {
    const int row = blockIdx.x, tid = threadIdx.x;
    const float4 rr = *(const float4*)(resid + (size_t)row * 1024 + tid * 4);
    const float4 bs = *(const float4*)(bias + tid * 4);
    float4 v;
    v.x = rr.x + bs.x; v.y = rr.y + bs.y; v.z = rr.z + bs.z; v.w = rr.w + bs.w;
#pragma unroll
    for (int p = 0; p < NP; ++p) {
        const float4 a = *(const float4*)(P + (size_t)(p * 2048 + row) * 1024 + tid * 4);
        v.x += a.x; v.y += a.y; v.z += a.z; v.w += a.w;
    }
    float s = v.x + v.y + v.z + v.w;
    float sq = v.x * v.x + v.y * v.y + v.z * v.z + v.w * v.w;
#pragma unroll
    for (int d = 1; d < 64; d <<= 1) {
        s += __shfl_xor(s, d);
        sq += __shfl_xor(sq, d);
    }
    __shared__ float red[8];
    const int w = tid >> 6;
    if ((tid & 63) == 0) { red[w] = s; red[4 + w] = sq; }
    __syncthreads();
    s = red[0] + red[1] + red[2] + red[3];
    sq = red[4] + red[5] + red[6] + red[7];
    const float mu = s * (1.f / 1024.f);
    const float rs = rsqrtf(sq * (1.f / 1024.f) - mu * mu + 1e-5f);
    const float4 gg = *(const float4*)(gam + tid * 4);
    const float4 bb = *(const float4*)(bet + tid * 4);
    float4 o;
    o.x = (v.x - mu) * rs * gg.x + bb.x;
    o.y = (v.y - mu) * rs * gg.y + bb.y;
    o.z = (v.z - mu) * rs * gg.z + bb.z;
    o.w = (v.w - mu) * rs * gg.w + bb.w;
    *(float4*)(outf + (size_t)row * 1024 + tid * 4) = o;
}

// ---------------------------------------------------------------------------
extern "C" void kernel_launch(void* const* d_in, const int* in_sizes, int n_in,
                              void* d_out, int out_size, void* d_ws, size_t ws_size,
                              hipStream_t stream) {
    const float* x    = (const float*)d_in[0];
    const float* ctx  = (const float*)d_in[1];
    const float* Wq   = (const float*)d_in[2];
    const float* bq   = (const float*)d_in[3];
    const float* Wkv  = (const float*)d_in[4];
    const float* bkv  = (const float*)d_in[5];
    const float* Wo   = (const float*)d_in[6];
    const float* bo   = (const float*)d_in[7];
    const float* g1   = (const float*)d_in[8];
    const float* b1   = (const float*)d_in[9];
    const float* W1   = (const float*)d_in[10];
    const float* bf1  = (const float*)d_in[11];
    const float* W2   = (const float*)d_in[12];
    const float* bf2  = (const float*)d_in[13];
    const float* g2   = (const float*)d_in[14];
    const float* b2   = (const float*)d_in[15];

    char* ws = (char*)d_ws;
    const size_t MB = 1u << 20;
    ushort* XCb  = (ushort*)(ws + 0);        // 8MB; dead after KV gemm
    ushort* WoT  = (ushort*)(ws + 8 * MB);   // 2MB
    ushort* W1T  = (ushort*)(ws + 10 * MB);  // 8MB
    ushort* W2T  = (ushort*)(ws + 18 * MB);  // 8MB
    ushort* WqT  = (ushort*)(ws + 26 * MB);  // 2MB; later x1b
    ushort* WkvT = (ushort*)(ws + 28 * MB);  // 4MB
    ushort* Qs   = (ushort*)(ws + 32 * MB);  // 4MB; later x1f
    ushort* attn = (ushort*)(ws + 36 * MB);  // 4MB
    ushort* Kb   = (ushort*)(ws + 40 * MB);  // 8MB; later ff (part)
    ushort* Vt   = (ushort*)(ws + 48 * MB);  // 8MB; later ff (part)
    ushort* x1b  = (ushort*)(ws + 26 * MB);  // 4MB
    float*  x1f  = (float*)(ws + 32 * MB);   // 8MB (over Qs+attn after use)
    ushort* ffb  = (ushort*)(ws + 40 * MB);  // 16MB (over Kb+Vt)
    float*  y1   = (float*)(ws + 56 * MB);   // 8MB
    ushort* Opart = (ushort*)(ws + 64 * MB); // NS*4MB bf16 attn partials
    float*  Pk4   = (float*)(ws + 64 * MB);  // 32MB FFN2 split-4 partials
    float*  Pk2   = (float*)(ws + 0);        // 16MB FFN2 split-2 fallback

    cvt2<<<4096, 256, 0, stream>>>(x, ctx, XCb, XCb + 2048 * 1024);
    tcvt_all<<<12288, 256, 0, stream>>>(Wq, Wkv, Wo, W1, W2,
                                        WqT, WkvT, WoT, W1T, W2T);
    // Q = (x@Wq + bq) * 0.125 * log2(e)
    gemm_bt<64, 128, 0, 0, 0, 1, 0, 0><<<dim3(8, 32), 256, 0, stream>>>(
        XCb, 1024, WqT, 1024, bq, nullptr, Qs, nullptr,
        2048, 1024, 1024, 0.18033688011112042f);
    // KV projection: K -> Kb [4096][1024]; V -> Vt [1024][4096] (transposed)
    gemm_bt<128, 128, 0, 0, 0, 0, 0, 1><<<dim3(16, 32), 256, 0, stream>>>(
        XCb, 1024, WkvT, 1024, bkv, nullptr, Kb, Vt,
        4096, 2048, 1024, 1.f);

    // attention: split-4 (>=82MB ws) > split-2 > single
    if (ws_size >= 82 * MB) {
        float* Ml = (float*)(ws + 80 * MB);
        flash_attn<4><<<1024, 512, 0, stream>>>(Qs, Kb, Vt, nullptr, Opart, Ml);
        attn_combine<4><<<2048, 256, 0, stream>>>(Opart, Ml, attn);
    } else if (ws_size >= 73 * MB) {
        float* Ml = (float*)(ws + 72 * MB);
        flash_attn<2><<<512, 512, 0, stream>>>(Qs, Kb, Vt, nullptr, Opart, Ml);
        attn_combine<2><<<2048, 256, 0, stream>>>(Opart, Ml, attn);
    } else {
        flash_attn<1><<<256, 512, 0, stream>>>(Qs, Kb, Vt, attn, nullptr, nullptr);
    }

    gemm_bt<64, 128, 0, 1, 1, 0, 0, 0><<<dim3(8, 32), 256, 0, stream>>>(
        attn, 1024, WoT, 1024, bo, x, y1, nullptr, 2048, 1024, 1024, 1.f);
    layernorm_k<<<2048, 256, 0, stream>>>(y1, g1, b1, x1f, x1b);
    gemm_bt<128, 128, 1, 0, 0, 0, 0, 0><<<dim3(32, 16), 256, 0, stream>>>(
        x1b, 1024, W1T, 1024, bf1, nullptr, ffb, nullptr, 2048, 4096, 1024, 1.f);
    // FFN2: 128x128 split-K, f32 partials merged in final LN
    if (ws_size >= 96 * MB) {
        gemm_bt<128, 128, 0, 1, 0, 0, 1, 0><<<dim3(8, 16, 4), 256, 0, stream>>>(
            ffb, 4096, W2T, 4096, nullptr, nullptr, Pk4, nullptr,
            2048, 1024, 1024, 1.f);
        layernorm_comb<4><<<2048, 256, 0, stream>>>(Pk4, bf2, x1f, g2, b2,
                                                    (float*)d_out);
    } else {
        gemm_bt<128, 128, 0, 1, 0, 0, 1, 0><<<dim3(8, 16, 2), 256, 0, stream>>>(
            ffb, 4096, W2T, 4096, nullptr, nullptr, Pk2, nullptr,
            2048, 1024, 2048, 1.f);
        layernorm_comb<2><<<2048, 256, 0, stream>>>(Pk2, bf2, x1f, g2, b2,
                                                    (float*)d_out);
    }
}

// Round 12
// 204.351 us; speedup vs baseline: 1.3559x; 1.0837x over previous
//
#include <hip/hip_runtime.h>

// ---------------------------------------------------------------------------
// TransformerDecoderBlockV2: bf16 MFMA implementation for gfx950
// B=1, N=2048, M=2048, D=1024, H=16, dh=64, DFF=4096
// ---------------------------------------------------------------------------

using bf16x8 = __attribute__((ext_vector_type(8))) short;
using f32x4  = __attribute__((ext_vector_type(4))) float;

__device__ __forceinline__ ushort f2bf(float f) {
    unsigned u = __float_as_uint(f);
    unsigned r = (u + 0x7fffu + ((u >> 16) & 1u)) >> 16;
    return (ushort)r;
}

__device__ __forceinline__ float bf2f(ushort u) {
    return __uint_as_float((uint)u << 16);
}

__device__ __forceinline__ void gload16(const void* g, void* l) {
    __builtin_amdgcn_global_load_lds(
        (const __attribute__((address_space(1))) void*)g,
        (__attribute__((address_space(3))) void*)l, 16, 0, 0);
}

__device__ __forceinline__ float gelu_erf(float v) {
    return 0.5f * v * (1.0f + erff(v * 0.70710678118654752f));
}

__device__ __forceinline__ uint cvtpk(float a, float b) {
    uint r;
    asm("v_cvt_pk_bf16_f32 %0, %1, %2" : "=v"(r) : "v"(a), "v"(b));
    return r;
}

// ---------------------------------------------------------------------------
// Fused prep: blocks 0..4095 convert x/ctx to bf16; 4096..16383 transpose+cvt
// the 5 weight matrices.
// ---------------------------------------------------------------------------
__global__ __launch_bounds__(256) void prep_all(
    const float* __restrict__ x, const float* __restrict__ ctx,
    ushort* __restrict__ XCb,
    const float* __restrict__ Wq, const float* __restrict__ Wkv,
    const float* __restrict__ Wo, const float* __restrict__ W1,
    const float* __restrict__ W2,
    ushort* __restrict__ WqT, ushort* __restrict__ WkvT,
    ushort* __restrict__ WoT, ushort* __restrict__ W1T,
    ushort* __restrict__ W2T) {
    __shared__ float tile[32][33];
    int b = blockIdx.x;
    if (b < 4096) {
        const float* in = (b < 2048) ? x : ctx;
        ushort* out = XCb + ((b < 2048) ? 0 : (size_t)2048 * 1024);
        const int i = ((b & 2047) * 256 + threadIdx.x) * 4;
        float4 v = *(const float4*)(in + i);
        ushort4 o;
        o.x = f2bf(v.x); o.y = f2bf(v.y); o.z = f2bf(v.z); o.w = f2bf(v.w);
        *(ushort4*)(out + i) = o;
        return;
    }
    b -= 4096;
    const float* in; ushort* out; int R, C, loc;
    if (b < 1024)      { in = Wq;  out = WqT;  R = 1024; C = 1024; loc = b; }
    else if (b < 3072) { in = Wkv; out = WkvT; R = 1024; C = 2048; loc = b - 1024; }
    else if (b < 4096) { in = Wo;  out = WoT;  R = 1024; C = 1024; loc = b - 3072; }
    else if (b < 8192) { in = W1;  out = W1T;  R = 1024; C = 4096; loc = b - 4096; }
    else               { in = W2;  out = W2T;  R = 4096; C = 1024; loc = b - 8192; }
    const int nbx = C >> 5;
    const int c0 = (loc % nbx) * 32, r0 = (loc / nbx) * 32;
    const int tx = threadIdx.x & 31, ty = threadIdx.x >> 5;
#pragma unroll
    for (int i = 0; i < 4; ++i)
        tile[ty + 8 * i][tx] = in[(size_t)(r0 + ty + 8 * i) * C + c0 + tx];
    __syncthreads();
#pragma unroll
    for (int i = 0; i < 4; ++i)
        out[(size_t)(c0 + ty + 8 * i) * R + r0 + tx] = f2bf(tile[tx][ty + 8 * i]);
}

// ---------------------------------------------------------------------------
// GEMM: C[M][N] = epilogue( A[M][K] * Bt[N][K]^T + bias ), bf16 in.
// 128x128 = m97-class structure; SPLITK via blockIdx.z (f32 or bf16 partials).
// VT: cols >= 1024 written TRANSPOSED bf16 to Vout[col-1024][row].
// ---------------------------------------------------------------------------
template <int BM, int BN, int ACT, int OUTF32, int RES, int SCALED, int SPLITK, int VT>
__global__ __launch_bounds__(256) void gemm_bt(
    const ushort* __restrict__ A, int lda, const ushort* __restrict__ Bt, int ldb,
    const float* __restrict__ bias, const float* __restrict__ resid,
    void* __restrict__ Cout, ushort* __restrict__ Vout,
    int M, int N, int K, float scale) {
    constexpr int MR = BM / 32, NR = BN / 32;
    __shared__ __align__(16) ushort Asm[BM * 64];
    __shared__ __align__(16) ushort Bsm[BN * 64];
    const int tid = threadIdx.x;
    const int w = tid >> 6, lane = tid & 63, g = lane >> 4, i15 = lane & 15;
    const int wm = w >> 1, wn = w & 1;
    const int m0 = blockIdx.y * BM, n0 = blockIdx.x * BN;
    if (SPLITK) {
        A += (size_t)blockIdx.z * K;
        Bt += (size_t)blockIdx.z * K;
    }

    f32x4 acc[MR][NR] = {};

    for (int kt = 0; kt < K; kt += 64) {
#pragma unroll
        for (int q = 0; q < BM / 32; ++q) {
            int off = (w * (BM / 32) + q) * 1024 + lane * 16;
            int r = off >> 7, cb = off & 127;
            int scb = cb ^ ((r & 7) << 4);
            const void* src = (const char*)A + ((size_t)(m0 + r) * lda + kt) * 2 + scb;
            gload16(src, (char*)Asm + (w * (BM / 32) + q) * 1024);
        }
#pragma unroll
        for (int q = 0; q < BN / 32; ++q) {
            int off = (w * (BN / 32) + q) * 1024 + lane * 16;
            int r = off >> 7, cb = off & 127;
            int scb = cb ^ ((r & 7) << 4);
            const void* src = (const char*)Bt + ((size_t)(n0 + r) * ldb + kt) * 2 + scb;
            gload16(src, (char*)Bsm + (w * (BN / 32) + q) * 1024);
        }
        __syncthreads();

#pragma unroll
        for (int kc = 0; kc < 2; ++kc) {
            bf16x8 af[MR], bfr[NR];
#pragma unroll
            for (int mi = 0; mi < MR; ++mi) {
                int r = wm * (BM / 2) + mi * 16 + i15;
                af[mi] = *(const bf16x8*)((const char*)Asm + r * 128 +
                                          ((kc * 64 + g * 16) ^ ((r & 7) << 4)));
            }
#pragma unroll
            for (int ni = 0; ni < NR; ++ni) {
                int r = wn * (BN / 2) + ni * 16 + i15;
                bfr[ni] = *(const bf16x8*)((const char*)Bsm + r * 128 +
                                           ((kc * 64 + g * 16) ^ ((r & 7) << 4)));
            }
#pragma unroll
            for (int mi = 0; mi < MR; ++mi)
#pragma unroll
                for (int ni = 0; ni < NR; ++ni)
                    acc[mi][ni] = __builtin_amdgcn_mfma_f32_16x16x32_bf16(
                        af[mi], bfr[ni], acc[mi][ni], 0, 0, 0);
        }
        __syncthreads();
    }

    float* Cf = (float*)Cout;
    ushort* Cb = (ushort*)Cout;
    if (SPLITK) {
        Cf += (size_t)blockIdx.z * M * N;
        Cb += (size_t)blockIdx.z * M * N;
    }

#pragma unroll
    for (int ni = 0; ni < NR; ++ni) {
        int col = n0 + wn * (BN / 2) + ni * 16 + i15;
        float bb = bias ? bias[col] : 0.f;
#pragma unroll
        for (int mi = 0; mi < MR; ++mi) {
            if (VT && col >= 1024) {
                int row = m0 + wm * (BM / 2) + mi * 16 + 4 * g;
                ushort4 ov;
                ov.x = f2bf(acc[mi][ni][0] + bb);
                ov.y = f2bf(acc[mi][ni][1] + bb);
                ov.z = f2bf(acc[mi][ni][2] + bb);
                ov.w = f2bf(acc[mi][ni][3] + bb);
                *(ushort4*)(Vout + (size_t)(col - 1024) * 4096 + row) = ov;
            } else {
#pragma unroll
                for (int r2 = 0; r2 < 4; ++r2) {
                    int row = m0 + wm * (BM / 2) + mi * 16 + 4 * g + r2;
                    float v = acc[mi][ni][r2] + bb;
                    if (ACT) v = gelu_erf(v);
                    if (SCALED) v *= scale;
                    size_t off = VT ? ((size_t)row * 1024 + col)
                                    : ((size_t)row * N + col);
                    if (OUTF32) {
                        float rv = RES ? resid[off] : 0.f;
                        Cf[off] = v + rv;
                    } else {
                        Cb[off] = f2bf(v);
                    }
                }
            }
        }
    }
}

// ---------------------------------------------------------------------------
// Flash attention v7: 8 waves x 16 q-rows, reg-staged dbuf K/V LDS,
// 16x16 swapped QK^T, exp2, defer-max, setprio, bf16 split partials.
// l computed by MFMA ones-column trick (ls accumulator, rows 4g+r).
// ---------------------------------------------------------------------------
template <int NS>
__global__ __launch_bounds__(512) void flash_attn(
    const ushort* __restrict__ Q,    // [2048][1024] bf16 (pre-scaled 0.125*log2e)
    const ushort* __restrict__ Kb,   // [4096][1024] bf16
    const ushort* __restrict__ Vt,   // [1024][4096] bf16
    ushort* __restrict__ O,          // NS==1: [2048][1024] bf16
    ushort* __restrict__ Opart,      // NS>1: [NS][2048][1024] bf16 (unnormalized)
    float* __restrict__ Ml) {        // NS>1: [NS][2048][16][2] f32
    constexpr int D = 1024;
    __shared__ __align__(16) ushort Ksm[2][64 * 64];
    __shared__ __align__(16) ushort Vsm[2][64 * 64];
    __shared__ __align__(16) ushort Psm[8][16 * 64];

    const int tid = threadIdx.x;
    const int w = tid >> 6, lane = tid & 63, g = lane >> 4, i15 = lane & 15;
    const int bid = blockIdx.x;
    const int h = bid & 15;                 // bid%8 == h%8 -> same-head same-XCD
    const int qB = 15 - ((bid >> 4) & 15);  // heavy q-blocks first
    const int s = (NS > 1) ? (bid >> 8) : 0;
    const int qb = qB * 128 + w * 16;       // wave's first q-row (includes w*16)
    const int qrow = qb + i15;
    const int diagW = qb >> 6;              // wave's partial-mask tile
    const int diagB = 2 * qB + 1;           // block's last self tile
    const int nt = diagB + 33;
    const int lo = (s * nt) / NS;
    const int hi = ((s + 1) * nt) / NS;

    bf16x8 qf[2];
    qf[0] = *(const bf16x8*)(Q + (size_t)qrow * D + h * 64 + g * 8);
    qf[1] = *(const bf16x8*)(Q + (size_t)qrow * D + h * 64 + 32 + g * 8);

    const short oneb = (short)0x3F80;       // 1.0 bf16
    const bf16x8 ones = {oneb, oneb, oneb, oneb, oneb, oneb, oneb, oneb};

    f32x4 o[4] = {};
    f32x4 ls = {};                          // row-sums l, rows 4g+r (replicated)
    float m_run = -INFINITY;

    // staging: 512 threads, 64x64 bf16 K tile + V tile, 1 uint4 each
    const int sr  = tid >> 3;               // 0..63
    const int scb = (tid & 7) * 16;
    const int ssw = scb ^ ((sr & 7) << 4);
    const char* kb0 = (const char*)Kb + ((size_t)sr * 1024 + h * 64) * 2 + scb;
    const char* vb0 = (const char*)Vt + ((size_t)(h * 64 + sr) * 4096) * 2 + scb;

    uint4 kreg, vreg;
    auto jt_of = [&](int t) { return (t <= diagB) ? t : (32 + (t - diagB - 1)); };
    auto stage = [&](int t) {
        const int jt = jt_of(t);
        kreg = *(const uint4*)(kb0 + (size_t)jt * 64 * 2048);
        vreg = *(const uint4*)(vb0 + (size_t)jt * 128);
    };
    auto wlds = [&](int buf) {
        *(uint4*)((char*)Ksm[buf] + sr * 128 + ssw) = kreg;
        *(uint4*)((char*)Vsm[buf] + sr * 128 + ssw) = vreg;
    };

    const int pbase = i15 * 128;            // within Psm[w]
    const int psw = (i15 & 7) << 4;

    auto body = [&](int buf, int t) {
        const int jt = jt_of(t);
        // S^T = K * Q^T
        f32x4 st[4];
        __builtin_amdgcn_s_setprio(1);
#pragma unroll
        for (int jg = 0; jg < 4; ++jg) {
            int jr = jg * 16 + i15;
            bf16x8 ka0 = *(const bf16x8*)((const char*)Ksm[buf] + jr * 128 +
                                          ((g * 16) ^ ((jr & 7) << 4)));
            bf16x8 ka1 = *(const bf16x8*)((const char*)Ksm[buf] + jr * 128 +
                                          ((64 + g * 16) ^ ((jr & 7) << 4)));
            f32x4 z = {};
            z = __builtin_amdgcn_mfma_f32_16x16x32_bf16(ka0, qf[0], z, 0, 0, 0);
            z = __builtin_amdgcn_mfma_f32_16x16x32_bf16(ka1, qf[1], z, 0, 0, 0);
            st[jg] = z;
        }
        __builtin_amdgcn_s_setprio(0);
        if (jt >= diagW && jt <= diagB) {   // partial or fully masked self tile
#pragma unroll
            for (int jg = 0; jg < 4; ++jg)
#pragma unroll
                for (int r = 0; r < 4; ++r) {
                    int j = jt * 64 + jg * 16 + 4 * g + r;
                    if (j > qrow) st[jg][r] = -50000.f;
                }
        }

        // row max: max3-shaped tree (8 ops) + 2 swizzles
        float a0 = fmaxf(fmaxf(st[0][0], st[0][1]), st[0][2]);
        float a1 = fmaxf(fmaxf(st[0][3], st[1][0]), st[1][1]);
        float a2 = fmaxf(fmaxf(st[1][2], st[1][3]), st[2][0]);
        float a3 = fmaxf(fmaxf(st[2][1], st[2][2]), st[2][3]);
        float a4 = fmaxf(fmaxf(st[3][0], st[3][1]), st[3][2]);
        float b0 = fmaxf(fmaxf(a0, a1), a2);
        float b1 = fmaxf(fmaxf(a3, a4), st[3][3]);
        float mt = fmaxf(b0, b1);
        mt = fmaxf(mt, __shfl_xor(mt, 16));
        mt = fmaxf(mt, __shfl_xor(mt, 32));

        const bool skip = __all(mt - m_run <= 8.f);
        float mnew, fscale;
        if (skip) { mnew = m_run; fscale = 1.f; }
        else      { mnew = fmaxf(m_run, mt); fscale = exp2f(m_run - mnew); }

        float pf[4][4];
#pragma unroll
        for (int jg = 0; jg < 4; ++jg)
#pragma unroll
            for (int r = 0; r < 4; ++r) pf[jg][r] = exp2f(st[jg][r] - mnew);
        m_run = mnew;

        if (!skip) {
#pragma unroll
            for (int r = 0; r < 4; ++r) {
                float fr = __shfl(fscale, 20 * g + r);
#pragma unroll
                for (int dg = 0; dg < 4; ++dg) o[dg][r] *= fr;
                ls[r] *= fr;
            }
        }

        // pack P -> per-wave swizzled LDS [16 i][64 j]
#pragma unroll
        for (int jg = 0; jg < 4; ++jg) {
            uint2 pk;
            pk.x = cvtpk(pf[jg][0], pf[jg][1]);
            pk.y = cvtpk(pf[jg][2], pf[jg][3]);
            *(uint2*)((char*)Psm[w] + pbase + ((jg * 32 + g * 8) ^ psw)) = pk;
        }

        // O += P * V ; ls += P * ones (row-sums on the matrix pipe)
        __builtin_amdgcn_s_setprio(1);
#pragma unroll
        for (int jc = 0; jc < 2; ++jc) {
            bf16x8 pa = *(const bf16x8*)((const char*)Psm[w] + pbase +
                                         ((jc * 64 + g * 16) ^ psw));
            ls = __builtin_amdgcn_mfma_f32_16x16x32_bf16(pa, ones, ls, 0, 0, 0);
#pragma unroll
            for (int dg = 0; dg < 4; ++dg) {
                int dr = dg * 16 + i15;
                bf16x8 vb = *(const bf16x8*)((const char*)Vsm[buf] + dr * 128 +
                                             ((jc * 64 + g * 16) ^ ((dr & 7) << 4)));
                o[dg] = __builtin_amdgcn_mfma_f32_16x16x32_bf16(pa, vb, o[dg], 0, 0, 0);
            }
        }
        __builtin_amdgcn_s_setprio(0);
    };

    stage(lo);
    wlds(0);
    __syncthreads();

    int t = lo;
    for (; t + 1 < hi; t += 2) {
        stage(t + 1);
        body(0, t);
        wlds(1);
        __syncthreads();
        if (t + 2 < hi) stage(t + 2);
        body(1, t + 1);
        if (t + 2 < hi) { wlds(0); __syncthreads(); }
    }
    if (t < hi) body(0, t);

    if (NS > 1) {
#pragma unroll
        for (int r = 0; r < 4; ++r) {
            if (i15 == 4 * g + r) {   // this lane's ls[r] row == qrow (BUGFIX: qrow, not qb+w*16+i15)
                float* mp = Ml + ((size_t)(s * 2048 + qrow) * 16 + h) * 2;
                mp[0] = m_run; mp[1] = ls[r];
            }
        }
#pragma unroll
        for (int r = 0; r < 4; ++r)
#pragma unroll
            for (int dg = 0; dg < 4; ++dg) {
                int row = qb + 4 * g + r;
                int col = h * 64 + dg * 16 + i15;
                Opart[(size_t)(s * 2048 + row) * 1024 + col] = f2bf(o[dg][r]);
            }
    } else {
#pragma unroll
        for (int r = 0; r < 4; ++r) {
            float inv = 1.f / ls[r];
#pragma unroll
            for (int dg = 0; dg < 4; ++dg) {
                int row = qb + 4 * g + r;
                int col = h * 64 + dg * 16 + i15;
                O[(size_t)row * D + col] = f2bf(o[dg][r] * inv);
            }
        }
    }
}

// ---------------------------------------------------------------------------
template <int NS>
__global__ __launch_bounds__(256) void attn_combine(
    const ushort* __restrict__ Opart, const float* __restrict__ Ml,
    ushort* __restrict__ O) {
    const int row = blockIdx.x, tid = threadIdx.x;
    const int c = tid * 4, h = c >> 6;
    float ms[NS], lsv[NS];
#pragma unroll
    for (int s = 0; s < NS; ++s) {
        const float* mp = Ml + ((size_t)(s * 2048 + row) * 16 + h) * 2;
        ms[s] = mp[0]; lsv[s] = mp[1];
    }
    float m = ms[0];
#pragma unroll
    for (int s = 1; s < NS; ++s) m = fmaxf(m, ms[s]);
    float denom = 0.f, wgt[NS];
#pragma unroll
    for (int s = 0; s < NS; ++s) { wgt[s] = exp2f(ms[s] - m); denom += lsv[s] * wgt[s]; }
    const float inv = 1.f / denom;
    float ax = 0, ay = 0, az = 0, aw = 0;
#pragma unroll
    for (int s = 0; s < NS; ++s) {
        ushort4 a = *(const ushort4*)(Opart + (size_t)(s * 2048 + row) * 1024 + c);
        ax += bf2f(a.x) * wgt[s]; ay += bf2f(a.y) * wgt[s];
        az += bf2f(a.z) * wgt[s]; aw += bf2f(a.w) * wgt[s];
    }
    ushort4 ob;
    ob.x = f2bf(ax * inv); ob.y = f2bf(ay * inv);
    ob.z = f2bf(az * inv); ob.w = f2bf(aw * inv);
    *(ushort4*)(O + (size_t)row * 1024 + c) = ob;
}

// ---------------------------------------------------------------------------
__global__ __launch_bounds__(256) void layernorm_k(
    const float* __restrict__ in, const float* __restrict__ gam,
    const float* __restrict__ bet, float* __restrict__ outf,
    ushort* __restrict__ outb) {
    const int row = blockIdx.x, tid = threadIdx.x;
    const float4 v = *(const float4*)(in + (size_t)row * 1024 + tid * 4);
    float s = v.x + v.y + v.z + v.w;
    float sq = v.x * v.x + v.y * v.y + v.z * v.z + v.w * v.w;
#pragma unroll
    for (int d = 1; d < 64; d <<= 1) {
        s += __shfl_xor(s, d);
        sq += __shfl_xor(sq, d);
    }
    __shared__ float red[8];
    const int w = tid >> 6;
    if ((tid & 63) == 0) { red[w] = s; red[4 + w] = sq; }
    __syncthreads();
    s = red[0] + red[1] + red[2] + red[3];
    sq = red[4] + red[5] + red[6] + red[7];
    const float mu = s * (1.f / 1024.f);
    const float rs = rsqrtf(sq * (1.f / 1024.f) - mu * mu + 1e-5f);
    const float4 gg = *(const float4*)(gam + tid * 4);
    const float4 bb = *(const float4*)(bet + tid * 4);
    float4 o;
    o.x = (v.x - mu) * rs * gg.x + bb.x;
    o.y = (v.y - mu) * rs * gg.y + bb.y;
    o.z = (v.z - mu) * rs * gg.z + bb.z;
    o.w = (v.w - mu) * rs * gg.w + bb.w;
    *(float4*)(outf + (size_t)row * 1024 + tid * 4) = o;
    if (outb) {
        ushort4 ob;
        ob.x = f2bf(o.x); ob.y = f2bf(o.y); ob.z = f2bf(o.z); ob.w = f2bf(o.w);
        *(ushort4*)(outb + (size_t)row * 1024 + tid * 4) = ob;
    }
}

// ---------------------------------------------------------------------------
// LN over (sum of NP split-K partials + bias + resid); partials f32 or bf16.
// ---------------------------------------------------------------------------
template <int NP, int PBF16, int OUTB>
__global__ __launch_bounds__(256) void layernorm_comb(
    const void* __restrict__ P,
    const float* __restrict__ bias, const float* __restrict__ resid,
    const float* __restrict__ gam, const float* __restrict__ bet,
    float* __restrict__ outf, ushort* __restrict__ outb) {
    const int row = blockIdx.x, tid = threadIdx.x;
    const float4 rr = *(const float4*)(resid + (size_t)row * 1024 + tid * 4);
    const float4 bs = *(const float4*)(bias + tid * 4);
    float4 v;
    v.x = rr.x + bs.x; v.y = rr.y + bs.y; v.z = rr.z + bs.z; v.w = rr.w + bs.w;
#pragma unroll
    for (int p = 0; p < NP; ++p) {
        if (PBF16) {
            ushort4 a = *(const ushort4*)((const ushort*)P +
                          (size_t)(p * 2048 + row) * 1024 + tid * 4);
            v.x += bf2f(a.x); v.y += bf2f(a.y); v.z += bf2f(a.z); v.w += bf2f(a.w);
        } else {
            float4 a = *(const float4*)((const float*)P +
                          (size_t)(p * 2048 + row) * 1024 + tid * 4);
            v.x += a.x; v.y += a.y; v.z += a.z; v.w += a.w;
        }
    }
    float s = v.x + v.y + v.z + v.w;
    float sq = v.x * v.x + v.y * v.y + v.z * v.z + v.w * v.w;
#pragma unroll
    for (int d = 1; d < 64; d <<= 1) {
        s += __shfl_xor(s, d);
        sq += __shfl_xor(sq, d);
    }
    __shared__ float red[8];
    const int w = tid >> 6;
    if ((tid & 63) == 0) { red[w] = s; red[4 + w] = sq; }
    __syncthreads();
    s = red[0] + red[1] + red[2] + red[3];
    sq = red[4] + red[5] + red[6] + red[7];
    const float mu = s * (1.f / 1024.f);
    const float rs = rsqrtf(sq * (1.f / 1024.f) - mu * mu + 1e-5f);
    const float4 gg = *(const float4*)(gam + tid * 4);
    const float4 bb = *(const float4*)(bet + tid * 4);
    float4 o;
    o.x = (v.x - mu) * rs * gg.x + bb.x;
    o.y = (v.y - mu) * rs * gg.y + bb.y;
    o.z = (v.z - mu) * rs * gg.z + bb.z;
    o.w = (v.w - mu) * rs * gg.w + bb.w;
    *(float4*)(outf + (size_t)row * 1024 + tid * 4) = o;
    if (OUTB) {
        ushort4 ob;
        ob.x = f2bf(o.x); ob.y = f2bf(o.y); ob.z = f2bf(o.z); ob.w = f2bf(o.w);
        *(ushort4*)(outb + (size_t)row * 1024 + tid * 4) = ob;
    }
}

// ---------------------------------------------------------------------------
extern "C" void kernel_launch(void* const* d_in, const int* in_sizes, int n_in,
                              void* d_out, int out_size, void* d_ws, size_t ws_size,
                              hipStream_t stream) {
    const float* x    = (const float*)d_in[0];
    const float* ctx  = (const float*)d_in[1];
    const float* Wq   = (const float*)d_in[2];
    const float* bq   = (const float*)d_in[3];
    const float* Wkv  = (const float*)d_in[4];
    const float* bkv  = (const float*)d_in[5];
    const float* Wo   = (const float*)d_in[6];
    const float* bo   = (const float*)d_in[7];
    const float* g1   = (const float*)d_in[8];
    const float* b1   = (const float*)d_in[9];
    const float* W1   = (const float*)d_in[10];
    const float* bf1  = (const float*)d_in[11];
    const float* W2   = (const float*)d_in[12];
    const float* bf2  = (const float*)d_in[13];
    const float* g2   = (const float*)d_in[14];
    const float* b2   = (const float*)d_in[15];

    char* ws = (char*)d_ws;
    const size_t MB = 1u << 20;
    ushort* XCb  = (ushort*)(ws + 0);        // 8MB; dead after KV gemm
    ushort* WoT  = (ushort*)(ws + 8 * MB);   // 2MB
    ushort* W1T  = (ushort*)(ws + 10 * MB);  // 8MB
    ushort* W2T  = (ushort*)(ws + 18 * MB);  // 8MB
    ushort* WqT  = (ushort*)(ws + 26 * MB);  // 2MB; later x1b
    ushort* WkvT = (ushort*)(ws + 28 * MB);  // 4MB
    ushort* Qs   = (ushort*)(ws + 32 * MB);  // 4MB; later x1f
    ushort* attn = (ushort*)(ws + 36 * MB);  // 4MB
    ushort* Kb   = (ushort*)(ws + 40 * MB);  // 8MB; later ffb (part)
    ushort* Vt   = (ushort*)(ws + 48 * MB);  // 8MB; later ffb (part)
    ushort* x1b  = (ushort*)(ws + 26 * MB);  // 4MB
    float*  x1f  = (float*)(ws + 32 * MB);   // 8MB (over Qs+attn after use)
    ushort* ffb  = (ushort*)(ws + 40 * MB);  // 16MB (over Kb+Vt)
    float*  y1   = (float*)(ws + 56 * MB);   // 8MB (fallback path)
    ushort* Opart = (ushort*)(ws + 64 * MB); // 16MB bf16 attn partials (NS=4)
    float*  Pwo   = (float*)(ws + 64 * MB);  // 16MB Wo split-2 f32 partials
    ushort* Pk4b  = (ushort*)(ws + 64 * MB); // 16MB FFN2 split-4 bf16 partials
    float*  Pk2   = (float*)(ws + 0);        // 16MB FFN2 split-2 fallback
    float*  Ml    = (float*)(ws + 80 * MB);  // 1MB

    prep_all<<<16384, 256, 0, stream>>>(x, ctx, XCb, Wq, Wkv, Wo, W1, W2,
                                        WqT, WkvT, WoT, W1T, W2T);
    // Q = (x@Wq + bq) * 0.125 * log2(e)
    gemm_bt<64, 128, 0, 0, 0, 1, 0, 0><<<dim3(8, 32), 256, 0, stream>>>(
        XCb, 1024, WqT, 1024, bq, nullptr, Qs, nullptr,
        2048, 1024, 1024, 0.18033688011112042f);
    // KV projection: K -> Kb [4096][1024]; V -> Vt [1024][4096] (transposed)
    gemm_bt<128, 128, 0, 0, 0, 0, 0, 1><<<dim3(16, 32), 256, 0, stream>>>(
        XCb, 1024, WkvT, 1024, bkv, nullptr, Kb, Vt,
        4096, 2048, 1024, 1.f);

    const bool big = ws_size >= 82 * MB;
    if (big) {
        flash_attn<4><<<1024, 512, 0, stream>>>(Qs, Kb, Vt, nullptr, Opart, Ml);
        attn_combine<4><<<2048, 256, 0, stream>>>(Opart, Ml, attn);
        // Wo split-K x2 -> raw f32 partials; combine fused into LN1
        gemm_bt<64, 128, 0, 1, 0, 0, 1, 0><<<dim3(8, 32, 2), 256, 0, stream>>>(
            attn, 1024, WoT, 1024, nullptr, nullptr, Pwo, nullptr,
            2048, 1024, 512, 1.f);
        layernorm_comb<2, 0, 1><<<2048, 256, 0, stream>>>(
            Pwo, bo, x, g1, b1, x1f, x1b);
        gemm_bt<128, 128, 1, 0, 0, 0, 0, 0><<<dim3(32, 16), 256, 0, stream>>>(
            x1b, 1024, W1T, 1024, bf1, nullptr, ffb, nullptr,
            2048, 4096, 1024, 1.f);
        // FFN2 split-K x4, bf16 partials, merged in final LN
        gemm_bt<128, 128, 0, 0, 0, 0, 1, 0><<<dim3(8, 16, 4), 256, 0, stream>>>(
            ffb, 4096, W2T, 4096, nullptr, nullptr, Pk4b, nullptr,
            2048, 1024, 1024, 1.f);
        layernorm_comb<4, 1, 0><<<2048, 256, 0, stream>>>(
            Pk4b, bf2, x1f, g2, b2, (float*)d_out, nullptr);
    } else {
        flash_attn<1><<<256, 512, 0, stream>>>(Qs, Kb, Vt, attn, nullptr, nullptr);
        gemm_bt<64, 128, 0, 1, 1, 0, 0, 0><<<dim3(8, 32), 256, 0, stream>>>(
            attn, 1024, WoT, 1024, bo, x, y1, nullptr, 2048, 1024, 1024, 1.f);
        layernorm_k<<<2048, 256, 0, stream>>>(y1, g1, b1, x1f, x1b);
        gemm_bt<128, 128, 1, 0, 0, 0, 0, 0><<<dim3(32, 16), 256, 0, stream>>>(
            x1b, 1024, W1T, 1024, bf1, nullptr, ffb, nullptr,
            2048, 4096, 1024, 1.f);
        gemm_bt<128, 128, 0, 1, 0, 0, 1, 0><<<dim3(8, 16, 2), 256, 0, stream>>>(
            ffb, 4096, W2T, 4096, nullptr, nullptr, Pk2, nullptr,
            2048, 1024, 2048, 1.f);
        layernorm_comb<2, 0, 0><<<2048, 256, 0, stream>>>(
            Pk2, bf2, x1f, g2, b2, (float*)d_out, nullptr);
    }
}